// Round 1
// baseline (6208.545 us; speedup 1.0000x reference)
//
#include <hip/hip_runtime.h>
#include <hip/hip_bf16.h>
#include <math.h>

#define T_ 197
#define B_ 64
#define F_ 768
#define N_ 8
#define CAP_ 49
#define H_ 3072
#define G_ 192
#define TB_ (T_*B_)       // 12608
#define HC_ 384
#define NPASS_ (H_/HC_)   // 8
#define NBN_ (B_*N_)      // 512

// ---------------- out = -x ----------------
__global__ void k_init_out(const float* __restrict__ x, float* __restrict__ out) {
    int i = blockIdx.x * blockDim.x + threadIdx.x;
    const float4* xv = (const float4*)x;
    float4* ov = (float4*)out;
    float4 v = xv[i];
    ov[i] = make_float4(-v.x, -v.y, -v.z, -v.w);
}

// ---------------- gate: 8 tokens per block ----------------
__global__ __launch_bounds__(256) void k_gate(
        const float* __restrict__ x, const float* __restrict__ Wg1,
        const float* __restrict__ bg1, const float* __restrict__ Wg2,
        const float* __restrict__ bg2, float* __restrict__ cw) {
    __shared__ float xsh[8][F_];
    __shared__ float gs[8][G_];
    __shared__ float lg[8][N_];
    int tid = threadIdx.x;
    int id0 = blockIdx.x * 8;

    const float4* xv = (const float4*)(x + (size_t)id0 * F_);
    float4* xshv = (float4*)&xsh[0][0];
    for (int idx = tid; idx < 8 * (F_/4); idx += 256) xshv[idx] = xv[idx];
    __syncthreads();

    if (tid < G_) {
        float acc[8];
        float bb = bg1[tid];
        #pragma unroll
        for (int tk = 0; tk < 8; ++tk) acc[tk] = bb;
        for (int k = 0; k < F_; ++k) {
            float w = Wg1[k * G_ + tid];
            #pragma unroll
            for (int tk = 0; tk < 8; ++tk) acc[tk] += xsh[tk][k] * w;
        }
        #pragma unroll
        for (int tk = 0; tk < 8; ++tk) gs[tk][tid] = fmaxf(acc[tk], 0.f);
    }
    __syncthreads();

    if (tid < 64) {
        int tk = tid >> 3, n = tid & 7;
        float acc = bg2[n];
        for (int k = 0; k < G_; ++k) acc += gs[tk][k] * Wg2[k * N_ + n];
        lg[tk][n] = acc;
    }
    __syncthreads();

    if (tid < 8) {
        int tk = tid;
        float p[8];
        float m = lg[tk][0];
        #pragma unroll
        for (int n = 1; n < 8; ++n) m = fmaxf(m, lg[tk][n]);
        float s = 0.f;
        #pragma unroll
        for (int n = 0; n < 8; ++n) { p[n] = expf(lg[tk][n] - m); s += p[n]; }
        float inv = 1.f / s;
        #pragma unroll
        for (int n = 0; n < 8; ++n) p[n] *= inv;
        // top-2, ties -> lower index (matches jax.lax.top_k)
        int i1 = 0; float v1 = p[0];
        #pragma unroll
        for (int n = 1; n < 8; ++n) if (p[n] > v1) { v1 = p[n]; i1 = n; }
        int i2 = -1; float v2 = -1.f;
        #pragma unroll
        for (int n = 0; n < 8; ++n) if (n != i1 && p[n] > v2) { v2 = p[n]; i2 = n; }
        int id = id0 + tk;
        int t = id / B_, b = id % B_;
        #pragma unroll
        for (int n = 0; n < 8; ++n) {
            float v = (n == i1 || n == i2) ? p[n] : 0.f;
            cw[((size_t)(b * N_ + n)) * T_ + t] = v;
        }
    }
}

// ---------------- capacity: exact top-CAP rank per (b,n) ----------------
__global__ __launch_bounds__(256) void k_capacity(
        const float* __restrict__ cw, int* __restrict__ toks,
        float* __restrict__ wts, int* __restrict__ counts) {
    __shared__ float v[T_];
    __shared__ int keep[T_];
    int tid = threadIdx.x;
    int bn = blockIdx.x;
    if (tid < T_) v[tid] = cw[(size_t)bn * T_ + tid];
    __syncthreads();
    int kp = 0; float my = 0.f;
    if (tid < T_) {
        my = v[tid];
        int rank = 0;
        for (int t2 = 0; t2 < T_; ++t2) {
            float vt = v[t2];
            rank += (vt > my) || (vt == my && t2 < tid);
        }
        kp = (rank < CAP_) && (my > 0.f);
    }
    if (tid < T_) keep[tid] = kp;
    __syncthreads();
    if (tid < T_ && kp) {
        int slot = 0;
        for (int t2 = 0; t2 < T_; ++t2) slot += (t2 < tid) ? keep[t2] : 0;
        toks[bn * CAP_ + slot] = tid;
        wts[bn * CAP_ + slot] = my;
    }
    if (tid == 0) {
        int tot = 0;
        for (int t2 = 0; t2 < T_; ++t2) tot += keep[t2];
        counts[bn] = tot;
    }
}

// ---------------- FC1: h[rows][HC chunk] = relu(x @ W1 + b1) ----------------
__global__ __launch_bounds__(HC_) void k_fc1(
        const float* __restrict__ x, const float* __restrict__ W1,
        const float* __restrict__ b1, const int* __restrict__ toks,
        const int* __restrict__ counts, __hip_bfloat16* __restrict__ h, int pass) {
    __shared__ float xs[25][F_];
    int tid = threadIdx.x;            // < 384
    int bn = blockIdx.x >> 1;
    int half = blockIdx.x & 1;
    int r0 = half * 25;
    int b = bn >> 3, n = bn & 7;
    int c = counts[bn];

    // stage 25 rows (zero padded beyond count / beyond CAP)
    for (int idx = tid; idx < 25 * (F_/4); idx += HC_) {
        int r = idx / (F_/4), k4 = idx % (F_/4);
        int gr = r0 + r;
        float4 val = make_float4(0.f, 0.f, 0.f, 0.f);
        if (gr < c) {
            int t = toks[bn * CAP_ + gr];
            val = ((const float4*)(x + ((size_t)(t * B_ + b)) * F_))[k4];
        }
        ((float4*)&xs[r][0])[k4] = val;
    }
    __syncthreads();

    int j = pass * HC_ + tid;
    const float* w1p = W1 + (size_t)n * F_ * H_ + j;   // stride H_ over k
    float bias = b1[n * H_ + j];
    float acc[25];
    #pragma unroll
    for (int r = 0; r < 25; ++r) acc[r] = bias;

    const float4* xsv = (const float4*)&xs[0][0];      // [25][F_/4]
    for (int k4 = 0; k4 < F_/4; ++k4) {
        float w0 = w1p[(size_t)(4*k4+0) * H_];
        float w1v = w1p[(size_t)(4*k4+1) * H_];
        float w2v = w1p[(size_t)(4*k4+2) * H_];
        float w3v = w1p[(size_t)(4*k4+3) * H_];
        #pragma unroll
        for (int r = 0; r < 25; ++r) {
            float4 xv = xsv[r * (F_/4) + k4];
            acc[r] += xv.x*w0 + xv.y*w1v + xv.z*w2v + xv.w*w3v;
        }
    }
    __hip_bfloat16* hp = h + ((size_t)bn * CAP_ + r0) * HC_ + tid;
    #pragma unroll
    for (int r = 0; r < 25; ++r) {
        int gr = r0 + r;
        if (gr < CAP_) hp[(size_t)r * HC_] = __float2bfloat16(fmaxf(acc[r], 0.f));
    }
}

// ---------------- FC2: out += fw * (h @ W2 + b2) ----------------
__global__ __launch_bounds__(768) void k_fc2(
        const float* __restrict__ W2, const float* __restrict__ b2,
        const int* __restrict__ toks, const float* __restrict__ wts,
        const int* __restrict__ counts, const __hip_bfloat16* __restrict__ h,
        float* __restrict__ out, int pass) {
    __shared__ float hs[CAP_][HC_];
    int tid = threadIdx.x;            // < 768
    int bn = blockIdx.x;
    int c = counts[bn];
    if (c == 0) return;               // uniform; before any barrier
    int b = bn >> 3, n = bn & 7;

    // stage h chunk (bf16 -> f32)
    const ushort4* hv = (const ushort4*)(h + (size_t)bn * CAP_ * HC_);
    for (int idx = tid; idx < CAP_ * (HC_/4); idx += 768) {
        ushort4 u = hv[idx];
        float4 fv;
        fv.x = __bfloat162float(*(const __hip_bfloat16*)&u.x);
        fv.y = __bfloat162float(*(const __hip_bfloat16*)&u.y);
        fv.z = __bfloat162float(*(const __hip_bfloat16*)&u.z);
        fv.w = __bfloat162float(*(const __hip_bfloat16*)&u.w);
        ((float4*)&hs[0][0])[idx] = fv;
    }
    __syncthreads();

    int f = tid;
    const float* w2p = W2 + (size_t)n * H_ * F_ + (size_t)(pass * HC_) * F_ + f;
    float acc[CAP_];
    #pragma unroll
    for (int r = 0; r < CAP_; ++r) acc[r] = 0.f;

    for (int j4 = 0; j4 < HC_/4; ++j4) {
        float w0 = w2p[(size_t)(4*j4+0) * F_];
        float w1v = w2p[(size_t)(4*j4+1) * F_];
        float w2v = w2p[(size_t)(4*j4+2) * F_];
        float w3v = w2p[(size_t)(4*j4+3) * F_];
        #pragma unroll
        for (int r = 0; r < CAP_; ++r) {
            float4 hh = ((const float4*)&hs[r][0])[j4];
            acc[r] += hh.x*w0 + hh.y*w1v + hh.z*w2v + hh.w*w3v;
        }
    }

    float bias = (pass == 0) ? b2[n * F_ + f] : 0.f;
    #pragma unroll
    for (int r = 0; r < CAP_; ++r) {
        if (r < c) {
            int t = toks[bn * CAP_ + r];
            float fw = wts[bn * CAP_ + r];
            atomicAdd(&out[((size_t)(t * B_ + b)) * F_ + f], fw * (acc[r] + bias));
        }
    }
}

extern "C" void kernel_launch(void* const* d_in, const int* in_sizes, int n_in,
                              void* d_out, int out_size, void* d_ws, size_t ws_size,
                              hipStream_t stream) {
    const float* x   = (const float*)d_in[0];
    const float* Wg1 = (const float*)d_in[1];
    const float* bg1 = (const float*)d_in[2];
    const float* Wg2 = (const float*)d_in[3];
    const float* bg2 = (const float*)d_in[4];
    const float* W1  = (const float*)d_in[5];
    const float* b1  = (const float*)d_in[6];
    const float* W2  = (const float*)d_in[7];
    const float* b2  = (const float*)d_in[8];
    float* out = (float*)d_out;

    // workspace carve-up (~20 MB total)
    __hip_bfloat16* h = (__hip_bfloat16*)d_ws;                         // 512*49*384 bf16 = 19.3 MB
    float* cw  = (float*)((char*)d_ws + (size_t)NBN_ * CAP_ * HC_ * 2);
    float* wts = cw + (size_t)NBN_ * T_;
    int* toks  = (int*)(wts + NBN_ * CAP_);
    int* counts = toks + NBN_ * CAP_;

    k_init_out<<<(TB_ * F_) / 1024, 256, 0, stream>>>(x, out);
    k_gate<<<TB_ / 8, 256, 0, stream>>>(x, Wg1, bg1, Wg2, bg2, cw);
    k_capacity<<<NBN_, 256, 0, stream>>>(cw, toks, wts, counts);
    for (int p = 0; p < NPASS_; ++p) {
        k_fc1<<<NBN_ * 2, HC_, 0, stream>>>(x, W1, b1, toks, counts, h, p);
        k_fc2<<<NBN_, 768, 0, stream>>>(W2, b2, toks, wts, counts, h, out, p);
    }
}

// Round 2
// 1279.013 us; speedup vs baseline: 4.8542x; 4.8542x over previous
//
#include <hip/hip_runtime.h>
#include <hip/hip_bf16.h>
#include <math.h>
#include <stdint.h>

#define T_ 197
#define B_ 64
#define F_ 768
#define N_ 8
#define CAP_ 49
#define H_ 3072
#define G_ 192
#define TB_ (T_*B_)       // 12608
#define NBN_ (B_*N_)      // 512
#define ME_ 3200          // padded rows per expert (25 * 128)
#define MR_ 3136          // real rows per expert (64 * 49)
#define MT_ 25600         // total padded rows
#define HC_ 768           // H chunk for MFMA path
#define NP_ 4             // passes (H_/HC_)
#define HCF_ 384          // fallback (round-1) H chunk
#define NPF_ 8

using bf16x8 = __attribute__((ext_vector_type(8))) short;
using f32x4  = __attribute__((ext_vector_type(4))) float;

__device__ __forceinline__ unsigned short f2bf(float v) {
    __hip_bfloat16 h = __float2bfloat16(v);
    return __builtin_bit_cast(unsigned short, h);
}

// async global->LDS, 16B per lane; LDS dest = wave-uniform base + lane*16
#define GLL16(g, l) __builtin_amdgcn_global_load_lds( \
    (const __attribute__((address_space(1))) unsigned int*)(uintptr_t)(g), \
    (__attribute__((address_space(3))) unsigned int*)(uintptr_t)(l), 16, 0, 0)

// ---------------- out = -x ----------------
__global__ void k_init_out(const float* __restrict__ x, float* __restrict__ out) {
    int i = blockIdx.x * blockDim.x + threadIdx.x;
    const float4* xv = (const float4*)x;
    float4* ov = (float4*)out;
    float4 v = xv[i];
    ov[i] = make_float4(-v.x, -v.y, -v.z, -v.w);
}

// ---------------- gate: 8 tokens per block (fp32 exact -> exact top-k) ----------------
__global__ __launch_bounds__(256) void k_gate(
        const float* __restrict__ x, const float* __restrict__ Wg1,
        const float* __restrict__ bg1, const float* __restrict__ Wg2,
        const float* __restrict__ bg2, float* __restrict__ cw) {
    __shared__ float xsh[8][F_];
    __shared__ float gs[8][G_];
    __shared__ float lg[8][N_];
    int tid = threadIdx.x;
    int id0 = blockIdx.x * 8;

    const float4* xv = (const float4*)(x + (size_t)id0 * F_);
    float4* xshv = (float4*)&xsh[0][0];
    for (int idx = tid; idx < 8 * (F_/4); idx += 256) xshv[idx] = xv[idx];
    __syncthreads();

    if (tid < G_) {
        float acc[8];
        float bb = bg1[tid];
        #pragma unroll
        for (int tk = 0; tk < 8; ++tk) acc[tk] = bb;
        for (int k = 0; k < F_; ++k) {
            float w = Wg1[k * G_ + tid];
            #pragma unroll
            for (int tk = 0; tk < 8; ++tk) acc[tk] += xsh[tk][k] * w;
        }
        #pragma unroll
        for (int tk = 0; tk < 8; ++tk) gs[tk][tid] = fmaxf(acc[tk], 0.f);
    }
    __syncthreads();

    if (tid < 64) {
        int tk = tid >> 3, n = tid & 7;
        float acc = bg2[n];
        for (int k = 0; k < G_; ++k) acc += gs[tk][k] * Wg2[k * N_ + n];
        lg[tk][n] = acc;
    }
    __syncthreads();

    if (tid < 8) {
        int tk = tid;
        float p[8];
        float m = lg[tk][0];
        #pragma unroll
        for (int n = 1; n < 8; ++n) m = fmaxf(m, lg[tk][n]);
        float s = 0.f;
        #pragma unroll
        for (int n = 0; n < 8; ++n) { p[n] = expf(lg[tk][n] - m); s += p[n]; }
        float inv = 1.f / s;
        #pragma unroll
        for (int n = 0; n < 8; ++n) p[n] *= inv;
        int i1 = 0; float v1 = p[0];
        #pragma unroll
        for (int n = 1; n < 8; ++n) if (p[n] > v1) { v1 = p[n]; i1 = n; }
        int i2 = -1; float v2 = -1.f;
        #pragma unroll
        for (int n = 0; n < 8; ++n) if (n != i1 && p[n] > v2) { v2 = p[n]; i2 = n; }
        int id = id0 + tk;
        int t = id / B_, b = id % B_;
        #pragma unroll
        for (int n = 0; n < 8; ++n) {
            float v = (n == i1 || n == i2) ? p[n] : 0.f;
            cw[((size_t)(b * N_ + n)) * T_ + t] = v;
        }
    }
}

// ---------------- capacity: exact top-CAP rank per (b,n) ----------------
__global__ __launch_bounds__(256) void k_capacity(
        const float* __restrict__ cw, int* __restrict__ toks,
        float* __restrict__ wts, int* __restrict__ counts) {
    __shared__ float v[T_];
    __shared__ int keep[T_];
    int tid = threadIdx.x;
    int bn = blockIdx.x;
    if (tid < T_) v[tid] = cw[(size_t)bn * T_ + tid];
    __syncthreads();
    int kp = 0; float my = 0.f;
    if (tid < T_) {
        my = v[tid];
        int rank = 0;
        for (int t2 = 0; t2 < T_; ++t2) {
            float vt = v[t2];
            rank += (vt > my) || (vt == my && t2 < tid);
        }
        kp = (rank < CAP_) && (my > 0.f);
    }
    if (tid < T_) keep[tid] = kp;
    __syncthreads();
    if (tid < T_ && kp) {
        int slot = 0;
        for (int t2 = 0; t2 < T_; ++t2) slot += (t2 < tid) ? keep[t2] : 0;
        toks[bn * CAP_ + slot] = tid;
        wts[bn * CAP_ + slot] = my;
    }
    if (tid == 0) {
        int tot = 0;
        for (int t2 = 0; t2 < T_; ++t2) tot += keep[t2];
        counts[bn] = tot;
    }
}

// ---------------- repack W [E][K][J] fp32 -> WT [E][J][K] bf16, pre-swizzled ----------------
// swizzle: within each 128B k-group of a row j, byte ^= ((j&7)<<4)
__global__ __launch_bounds__(256) void k_repack(
        const float* __restrict__ W, unsigned short* __restrict__ WT, int K, int J) {
    int bid = blockIdx.x;
    int nk = K >> 8, nj = J >> 8;
    int kt = bid % nk; bid /= nk;
    int jt = bid % nj; int e = bid / nj;
    int j = jt * 256 + threadIdx.x;
    const float* src = W + ((size_t)e * K + (size_t)kt * 256) * J + j;
    char* drow = (char*)WT + ((size_t)e * J + j) * (size_t)K * 2 + (size_t)kt * 512;
    int swz = (j & 7) << 4;
    for (int c = 0; c < 32; ++c) {
        float f[8];
        #pragma unroll
        for (int s = 0; s < 8; ++s) f[s] = src[(size_t)(c * 8 + s) * J];
        uint4 u;
        u.x = f2bf(f[0]) | ((unsigned)f2bf(f[1]) << 16);
        u.y = f2bf(f[2]) | ((unsigned)f2bf(f[3]) << 16);
        u.z = f2bf(f[4]) | ((unsigned)f2bf(f[5]) << 16);
        u.w = f2bf(f[6]) | ((unsigned)f2bf(f[7]) << 16);
        *(uint4*)(drow + (c >> 3) * 128 + (((c & 7) * 16) ^ swz)) = u;
    }
}

// ---------------- gather x rows -> Xg [MT_][768] bf16, pre-swizzled, zero-padded ----------------
__global__ __launch_bounds__(256) void k_gather(
        const float* __restrict__ x, const int* __restrict__ toks,
        const int* __restrict__ counts, unsigned short* __restrict__ Xg) {
    int gi = blockIdx.x * 256 + threadIdx.x;     // MT_*96 total
    int R = gi / 96, c = gi - R * 96;            // c: 16B chunk (8 bf16)
    int e = R / ME_, re = R - e * ME_;
    uint4 val = make_uint4(0u, 0u, 0u, 0u);
    if (re < MR_) {
        int g = re / CAP_, slot = re - g * CAP_;
        int bn = g * N_ + e;
        if (slot < counts[bn]) {
            int t = toks[bn * CAP_ + slot];
            const float* xp = x + ((size_t)t * B_ + g) * F_ + c * 8;
            float4 v0 = *(const float4*)xp;
            float4 v1 = *(const float4*)(xp + 4);
            val.x = f2bf(v0.x) | ((unsigned)f2bf(v0.y) << 16);
            val.y = f2bf(v0.z) | ((unsigned)f2bf(v0.w) << 16);
            val.z = f2bf(v1.x) | ((unsigned)f2bf(v1.y) << 16);
            val.w = f2bf(v1.z) | ((unsigned)f2bf(v1.w) << 16);
        }
    }
    int w = (c * 16) & 127;
    char* dst = (char*)Xg + (size_t)R * 1536 + (c >> 3) * 128 + (w ^ ((R & 7) << 4));
    *(uint4*)dst = val;
}

// ---------------- GEMM1: Hg^T-chunk = relu(W1T . Xg^T + b1)  (all operands row-contig) ----------------
__global__ __launch_bounds__(256) void k_gemm1(
        const unsigned short* __restrict__ W1T, const unsigned short* __restrict__ Xg,
        const float* __restrict__ b1, unsigned short* __restrict__ Hg, int pass) {
    __shared__ char ldsA[16384];
    __shared__ char ldsB[16384];
    int bid = blockIdx.x;
    int swzb = (bid & 7) * 150 + (bid >> 3);     // XCD swizzle, 1200 % 8 == 0 (bijective)
    int jt = swzb / 200;                          // 0..5: 128-col tile within H chunk
    int mt = swzb - jt * 200;                     // 0..199: token-row tile
    int e = mt / 25;
    int tid = threadIdx.x, lane = tid & 63, wid = tid >> 6;
    int lr8 = lane >> 3, sl = (lane & 7) << 4;
    const char* Ab = (const char*)W1T + ((size_t)e * H_ + (size_t)pass * HC_ + (size_t)jt * 128) * (F_ * 2);
    const char* Bb = (const char*)Xg + (size_t)mt * 128 * (F_ * 2);
    f32x4 acc[4][4] = {};
    int swz = (lane & 7) << 4;
    int q16 = (lane >> 4) << 4;
    const char* la = ldsA + ((wid & 1) * 64) * 128;
    const char* lb = ldsB + ((wid >> 1) * 64) * 128;

    for (int it = 0; it < 12; ++it) {
        int kb = it << 7;
        #pragma unroll
        for (int i = 0; i < 4; ++i) {
            int lr = wid * 32 + i * 8 + lr8;
            GLL16(Ab + (size_t)lr * 1536 + kb + sl, ldsA + (wid * 32 + i * 8) * 128);
            GLL16(Bb + (size_t)lr * 1536 + kb + sl, ldsB + (wid * 32 + i * 8) * 128);
        }
        __syncthreads();
        #pragma unroll
        for (int ks = 0; ks < 2; ++ks) {
            bf16x8 af[4], bfr[4];
            int kk = (ks * 64 + q16) ^ swz;
            #pragma unroll
            for (int t = 0; t < 4; ++t) {
                int ro = (16 * t + (lane & 15)) * 128;
                af[t]  = *(const bf16x8*)(la + ro + kk);
                bfr[t] = *(const bf16x8*)(lb + ro + kk);
            }
            #pragma unroll
            for (int ti = 0; ti < 4; ++ti)
                #pragma unroll
                for (int tm = 0; tm < 4; ++tm)
                    acc[ti][tm] = __builtin_amdgcn_mfma_f32_16x16x32_bf16(af[ti], bfr[tm], acc[ti][tm], 0, 0, 0);
        }
        __syncthreads();
    }
    // epilogue: lane holds 4 consecutive j at fixed token m; write 8B swizzled bf16 to Hg[m][j]
    int jl0 = jt * 128 + (wid & 1) * 64;
    int ml0 = mt * 128 + (wid >> 1) * 64;
    const float* b1p = b1 + (size_t)e * H_ + (size_t)pass * HC_;
    #pragma unroll
    for (int tj = 0; tj < 4; ++tj) {
        int jc = jl0 + 16 * tj + ((lane >> 4) << 2);
        float bb0 = b1p[jc], bb1 = b1p[jc + 1], bb2 = b1p[jc + 2], bb3 = b1p[jc + 3];
        #pragma unroll
        for (int tm = 0; tm < 4; ++tm) {
            int m = ml0 + 16 * tm + (lane & 15);
            f32x4 a = acc[tj][tm];
            unsigned int u0 = f2bf(fmaxf(a[0] + bb0, 0.f)) | ((unsigned)f2bf(fmaxf(a[1] + bb1, 0.f)) << 16);
            unsigned int u1 = f2bf(fmaxf(a[2] + bb2, 0.f)) | ((unsigned)f2bf(fmaxf(a[3] + bb3, 0.f)) << 16);
            int w = (jc * 2) & 127;
            char* dst = (char*)Hg + (size_t)m * 1536 + ((jc * 2) & ~127) + (w ^ ((m & 7) << 4));
            *(uint2*)dst = make_uint2(u0, u1);
        }
    }
}

// ---------------- GEMM2: out^T += fw * (W2T . Hg^T) (+ b2 at pass 0), scatter-atomic ----------------
__global__ __launch_bounds__(256) void k_gemm2(
        const unsigned short* __restrict__ W2T, const unsigned short* __restrict__ Hg,
        const float* __restrict__ b2, const int* __restrict__ toks,
        const float* __restrict__ wts, const int* __restrict__ counts,
        float* __restrict__ out, int pass) {
    __shared__ char ldsA[16384];
    __shared__ char ldsB[16384];
    int bid = blockIdx.x;
    int swzb = (bid & 7) * 150 + (bid >> 3);
    int ft = swzb / 200;                          // 0..5: 128-col tile of F
    int mt = swzb - ft * 200;
    int e = mt / 25;
    int tid = threadIdx.x, lane = tid & 63, wid = tid >> 6;
    int lr8 = lane >> 3, sl = (lane & 7) << 4;
    const char* Ab = (const char*)W2T + ((size_t)e * F_ + (size_t)ft * 128) * (H_ * 2) + (size_t)pass * HC_ * 2;
    const char* Bb = (const char*)Hg + (size_t)mt * 128 * (HC_ * 2);
    f32x4 acc[4][4] = {};
    int swz = (lane & 7) << 4;
    int q16 = (lane >> 4) << 4;
    const char* la = ldsA + ((wid & 1) * 64) * 128;
    const char* lb = ldsB + ((wid >> 1) * 64) * 128;

    for (int it = 0; it < 12; ++it) {
        int kb = it << 7;
        #pragma unroll
        for (int i = 0; i < 4; ++i) {
            int lr = wid * 32 + i * 8 + lr8;
            GLL16(Ab + (size_t)lr * 6144 + kb + sl, ldsA + (wid * 32 + i * 8) * 128);
            GLL16(Bb + (size_t)lr * 1536 + kb + sl, ldsB + (wid * 32 + i * 8) * 128);
        }
        __syncthreads();
        #pragma unroll
        for (int ks = 0; ks < 2; ++ks) {
            bf16x8 af[4], bfr[4];
            int kk = (ks * 64 + q16) ^ swz;
            #pragma unroll
            for (int t = 0; t < 4; ++t) {
                int ro = (16 * t + (lane & 15)) * 128;
                af[t]  = *(const bf16x8*)(la + ro + kk);
                bfr[t] = *(const bf16x8*)(lb + ro + kk);
            }
            #pragma unroll
            for (int ti = 0; ti < 4; ++ti)
                #pragma unroll
                for (int tm = 0; tm < 4; ++tm)
                    acc[ti][tm] = __builtin_amdgcn_mfma_f32_16x16x32_bf16(af[ti], bfr[tm], acc[ti][tm], 0, 0, 0);
        }
        __syncthreads();
    }
    // epilogue: lane = one token row per tm; 4 consecutive f per tf; atomicAdd into out
    int fl0 = ft * 128 + (wid & 1) * 64;
    int ml0 = mt * 128 + (wid >> 1) * 64;
    const float* b2p = b2 + (size_t)e * F_;
    int trow[4]; int gb[4]; float fwv[4];
    #pragma unroll
    for (int tm = 0; tm < 4; ++tm) {
        int m = ml0 + 16 * tm + (lane & 15);
        int re = m - e * ME_;
        int t = -1, g = 0; float fw = 0.f;
        if (re < MR_) {
            g = re / CAP_;
            int slot = re - g * CAP_;
            int bn = g * N_ + e;
            if (slot < counts[bn]) { t = toks[bn * CAP_ + slot]; fw = wts[bn * CAP_ + slot]; }
        }
        trow[tm] = t; gb[tm] = g; fwv[tm] = fw;
    }
    #pragma unroll
    for (int tf = 0; tf < 4; ++tf) {
        int f = fl0 + 16 * tf + ((lane >> 4) << 2);
        float c0 = 0.f, c1 = 0.f, c2 = 0.f, c3 = 0.f;
        if (pass == 0) { c0 = b2p[f]; c1 = b2p[f + 1]; c2 = b2p[f + 2]; c3 = b2p[f + 3]; }
        #pragma unroll
        for (int tm = 0; tm < 4; ++tm) {
            if (trow[tm] >= 0) {
                float* op = out + ((size_t)trow[tm] * B_ + gb[tm]) * F_ + f;
                f32x4 a = acc[tf][tm];
                float fw = fwv[tm];
                atomicAdd(op + 0, fw * (a[0] + c0));
                atomicAdd(op + 1, fw * (a[1] + c1));
                atomicAdd(op + 2, fw * (a[2] + c2));
                atomicAdd(op + 3, fw * (a[3] + c3));
            }
        }
    }
}

// ================= round-1 fallback kernels (used only if ws_size is small) =================
__global__ __launch_bounds__(HCF_) void k_fc1(
        const float* __restrict__ x, const float* __restrict__ W1,
        const float* __restrict__ b1, const int* __restrict__ toks,
        const int* __restrict__ counts, __hip_bfloat16* __restrict__ h, int pass) {
    __shared__ float xs[25][F_];
    int tid = threadIdx.x;
    int bn = blockIdx.x >> 1;
    int half = blockIdx.x & 1;
    int r0 = half * 25;
    int b = bn >> 3, n = bn & 7;
    int c = counts[bn];
    for (int idx = tid; idx < 25 * (F_/4); idx += HCF_) {
        int r = idx / (F_/4), k4 = idx % (F_/4);
        int gr = r0 + r;
        float4 val = make_float4(0.f, 0.f, 0.f, 0.f);
        if (gr < c) {
            int t = toks[bn * CAP_ + gr];
            val = ((const float4*)(x + ((size_t)(t * B_ + b)) * F_))[k4];
        }
        ((float4*)&xs[r][0])[k4] = val;
    }
    __syncthreads();
    int j = pass * HCF_ + tid;
    const float* w1p = W1 + (size_t)n * F_ * H_ + j;
    float bias = b1[n * H_ + j];
    float acc[25];
    #pragma unroll
    for (int r = 0; r < 25; ++r) acc[r] = bias;
    const float4* xsv = (const float4*)&xs[0][0];
    for (int k4 = 0; k4 < F_/4; ++k4) {
        float w0 = w1p[(size_t)(4*k4+0) * H_];
        float w1v = w1p[(size_t)(4*k4+1) * H_];
        float w2v = w1p[(size_t)(4*k4+2) * H_];
        float w3v = w1p[(size_t)(4*k4+3) * H_];
        #pragma unroll
        for (int r = 0; r < 25; ++r) {
            float4 xv = xsv[r * (F_/4) + k4];
            acc[r] += xv.x*w0 + xv.y*w1v + xv.z*w2v + xv.w*w3v;
        }
    }
    __hip_bfloat16* hp = h + ((size_t)bn * CAP_ + r0) * HCF_ + tid;
    #pragma unroll
    for (int r = 0; r < 25; ++r) {
        int gr = r0 + r;
        if (gr < CAP_) hp[(size_t)r * HCF_] = __float2bfloat16(fmaxf(acc[r], 0.f));
    }
}

__global__ __launch_bounds__(768) void k_fc2(
        const float* __restrict__ W2, const float* __restrict__ b2,
        const int* __restrict__ toks, const float* __restrict__ wts,
        const int* __restrict__ counts, const __hip_bfloat16* __restrict__ h,
        float* __restrict__ out, int pass) {
    __shared__ float hs[CAP_][HCF_];
    int tid = threadIdx.x;
    int bn = blockIdx.x;
    int c = counts[bn];
    if (c == 0) return;
    int b = bn >> 3, n = bn & 7;
    const ushort4* hv = (const ushort4*)(h + (size_t)bn * CAP_ * HCF_);
    for (int idx = tid; idx < CAP_ * (HCF_/4); idx += 768) {
        ushort4 u = hv[idx];
        float4 fv;
        fv.x = __bfloat162float(*(const __hip_bfloat16*)&u.x);
        fv.y = __bfloat162float(*(const __hip_bfloat16*)&u.y);
        fv.z = __bfloat162float(*(const __hip_bfloat16*)&u.z);
        fv.w = __bfloat162float(*(const __hip_bfloat16*)&u.w);
        ((float4*)&hs[0][0])[idx] = fv;
    }
    __syncthreads();
    int f = tid;
    const float* w2p = W2 + (size_t)n * H_ * F_ + (size_t)(pass * HCF_) * F_ + f;
    float acc[CAP_];
    #pragma unroll
    for (int r = 0; r < CAP_; ++r) acc[r] = 0.f;
    for (int j4 = 0; j4 < HCF_/4; ++j4) {
        float w0 = w2p[(size_t)(4*j4+0) * F_];
        float w1v = w2p[(size_t)(4*j4+1) * F_];
        float w2v = w2p[(size_t)(4*j4+2) * F_];
        float w3v = w2p[(size_t)(4*j4+3) * F_];
        #pragma unroll
        for (int r = 0; r < CAP_; ++r) {
            float4 hh = ((const float4*)&hs[r][0])[j4];
            acc[r] += hh.x*w0 + hh.y*w1v + hh.z*w2v + hh.w*w3v;
        }
    }
    float bias = (pass == 0) ? b2[n * F_ + f] : 0.f;
    #pragma unroll
    for (int r = 0; r < CAP_; ++r) {
        if (r < c) {
            int t = toks[bn * CAP_ + r];
            float fw = wts[bn * CAP_ + r];
            atomicAdd(&out[((size_t)(t * B_ + b)) * F_ + f], fw * (acc[r] + bias));
        }
    }
}

extern "C" void kernel_launch(void* const* d_in, const int* in_sizes, int n_in,
                              void* d_out, int out_size, void* d_ws, size_t ws_size,
                              hipStream_t stream) {
    const float* x   = (const float*)d_in[0];
    const float* Wg1 = (const float*)d_in[1];
    const float* bg1 = (const float*)d_in[2];
    const float* Wg2 = (const float*)d_in[3];
    const float* bg2 = (const float*)d_in[4];
    const float* W1  = (const float*)d_in[5];
    const float* b1  = (const float*)d_in[6];
    const float* W2  = (const float*)d_in[7];
    const float* b2  = (const float*)d_in[8];
    float* out = (float*)d_out;

    // MFMA-path ws layout (~155 MB)
    size_t oW1T = 0;
    size_t oW2T = oW1T + (size_t)N_ * H_ * F_ * 2;
    size_t oXg  = oW2T + (size_t)N_ * H_ * F_ * 2;
    size_t oHg  = oXg  + (size_t)MT_ * F_ * 2;
    size_t oCw  = oHg  + (size_t)MT_ * HC_ * 2;
    size_t oWts = oCw  + (size_t)NBN_ * T_ * 4;
    size_t oTok = oWts + (size_t)NBN_ * CAP_ * 4;
    size_t oCnt = oTok + (size_t)NBN_ * CAP_ * 4;
    size_t need = oCnt + (size_t)NBN_ * 4;

    k_init_out<<<(TB_ * F_) / 1024, 256, 0, stream>>>(x, out);

    if (ws_size >= need) {
        unsigned short* W1T = (unsigned short*)((char*)d_ws + oW1T);
        unsigned short* W2T = (unsigned short*)((char*)d_ws + oW2T);
        unsigned short* Xg  = (unsigned short*)((char*)d_ws + oXg);
        unsigned short* Hg  = (unsigned short*)((char*)d_ws + oHg);
        float* cw   = (float*)((char*)d_ws + oCw);
        float* wts  = (float*)((char*)d_ws + oWts);
        int* toks   = (int*)((char*)d_ws + oTok);
        int* counts = (int*)((char*)d_ws + oCnt);

        k_gate<<<TB_ / 8, 256, 0, stream>>>(x, Wg1, bg1, Wg2, bg2, cw);
        k_capacity<<<NBN_, 256, 0, stream>>>(cw, toks, wts, counts);
        k_repack<<<N_ * (H_/256) * (F_/256), 256, 0, stream>>>(W1, W1T, F_, H_);  // [8][768][3072]->[8][3072][768]
        k_repack<<<N_ * (F_/256) * (H_/256), 256, 0, stream>>>(W2, W2T, H_, F_);  // [8][3072][768]->[8][768][3072]
        k_gather<<<(MT_ * 96) / 256, 256, 0, stream>>>(x, toks, counts, Xg);
        for (int p = 0; p < NP_; ++p) {
            k_gemm1<<<1200, 256, 0, stream>>>(W1T, Xg, b1, Hg, p);
            k_gemm2<<<1200, 256, 0, stream>>>(W2T, Hg, b2, toks, wts, counts, out, p);
        }
    } else {
        // round-1 fallback (~20 MB ws)
        __hip_bfloat16* h = (__hip_bfloat16*)d_ws;
        float* cw  = (float*)((char*)d_ws + (size_t)NBN_ * CAP_ * HCF_ * 2);
        float* wts = cw + (size_t)NBN_ * T_;
        int* toks  = (int*)(wts + NBN_ * CAP_);
        int* counts = toks + NBN_ * CAP_;
        k_gate<<<TB_ / 8, 256, 0, stream>>>(x, Wg1, bg1, Wg2, bg2, cw);
        k_capacity<<<NBN_, 256, 0, stream>>>(cw, toks, wts, counts);
        for (int p = 0; p < NPF_; ++p) {
            k_fc1<<<NBN_ * 2, HCF_, 0, stream>>>(x, W1, b1, toks, counts, h, p);
            k_fc2<<<NBN_, 768, 0, stream>>>(W2, b2, toks, wts, counts, h, out, p);
        }
    }
}

// Round 3
// 804.099 us; speedup vs baseline: 7.7211x; 1.5906x over previous
//
#include <hip/hip_runtime.h>
#include <hip/hip_bf16.h>
#include <math.h>
#include <stdint.h>

#define T_ 197
#define B_ 64
#define F_ 768
#define N_ 8
#define CAP_ 49
#define H_ 3072
#define G_ 192
#define TB_ (T_*B_)       // 12608
#define NBN_ (B_*N_)      // 512
#define ME_ 3200          // padded rows per expert (25 * 128)
#define MR_ 3136          // real rows per expert (64 * 49)
#define MT_ 25600         // total padded rows
#define HCF_ 384          // fallback (round-1) H chunk
#define NPF_ 8

using bf16x8 = __attribute__((ext_vector_type(8))) short;
using f32x4  = __attribute__((ext_vector_type(4))) float;

__device__ __forceinline__ unsigned short f2bf(float v) {
    __hip_bfloat16 h = __float2bfloat16(v);
    return __builtin_bit_cast(unsigned short, h);
}

// async global->LDS, 16B per lane; LDS dest = wave-uniform base + lane*16
#define GLL16(g, l) __builtin_amdgcn_global_load_lds( \
    (const __attribute__((address_space(1))) unsigned int*)(uintptr_t)(g), \
    (__attribute__((address_space(3))) unsigned int*)(uintptr_t)(l), 16, 0, 0)

// m204 bijective XCD swizzle
__device__ __forceinline__ int xcd_swz(int bid, int nblk) {
    int q = nblk >> 3, r = nblk & 7;
    int xcd = bid & 7, idx = bid >> 3;
    int base = (xcd < r) ? xcd * (q + 1) : r * (q + 1) + (xcd - r) * q;
    return base + idx;
}

// ---------------- out = -x ----------------
__global__ void k_init_out(const float* __restrict__ x, float* __restrict__ out) {
    int i = blockIdx.x * blockDim.x + threadIdx.x;
    const float4* xv = (const float4*)x;
    float4* ov = (float4*)out;
    float4 v = xv[i];
    ov[i] = make_float4(-v.x, -v.y, -v.z, -v.w);
}

// ---------------- gate: 8 tokens per block (fp32 exact -> exact top-k) ----------------
__global__ __launch_bounds__(256) void k_gate(
        const float* __restrict__ x, const float* __restrict__ Wg1,
        const float* __restrict__ bg1, const float* __restrict__ Wg2,
        const float* __restrict__ bg2, float* __restrict__ cw) {
    __shared__ float xsh[8][F_];
    __shared__ float gs[8][G_];
    __shared__ float lg[8][N_];
    int tid = threadIdx.x;
    int id0 = blockIdx.x * 8;

    const float4* xv = (const float4*)(x + (size_t)id0 * F_);
    float4* xshv = (float4*)&xsh[0][0];
    for (int idx = tid; idx < 8 * (F_/4); idx += 256) xshv[idx] = xv[idx];
    __syncthreads();

    if (tid < G_) {
        float acc[8];
        float bb = bg1[tid];
        #pragma unroll
        for (int tk = 0; tk < 8; ++tk) acc[tk] = bb;
        for (int k = 0; k < F_; ++k) {
            float w = Wg1[k * G_ + tid];
            #pragma unroll
            for (int tk = 0; tk < 8; ++tk) acc[tk] += xsh[tk][k] * w;
        }
        #pragma unroll
        for (int tk = 0; tk < 8; ++tk) gs[tk][tid] = fmaxf(acc[tk], 0.f);
    }
    __syncthreads();

    if (tid < 64) {
        int tk = tid >> 3, n = tid & 7;
        float acc = bg2[n];
        for (int k = 0; k < G_; ++k) acc += gs[tk][k] * Wg2[k * N_ + n];
        lg[tk][n] = acc;
    }
    __syncthreads();

    if (tid < 8) {
        int tk = tid;
        float p[8];
        float m = lg[tk][0];
        #pragma unroll
        for (int n = 1; n < 8; ++n) m = fmaxf(m, lg[tk][n]);
        float s = 0.f;
        #pragma unroll
        for (int n = 0; n < 8; ++n) { p[n] = expf(lg[tk][n] - m); s += p[n]; }
        float inv = 1.f / s;
        #pragma unroll
        for (int n = 0; n < 8; ++n) p[n] *= inv;
        int i1 = 0; float v1 = p[0];
        #pragma unroll
        for (int n = 1; n < 8; ++n) if (p[n] > v1) { v1 = p[n]; i1 = n; }
        int i2 = -1; float v2 = -1.f;
        #pragma unroll
        for (int n = 0; n < 8; ++n) if (n != i1 && p[n] > v2) { v2 = p[n]; i2 = n; }
        int id = id0 + tk;
        int t = id / B_, b = id % B_;
        #pragma unroll
        for (int n = 0; n < 8; ++n) {
            float v = (n == i1 || n == i2) ? p[n] : 0.f;
            cw[((size_t)(b * N_ + n)) * T_ + t] = v;
        }
    }
}

// ---------------- capacity: exact top-CAP rank per (b,n) ----------------
__global__ __launch_bounds__(256) void k_capacity(
        const float* __restrict__ cw, int* __restrict__ toks,
        float* __restrict__ wts, int* __restrict__ counts) {
    __shared__ float v[T_];
    __shared__ int keep[T_];
    int tid = threadIdx.x;
    int bn = blockIdx.x;
    if (tid < T_) v[tid] = cw[(size_t)bn * T_ + tid];
    __syncthreads();
    int kp = 0; float my = 0.f;
    if (tid < T_) {
        my = v[tid];
        int rank = 0;
        for (int t2 = 0; t2 < T_; ++t2) {
            float vt = v[t2];
            rank += (vt > my) || (vt == my && t2 < tid);
        }
        kp = (rank < CAP_) && (my > 0.f);
    }
    if (tid < T_) keep[tid] = kp;
    __syncthreads();
    if (tid < T_ && kp) {
        int slot = 0;
        for (int t2 = 0; t2 < T_; ++t2) slot += (t2 < tid) ? keep[t2] : 0;
        toks[bn * CAP_ + slot] = tid;
        wts[bn * CAP_ + slot] = my;
    }
    if (tid == 0) {
        int tot = 0;
        for (int t2 = 0; t2 < T_; ++t2) tot += keep[t2];
        counts[bn] = tot;
    }
}

// ---------------- repack W [E][K][J] fp32 -> WT [E][J][K] bf16, pre-swizzled ----------------
// swizzle: within each 128B k-group of a row j, 16B slot s -> s ^ (j&7)
__global__ __launch_bounds__(256) void k_repack(
        const float* __restrict__ W, unsigned short* __restrict__ WT, int K, int J) {
    int bid = blockIdx.x;
    int nk = K >> 8, nj = J >> 8;
    int kt = bid % nk; bid /= nk;
    int jt = bid % nj; int e = bid / nj;
    int j = jt * 256 + threadIdx.x;
    const float* src = W + ((size_t)e * K + (size_t)kt * 256) * J + j;
    char* drow = (char*)WT + ((size_t)e * J + j) * (size_t)K * 2 + (size_t)kt * 512;
    int swz = (j & 7) << 4;
    for (int c = 0; c < 32; ++c) {
        float f[8];
        #pragma unroll
        for (int s = 0; s < 8; ++s) f[s] = src[(size_t)(c * 8 + s) * J];
        uint4 u;
        u.x = f2bf(f[0]) | ((unsigned)f2bf(f[1]) << 16);
        u.y = f2bf(f[2]) | ((unsigned)f2bf(f[3]) << 16);
        u.z = f2bf(f[4]) | ((unsigned)f2bf(f[5]) << 16);
        u.w = f2bf(f[6]) | ((unsigned)f2bf(f[7]) << 16);
        *(uint4*)(drow + (c >> 3) * 128 + (((c & 7) * 16) ^ swz)) = u;
    }
}

// ---------------- gather x rows -> Xg [MT_][768] bf16, pre-swizzled, zero-padded ----------------
__global__ __launch_bounds__(256) void k_gather(
        const float* __restrict__ x, const int* __restrict__ toks,
        const int* __restrict__ counts, unsigned short* __restrict__ Xg) {
    int gi = blockIdx.x * 256 + threadIdx.x;     // MT_*96 total
    int R = gi / 96, c = gi - R * 96;            // c: 16B chunk (8 bf16)
    int e = R / ME_, re = R - e * ME_;
    uint4 val = make_uint4(0u, 0u, 0u, 0u);
    if (re < MR_) {
        int g = re / CAP_, slot = re - g * CAP_;
        int bn = g * N_ + e;
        if (slot < counts[bn]) {
            int t = toks[bn * CAP_ + slot];
            const float* xp = x + ((size_t)t * B_ + g) * F_ + c * 8;
            float4 v0 = *(const float4*)xp;
            float4 v1 = *(const float4*)(xp + 4);
            val.x = f2bf(v0.x) | ((unsigned)f2bf(v0.y) << 16);
            val.y = f2bf(v0.z) | ((unsigned)f2bf(v0.w) << 16);
            val.z = f2bf(v1.x) | ((unsigned)f2bf(v1.y) << 16);
            val.w = f2bf(v1.z) | ((unsigned)f2bf(v1.w) << 16);
        }
    }
    int w = (c * 16) & 127;
    char* dst = (char*)Xg + (size_t)R * 1536 + (c >> 3) * 128 + (w ^ ((R & 7) << 4));
    *(uint4*)dst = val;
}

// ---------------- GEMM1 (merged): Hg = relu(W1T . Xg^T + b1), full H per dispatch ----------------
// grid = grp*25 mt-tiles * 24 jt-tiles; jt-inner for Xg L2 reuse
__global__ __launch_bounds__(256) void k_gemm1(
        const unsigned short* __restrict__ W1T, const unsigned short* __restrict__ Xg,
        const float* __restrict__ b1, unsigned short* __restrict__ Hg,
        int e0, int nblk) {
    __shared__ char ldsA[16384];
    __shared__ char ldsB[16384];
    int swzb = xcd_swz(blockIdx.x, nblk);
    int mt = swzb / 24;                           // group-local row tile
    int jt = swzb % 24;                           // 128-col tile of H
    int em = mt / 25;
    int e = e0 + em;
    int tid = threadIdx.x, lane = tid & 63, wid = tid >> 6;
    int lr8 = lane >> 3, sl = (lane & 7) << 4;
    const char* Ab = (const char*)W1T + ((size_t)e * H_ + (size_t)jt * 128) * (F_ * 2);
    const char* Bb = (const char*)Xg + ((size_t)e * ME_ + (size_t)(mt % 25) * 128) * (F_ * 2);
    f32x4 acc[4][4] = {};
    int swz = (lane & 7) << 4;
    int q16 = (lane >> 4) << 4;
    const char* la = ldsA + ((wid & 1) * 64) * 128;
    const char* lb = ldsB + ((wid >> 1) * 64) * 128;

    for (int it = 0; it < 12; ++it) {
        int kb = it << 7;
        #pragma unroll
        for (int i = 0; i < 4; ++i) {
            int lr = wid * 32 + i * 8 + lr8;
            GLL16(Ab + (size_t)lr * 1536 + kb + sl, ldsA + (wid * 32 + i * 8) * 128);
            GLL16(Bb + (size_t)lr * 1536 + kb + sl, ldsB + (wid * 32 + i * 8) * 128);
        }
        __syncthreads();
        #pragma unroll
        for (int ks = 0; ks < 2; ++ks) {
            bf16x8 af[4], bfr[4];
            int kk = (ks * 64 + q16) ^ swz;
            #pragma unroll
            for (int t = 0; t < 4; ++t) {
                int ro = (16 * t + (lane & 15)) * 128;
                af[t]  = *(const bf16x8*)(la + ro + kk);
                bfr[t] = *(const bf16x8*)(lb + ro + kk);
            }
            #pragma unroll
            for (int ti = 0; ti < 4; ++ti)
                #pragma unroll
                for (int tm = 0; tm < 4; ++tm)
                    acc[ti][tm] = __builtin_amdgcn_mfma_f32_16x16x32_bf16(af[ti], bfr[tm], acc[ti][tm], 0, 0, 0);
        }
        __syncthreads();
    }
    // epilogue: bias+relu -> bf16, swizzled 8B stores into Hg [grp*3200][3072]
    int jl0 = jt * 128 + (wid & 1) * 64;
    int ml0 = mt * 128 + (wid >> 1) * 64;         // group-local Hg row
    const float* b1p = b1 + (size_t)e * H_;
    #pragma unroll
    for (int tj = 0; tj < 4; ++tj) {
        int jc = jl0 + 16 * tj + ((lane >> 4) << 2);
        float bb0 = b1p[jc], bb1 = b1p[jc + 1], bb2 = b1p[jc + 2], bb3 = b1p[jc + 3];
        #pragma unroll
        for (int tm = 0; tm < 4; ++tm) {
            int m = ml0 + 16 * tm + (lane & 15);
            f32x4 a = acc[tj][tm];
            unsigned int u0 = f2bf(fmaxf(a[0] + bb0, 0.f)) | ((unsigned)f2bf(fmaxf(a[1] + bb1, 0.f)) << 16);
            unsigned int u1 = f2bf(fmaxf(a[2] + bb2, 0.f)) | ((unsigned)f2bf(fmaxf(a[3] + bb3, 0.f)) << 16);
            int w = (jc * 2) & 127;
            char* dst = (char*)Hg + (size_t)m * (H_ * 2) + ((jc * 2) & ~127) + (w ^ ((m & 7) << 4));
            *(uint2*)dst = make_uint2(u0, u1);
        }
    }
}

// ---------------- GEMM2 (merged): out += fw * (W2T . Hg^T + b2), K=3072 in one dispatch ----------------
// grid = grp*25 mt-tiles * 6 ft-tiles; ft-inner for Hg L2 reuse
__global__ __launch_bounds__(256) void k_gemm2(
        const unsigned short* __restrict__ W2T, const unsigned short* __restrict__ Hg,
        const float* __restrict__ b2, const int* __restrict__ toks,
        const float* __restrict__ wts, const int* __restrict__ counts,
        float* __restrict__ out, int e0, int nblk) {
    __shared__ char ldsA[16384];
    __shared__ char ldsB[16384];
    int swzb = xcd_swz(blockIdx.x, nblk);
    int mt = swzb / 6;                            // group-local row tile
    int ft = swzb % 6;                            // 128-col tile of F
    int em = mt / 25;
    int e = e0 + em;
    int tid = threadIdx.x, lane = tid & 63, wid = tid >> 6;
    int lr8 = lane >> 3, sl = (lane & 7) << 4;
    const char* Ab = (const char*)W2T + ((size_t)e * F_ + (size_t)ft * 128) * (H_ * 2);
    const char* Bb = (const char*)Hg + (size_t)mt * 128 * (H_ * 2);
    f32x4 acc[4][4] = {};
    int swz = (lane & 7) << 4;
    int q16 = (lane >> 4) << 4;
    const char* la = ldsA + ((wid & 1) * 64) * 128;
    const char* lb = ldsB + ((wid >> 1) * 64) * 128;

    for (int it = 0; it < 48; ++it) {
        int kb = it << 7;
        #pragma unroll
        for (int i = 0; i < 4; ++i) {
            int lr = wid * 32 + i * 8 + lr8;
            GLL16(Ab + (size_t)lr * 6144 + kb + sl, ldsA + (wid * 32 + i * 8) * 128);
            GLL16(Bb + (size_t)lr * 6144 + kb + sl, ldsB + (wid * 32 + i * 8) * 128);
        }
        __syncthreads();
        #pragma unroll
        for (int ks = 0; ks < 2; ++ks) {
            bf16x8 af[4], bfr[4];
            int kk = (ks * 64 + q16) ^ swz;
            #pragma unroll
            for (int t = 0; t < 4; ++t) {
                int ro = (16 * t + (lane & 15)) * 128;
                af[t]  = *(const bf16x8*)(la + ro + kk);
                bfr[t] = *(const bf16x8*)(lb + ro + kk);
            }
            #pragma unroll
            for (int ti = 0; ti < 4; ++ti)
                #pragma unroll
                for (int tm = 0; tm < 4; ++tm)
                    acc[ti][tm] = __builtin_amdgcn_mfma_f32_16x16x32_bf16(af[ti], bfr[tm], acc[ti][tm], 0, 0, 0);
        }
        __syncthreads();
    }
    // epilogue: atomic scatter, one update per (token-slot, f) total
    int fl0 = ft * 128 + (wid & 1) * 64;
    int ml0 = mt * 128 + (wid >> 1) * 64;
    const float* b2p = b2 + (size_t)e * F_;
    int trow[4]; int gb[4]; float fwv[4];
    #pragma unroll
    for (int tm = 0; tm < 4; ++tm) {
        int m = ml0 + 16 * tm + (lane & 15);      // group-local
        int re = m - em * ME_;                    // expert-local
        int t = -1, g = 0; float fw = 0.f;
        if (re < MR_) {
            g = re / CAP_;
            int slot = re - g * CAP_;
            int bn = g * N_ + e;
            if (slot < counts[bn]) { t = toks[bn * CAP_ + slot]; fw = wts[bn * CAP_ + slot]; }
        }
        trow[tm] = t; gb[tm] = g; fwv[tm] = fw;
    }
    #pragma unroll
    for (int tf = 0; tf < 4; ++tf) {
        int f = fl0 + 16 * tf + ((lane >> 4) << 2);
        float c0 = b2p[f], c1 = b2p[f + 1], c2 = b2p[f + 2], c3 = b2p[f + 3];
        #pragma unroll
        for (int tm = 0; tm < 4; ++tm) {
            if (trow[tm] >= 0) {
                float* op = out + ((size_t)trow[tm] * B_ + gb[tm]) * F_ + f;
                f32x4 a = acc[tf][tm];
                float fw = fwv[tm];
                atomicAdd(op + 0, fw * (a[0] + c0));
                atomicAdd(op + 1, fw * (a[1] + c1));
                atomicAdd(op + 2, fw * (a[2] + c2));
                atomicAdd(op + 3, fw * (a[3] + c3));
            }
        }
    }
}

// ================= round-1 fallback kernels (used only if ws_size is tiny) =================
__global__ __launch_bounds__(HCF_) void k_fc1(
        const float* __restrict__ x, const float* __restrict__ W1,
        const float* __restrict__ b1, const int* __restrict__ toks,
        const int* __restrict__ counts, __hip_bfloat16* __restrict__ h, int pass) {
    __shared__ float xs[25][F_];
    int tid = threadIdx.x;
    int bn = blockIdx.x >> 1;
    int half = blockIdx.x & 1;
    int r0 = half * 25;
    int b = bn >> 3, n = bn & 7;
    int c = counts[bn];
    for (int idx = tid; idx < 25 * (F_/4); idx += HCF_) {
        int r = idx / (F_/4), k4 = idx % (F_/4);
        int gr = r0 + r;
        float4 val = make_float4(0.f, 0.f, 0.f, 0.f);
        if (gr < c) {
            int t = toks[bn * CAP_ + gr];
            val = ((const float4*)(x + ((size_t)(t * B_ + b)) * F_))[k4];
        }
        ((float4*)&xs[r][0])[k4] = val;
    }
    __syncthreads();
    int j = pass * HCF_ + tid;
    const float* w1p = W1 + (size_t)n * F_ * H_ + j;
    float bias = b1[n * H_ + j];
    float acc[25];
    #pragma unroll
    for (int r = 0; r < 25; ++r) acc[r] = bias;
    const float4* xsv = (const float4*)&xs[0][0];
    for (int k4 = 0; k4 < F_/4; ++k4) {
        float w0 = w1p[(size_t)(4*k4+0) * H_];
        float w1v = w1p[(size_t)(4*k4+1) * H_];
        float w2v = w1p[(size_t)(4*k4+2) * H_];
        float w3v = w1p[(size_t)(4*k4+3) * H_];
        #pragma unroll
        for (int r = 0; r < 25; ++r) {
            float4 xv = xsv[r * (F_/4) + k4];
            acc[r] += xv.x*w0 + xv.y*w1v + xv.z*w2v + xv.w*w3v;
        }
    }
    __hip_bfloat16* hp = h + ((size_t)bn * CAP_ + r0) * HCF_ + tid;
    #pragma unroll
    for (int r = 0; r < 25; ++r) {
        int gr = r0 + r;
        if (gr < CAP_) hp[(size_t)r * HCF_] = __float2bfloat16(fmaxf(acc[r], 0.f));
    }
}

__global__ __launch_bounds__(768) void k_fc2(
        const float* __restrict__ W2, const float* __restrict__ b2,
        const int* __restrict__ toks, const float* __restrict__ wts,
        const int* __restrict__ counts, const __hip_bfloat16* __restrict__ h,
        float* __restrict__ out, int pass) {
    __shared__ float hs[CAP_][HCF_];
    int tid = threadIdx.x;
    int bn = blockIdx.x;
    int c = counts[bn];
    if (c == 0) return;
    int b = bn >> 3, n = bn & 7;
    const ushort4* hv = (const ushort4*)(h + (size_t)bn * CAP_ * HCF_);
    for (int idx = tid; idx < CAP_ * (HCF_/4); idx += 768) {
        ushort4 u = hv[idx];
        float4 fv;
        fv.x = __bfloat162float(*(const __hip_bfloat16*)&u.x);
        fv.y = __bfloat162float(*(const __hip_bfloat16*)&u.y);
        fv.z = __bfloat162float(*(const __hip_bfloat16*)&u.z);
        fv.w = __bfloat162float(*(const __hip_bfloat16*)&u.w);
        ((float4*)&hs[0][0])[idx] = fv;
    }
    __syncthreads();
    int f = tid;
    const float* w2p = W2 + (size_t)n * H_ * F_ + (size_t)(pass * HCF_) * F_ + f;
    float acc[CAP_];
    #pragma unroll
    for (int r = 0; r < CAP_; ++r) acc[r] = 0.f;
    for (int j4 = 0; j4 < HCF_/4; ++j4) {
        float w0 = w2p[(size_t)(4*j4+0) * F_];
        float w1v = w2p[(size_t)(4*j4+1) * F_];
        float w2v = w2p[(size_t)(4*j4+2) * F_];
        float w3v = w2p[(size_t)(4*j4+3) * F_];
        #pragma unroll
        for (int r = 0; r < CAP_; ++r) {
            float4 hh = ((const float4*)&hs[r][0])[j4];
            acc[r] += hh.x*w0 + hh.y*w1v + hh.z*w2v + hh.w*w3v;
        }
    }
    float bias = (pass == 0) ? b2[n * F_ + f] : 0.f;
    #pragma unroll
    for (int r = 0; r < CAP_; ++r) {
        if (r < c) {
            int t = toks[bn * CAP_ + r];
            float fw = wts[bn * CAP_ + r];
            atomicAdd(&out[((size_t)(t * B_ + b)) * F_ + f], fw * (acc[r] + bias));
        }
    }
}

extern "C" void kernel_launch(void* const* d_in, const int* in_sizes, int n_in,
                              void* d_out, int out_size, void* d_ws, size_t ws_size,
                              hipStream_t stream) {
    const float* x   = (const float*)d_in[0];
    const float* Wg1 = (const float*)d_in[1];
    const float* bg1 = (const float*)d_in[2];
    const float* Wg2 = (const float*)d_in[3];
    const float* bg2 = (const float*)d_in[4];
    const float* W1  = (const float*)d_in[5];
    const float* b1  = (const float*)d_in[6];
    const float* W2  = (const float*)d_in[7];
    const float* b2  = (const float*)d_in[8];
    float* out = (float*)d_out;

    // fixed ws layout (small arrays before variable-size Hg)
    size_t oW1T = 0;
    size_t oW2T = oW1T + (size_t)N_ * H_ * F_ * 2;          // 37,748,736
    size_t oXg  = oW2T + (size_t)N_ * H_ * F_ * 2;
    size_t oCw  = oXg  + (size_t)MT_ * F_ * 2;
    size_t oWts = oCw  + (size_t)NBN_ * T_ * 4;
    size_t oTok = oWts + (size_t)NBN_ * CAP_ * 4;
    size_t oCnt = oTok + (size_t)NBN_ * CAP_ * 4;
    size_t oHg  = oCnt + (size_t)NBN_ * 4;                  // 115,425,280
    size_t hgPerExpert = (size_t)ME_ * H_ * 2;              // 19,660,800

    int grp = 0;
    if (ws_size >= oHg + 8 * hgPerExpert) grp = 8;
    else if (ws_size >= oHg + 4 * hgPerExpert) grp = 4;
    else if (ws_size >= oHg + 2 * hgPerExpert) grp = 2;

    k_init_out<<<(TB_ * F_) / 1024, 256, 0, stream>>>(x, out);

    if (grp > 0) {
        unsigned short* W1T = (unsigned short*)((char*)d_ws + oW1T);
        unsigned short* W2T = (unsigned short*)((char*)d_ws + oW2T);
        unsigned short* Xg  = (unsigned short*)((char*)d_ws + oXg);
        unsigned short* Hg  = (unsigned short*)((char*)d_ws + oHg);
        float* cw   = (float*)((char*)d_ws + oCw);
        float* wts  = (float*)((char*)d_ws + oWts);
        int* toks   = (int*)((char*)d_ws + oTok);
        int* counts = (int*)((char*)d_ws + oCnt);

        k_gate<<<TB_ / 8, 256, 0, stream>>>(x, Wg1, bg1, Wg2, bg2, cw);
        k_capacity<<<NBN_, 256, 0, stream>>>(cw, toks, wts, counts);
        k_repack<<<N_ * (H_/256) * (F_/256), 256, 0, stream>>>(W1, W1T, F_, H_);
        k_repack<<<N_ * (F_/256) * (H_/256), 256, 0, stream>>>(W2, W2T, H_, F_);
        k_gather<<<(MT_ * 96) / 256, 256, 0, stream>>>(x, toks, counts, Xg);
        for (int e0 = 0; e0 < N_; e0 += grp) {
            int nblk1 = grp * 25 * 24;
            int nblk2 = grp * 25 * 6;
            k_gemm1<<<nblk1, 256, 0, stream>>>(W1T, Xg, b1, Hg, e0, nblk1);
            k_gemm2<<<nblk2, 256, 0, stream>>>(W2T, Hg, b2, toks, wts, counts, out, e0, nblk2);
        }
    } else {
        // round-1 fallback (~20 MB ws)
        __hip_bfloat16* h = (__hip_bfloat16*)d_ws;
        float* cw  = (float*)((char*)d_ws + (size_t)NBN_ * CAP_ * HCF_ * 2);
        float* wts = cw + (size_t)NBN_ * T_;
        int* toks  = (int*)(wts + NBN_ * CAP_);
        int* counts = toks + NBN_ * CAP_;
        k_gate<<<TB_ / 8, 256, 0, stream>>>(x, Wg1, bg1, Wg2, bg2, cw);
        k_capacity<<<NBN_, 256, 0, stream>>>(cw, toks, wts, counts);
        for (int p = 0; p < NPF_; ++p) {
            k_fc1<<<NBN_ * 2, HCF_, 0, stream>>>(x, W1, b1, toks, counts, h, p);
            k_fc2<<<NBN_, 768, 0, stream>>>(W2, b2, toks, wts, counts, h, out, p);
        }
    }
}

// Round 4
// 613.684 us; speedup vs baseline: 10.1168x; 1.3103x over previous
//
#include <hip/hip_runtime.h>
#include <hip/hip_bf16.h>
#include <math.h>
#include <stdint.h>

#define T_ 197
#define B_ 64
#define F_ 768
#define N_ 8
#define CAP_ 49
#define H_ 3072
#define G_ 192
#define TB_ (T_*B_)       // 12608
#define NBN_ (B_*N_)      // 512
#define ME_ 3200          // padded rows per expert (25 * 128)
#define MR_ 3136          // real rows per expert (64 * 49)
#define MT_ 25600         // total padded rows
#define HCF_ 384          // fallback (round-1) H chunk
#define NPF_ 8

using bf16x8 = __attribute__((ext_vector_type(8))) short;
using f32x4  = __attribute__((ext_vector_type(4))) float;

__device__ __forceinline__ unsigned short f2bf(float v) {
    __hip_bfloat16 h = __float2bfloat16(v);
    return __builtin_bit_cast(unsigned short, h);
}
__device__ __forceinline__ float bf2f(unsigned short u) {
    unsigned int w = ((unsigned int)u) << 16;
    return __builtin_bit_cast(float, w);
}

// async global->LDS, 16B per lane; LDS dest = wave-uniform base + lane*16
#define GLL16(g, l) __builtin_amdgcn_global_load_lds( \
    (const __attribute__((address_space(1))) unsigned int*)(uintptr_t)(g), \
    (__attribute__((address_space(3))) unsigned int*)(uintptr_t)(l), 16, 0, 0)

// m204 bijective XCD swizzle
__device__ __forceinline__ int xcd_swz(int bid, int nblk) {
    int q = nblk >> 3, r = nblk & 7;
    int xcd = bid & 7, idx = bid >> 3;
    int base = (xcd < r) ? xcd * (q + 1) : r * (q + 1) + (xcd - r) * q;
    return base + idx;
}

// ---------------- out = -x (fallback path only) ----------------
__global__ void k_init_out(const float* __restrict__ x, float* __restrict__ out) {
    int i = blockIdx.x * blockDim.x + threadIdx.x;
    const float4* xv = (const float4*)x;
    float4* ov = (float4*)out;
    float4 v = xv[i];
    ov[i] = make_float4(-v.x, -v.y, -v.z, -v.w);
}

// ---------------- gate: 8 tokens per block (fp32 exact -> exact top-k); also zeroes ecnt ----------------
__global__ __launch_bounds__(256) void k_gate(
        const float* __restrict__ x, const float* __restrict__ Wg1,
        const float* __restrict__ bg1, const float* __restrict__ Wg2,
        const float* __restrict__ bg2, float* __restrict__ cw,
        int* __restrict__ ecnt) {
    __shared__ float xsh[8][F_];
    __shared__ float gs[8][G_];
    __shared__ float lg[8][N_];
    int tid = threadIdx.x;
    int id0 = blockIdx.x * 8;

    int gid = blockIdx.x * 256 + tid;
    if (gid < TB_ && ecnt) ecnt[gid] = 0;

    const float4* xv = (const float4*)(x + (size_t)id0 * F_);
    float4* xshv = (float4*)&xsh[0][0];
    for (int idx = tid; idx < 8 * (F_/4); idx += 256) xshv[idx] = xv[idx];
    __syncthreads();

    if (tid < G_) {
        float acc[8];
        float bb = bg1[tid];
        #pragma unroll
        for (int tk = 0; tk < 8; ++tk) acc[tk] = bb;
        for (int k = 0; k < F_; ++k) {
            float w = Wg1[k * G_ + tid];
            #pragma unroll
            for (int tk = 0; tk < 8; ++tk) acc[tk] += xsh[tk][k] * w;
        }
        #pragma unroll
        for (int tk = 0; tk < 8; ++tk) gs[tk][tid] = fmaxf(acc[tk], 0.f);
    }
    __syncthreads();

    if (tid < 64) {
        int tk = tid >> 3, n = tid & 7;
        float acc = bg2[n];
        for (int k = 0; k < G_; ++k) acc += gs[tk][k] * Wg2[k * N_ + n];
        lg[tk][n] = acc;
    }
    __syncthreads();

    if (tid < 8) {
        int tk = tid;
        float p[8];
        float m = lg[tk][0];
        #pragma unroll
        for (int n = 1; n < 8; ++n) m = fmaxf(m, lg[tk][n]);
        float s = 0.f;
        #pragma unroll
        for (int n = 0; n < 8; ++n) { p[n] = expf(lg[tk][n] - m); s += p[n]; }
        float inv = 1.f / s;
        #pragma unroll
        for (int n = 0; n < 8; ++n) p[n] *= inv;
        int i1 = 0; float v1 = p[0];
        #pragma unroll
        for (int n = 1; n < 8; ++n) if (p[n] > v1) { v1 = p[n]; i1 = n; }
        int i2 = -1; float v2 = -1.f;
        #pragma unroll
        for (int n = 0; n < 8; ++n) if (n != i1 && p[n] > v2) { v2 = p[n]; i2 = n; }
        int id = id0 + tk;
        int t = id / B_, b = id % B_;
        #pragma unroll
        for (int n = 0; n < 8; ++n) {
            float v = (n == i1 || n == i2) ? p[n] : 0.f;
            cw[((size_t)(b * N_ + n)) * T_ + t] = v;
        }
    }
}

// ---------------- capacity: exact top-CAP rank per (b,n); builds inverse map ----------------
__global__ __launch_bounds__(256) void k_capacity(
        const float* __restrict__ cw, int* __restrict__ toks,
        float* __restrict__ wts, int* __restrict__ counts,
        int* __restrict__ ecnt, int* __restrict__ erow) {
    __shared__ float v[T_];
    __shared__ int keep[T_];
    int tid = threadIdx.x;
    int bn = blockIdx.x;
    int b = bn >> 3, n = bn & 7;
    if (tid < T_) v[tid] = cw[(size_t)bn * T_ + tid];
    __syncthreads();
    int kp = 0; float my = 0.f;
    if (tid < T_) {
        my = v[tid];
        int rank = 0;
        for (int t2 = 0; t2 < T_; ++t2) {
            float vt = v[t2];
            rank += (vt > my) || (vt == my && t2 < tid);
        }
        kp = (rank < CAP_) && (my > 0.f);
    }
    if (tid < T_) keep[tid] = kp;
    __syncthreads();
    if (tid < T_ && kp) {
        int slot = 0;
        for (int t2 = 0; t2 < T_; ++t2) slot += (t2 < tid) ? keep[t2] : 0;
        toks[bn * CAP_ + slot] = tid;
        wts[bn * CAP_ + slot] = my;
        if (ecnt) {
            int orow = tid * B_ + b;                       // output row (t,b)
            int pos = atomicAdd(&ecnt[orow], 1);          // <= 2 appends; order-free (sum is commutative)
            erow[orow * 2 + pos] = n * ME_ + b * CAP_ + slot;   // Og row
        }
    }
    if (tid == 0) {
        int tot = 0;
        for (int t2 = 0; t2 < T_; ++t2) tot += keep[t2];
        counts[bn] = tot;
    }
}

// ---------------- repack W [E][K][J] fp32 -> WT [E][J][K] bf16, pre-swizzled ----------------
__global__ __launch_bounds__(256) void k_repack(
        const float* __restrict__ W, unsigned short* __restrict__ WT, int K, int J) {
    int bid = blockIdx.x;
    int nk = K >> 8, nj = J >> 8;
    int kt = bid % nk; bid /= nk;
    int jt = bid % nj; int e = bid / nj;
    int j = jt * 256 + threadIdx.x;
    const float* src = W + ((size_t)e * K + (size_t)kt * 256) * J + j;
    char* drow = (char*)WT + ((size_t)e * J + j) * (size_t)K * 2 + (size_t)kt * 512;
    int swz = (j & 7) << 4;
    for (int c = 0; c < 32; ++c) {
        float f[8];
        #pragma unroll
        for (int s = 0; s < 8; ++s) f[s] = src[(size_t)(c * 8 + s) * J];
        uint4 u;
        u.x = f2bf(f[0]) | ((unsigned)f2bf(f[1]) << 16);
        u.y = f2bf(f[2]) | ((unsigned)f2bf(f[3]) << 16);
        u.z = f2bf(f[4]) | ((unsigned)f2bf(f[5]) << 16);
        u.w = f2bf(f[6]) | ((unsigned)f2bf(f[7]) << 16);
        *(uint4*)(drow + (c >> 3) * 128 + (((c & 7) * 16) ^ swz)) = u;
    }
}

// ---------------- gather x rows -> Xg [MT_][768] bf16, pre-swizzled, zero-padded ----------------
__global__ __launch_bounds__(256) void k_gather(
        const float* __restrict__ x, const int* __restrict__ toks,
        const int* __restrict__ counts, unsigned short* __restrict__ Xg) {
    int gi = blockIdx.x * 256 + threadIdx.x;     // MT_*96 total
    int R = gi / 96, c = gi - R * 96;            // c: 16B chunk (8 bf16)
    int e = R / ME_, re = R - e * ME_;
    uint4 val = make_uint4(0u, 0u, 0u, 0u);
    if (re < MR_) {
        int g = re / CAP_, slot = re - g * CAP_;
        int bn = g * N_ + e;
        if (slot < counts[bn]) {
            int t = toks[bn * CAP_ + slot];
            const float* xp = x + ((size_t)t * B_ + g) * F_ + c * 8;
            float4 v0 = *(const float4*)xp;
            float4 v1 = *(const float4*)(xp + 4);
            val.x = f2bf(v0.x) | ((unsigned)f2bf(v0.y) << 16);
            val.y = f2bf(v0.z) | ((unsigned)f2bf(v0.w) << 16);
            val.z = f2bf(v1.x) | ((unsigned)f2bf(v1.y) << 16);
            val.w = f2bf(v1.z) | ((unsigned)f2bf(v1.w) << 16);
        }
    }
    int w = (c * 16) & 127;
    char* dst = (char*)Xg + (size_t)R * 1536 + (c >> 3) * 128 + (w ^ ((R & 7) << 4));
    *(uint4*)dst = val;
}

// ---------------- GEMM1: Hg = relu(W1T . Xg^T + b1), 2-phase dbuf ----------------
__global__ __launch_bounds__(256) void k_gemm1(
        const unsigned short* __restrict__ W1T, const unsigned short* __restrict__ Xg,
        const float* __restrict__ b1, unsigned short* __restrict__ Hg,
        int e0, int nblk) {
    __shared__ char ldsA[2][16384];
    __shared__ char ldsB[2][16384];
    int swzb = xcd_swz(blockIdx.x, nblk);
    int mt = swzb / 24;
    int jt = swzb % 24;
    int em = mt / 25;
    int e = e0 + em;
    int tid = threadIdx.x, lane = tid & 63, wid = tid >> 6;
    int lr8 = lane >> 3, sl = (lane & 7) << 4;
    const char* Ab = (const char*)W1T + ((size_t)e * H_ + (size_t)jt * 128) * (F_ * 2);
    const char* Bb = (const char*)Xg + ((size_t)e * ME_ + (size_t)(mt % 25) * 128) * (F_ * 2);
    f32x4 acc[4][4] = {};
    int swz = (lane & 7) << 4;
    int q16 = (lane >> 4) << 4;

    auto stage = [&](int buf, int it) {
        int kb = it << 7;
        #pragma unroll
        for (int i = 0; i < 4; ++i) {
            int lr = wid * 32 + i * 8 + lr8;
            GLL16(Ab + (size_t)lr * 1536 + kb + sl, ldsA[buf] + (wid * 32 + i * 8) * 128);
            GLL16(Bb + (size_t)lr * 1536 + kb + sl, ldsB[buf] + (wid * 32 + i * 8) * 128);
        }
    };

    stage(0, 0);
    __syncthreads();                              // vmcnt(0) drain + barrier
    int cur = 0;
    for (int it = 0; it < 12; ++it) {
        if (it < 11) stage(cur ^ 1, it + 1);      // prefetch overlaps compute below
        const char* la = ldsA[cur] + ((wid & 1) * 64) * 128;
        const char* lb = ldsB[cur] + ((wid >> 1) * 64) * 128;
        #pragma unroll
        for (int ks = 0; ks < 2; ++ks) {
            bf16x8 af[4], bfr[4];
            int kk = (ks * 64 + q16) ^ swz;
            #pragma unroll
            for (int t = 0; t < 4; ++t) {
                int ro = (16 * t + (lane & 15)) * 128;
                af[t]  = *(const bf16x8*)(la + ro + kk);
                bfr[t] = *(const bf16x8*)(lb + ro + kk);
            }
            #pragma unroll
            for (int ti = 0; ti < 4; ++ti)
                #pragma unroll
                for (int tm = 0; tm < 4; ++tm)
                    acc[ti][tm] = __builtin_amdgcn_mfma_f32_16x16x32_bf16(af[ti], bfr[tm], acc[ti][tm], 0, 0, 0);
        }
        __syncthreads();
        cur ^= 1;
    }
    // epilogue: bias+relu -> bf16, swizzled 8B stores into Hg
    int jl0 = jt * 128 + (wid & 1) * 64;
    int ml0 = mt * 128 + (wid >> 1) * 64;
    const float* b1p = b1 + (size_t)e * H_;
    #pragma unroll
    for (int tj = 0; tj < 4; ++tj) {
        int jc = jl0 + 16 * tj + ((lane >> 4) << 2);
        float bb0 = b1p[jc], bb1 = b1p[jc + 1], bb2 = b1p[jc + 2], bb3 = b1p[jc + 3];
        #pragma unroll
        for (int tm = 0; tm < 4; ++tm) {
            int m = ml0 + 16 * tm + (lane & 15);
            f32x4 a = acc[tj][tm];
            unsigned int u0 = f2bf(fmaxf(a[0] + bb0, 0.f)) | ((unsigned)f2bf(fmaxf(a[1] + bb1, 0.f)) << 16);
            unsigned int u1 = f2bf(fmaxf(a[2] + bb2, 0.f)) | ((unsigned)f2bf(fmaxf(a[3] + bb3, 0.f)) << 16);
            int w = (jc * 2) & 127;
            char* dst = (char*)Hg + (size_t)m * (H_ * 2) + ((jc * 2) & ~127) + (w ^ ((m & 7) << 4));
            *(uint2*)dst = make_uint2(u0, u1);
        }
    }
}

// ---------------- GEMM2: Og = fw * (W2T . Hg^T + b2), 2-phase dbuf, clean stores ----------------
__global__ __launch_bounds__(256) void k_gemm2(
        const unsigned short* __restrict__ W2T, const unsigned short* __restrict__ Hg,
        const float* __restrict__ b2, const float* __restrict__ wts,
        const int* __restrict__ counts, unsigned short* __restrict__ Og,
        int e0, int nblk) {
    __shared__ char ldsA[2][16384];
    __shared__ char ldsB[2][16384];
    int swzb = xcd_swz(blockIdx.x, nblk);
    int mt = swzb / 6;
    int ft = swzb % 6;
    int em = mt / 25;
    int e = e0 + em;
    int tid = threadIdx.x, lane = tid & 63, wid = tid >> 6;
    int lr8 = lane >> 3, sl = (lane & 7) << 4;
    const char* Ab = (const char*)W2T + ((size_t)e * F_ + (size_t)ft * 128) * (H_ * 2);
    const char* Bb = (const char*)Hg + (size_t)mt * 128 * (H_ * 2);
    f32x4 acc[4][4] = {};
    int swz = (lane & 7) << 4;
    int q16 = (lane >> 4) << 4;

    auto stage = [&](int buf, int it) {
        int kb = it << 7;
        #pragma unroll
        for (int i = 0; i < 4; ++i) {
            int lr = wid * 32 + i * 8 + lr8;
            GLL16(Ab + (size_t)lr * 6144 + kb + sl, ldsA[buf] + (wid * 32 + i * 8) * 128);
            GLL16(Bb + (size_t)lr * 6144 + kb + sl, ldsB[buf] + (wid * 32 + i * 8) * 128);
        }
    };

    stage(0, 0);
    __syncthreads();
    int cur = 0;
    for (int it = 0; it < 48; ++it) {
        if (it < 47) stage(cur ^ 1, it + 1);
        const char* la = ldsA[cur] + ((wid & 1) * 64) * 128;
        const char* lb = ldsB[cur] + ((wid >> 1) * 64) * 128;
        #pragma unroll
        for (int ks = 0; ks < 2; ++ks) {
            bf16x8 af[4], bfr[4];
            int kk = (ks * 64 + q16) ^ swz;
            #pragma unroll
            for (int t = 0; t < 4; ++t) {
                int ro = (16 * t + (lane & 15)) * 128;
                af[t]  = *(const bf16x8*)(la + ro + kk);
                bfr[t] = *(const bf16x8*)(lb + ro + kk);
            }
            #pragma unroll
            for (int ti = 0; ti < 4; ++ti)
                #pragma unroll
                for (int tm = 0; tm < 4; ++tm)
                    acc[ti][tm] = __builtin_amdgcn_mfma_f32_16x16x32_bf16(af[ti], bfr[tm], acc[ti][tm], 0, 0, 0);
        }
        __syncthreads();
        cur ^= 1;
    }
    // epilogue: Og[row][f] = fw * (acc + b2), bf16, plain stores (no atomics)
    int fl0 = ft * 128 + (wid & 1) * 64;
    int ml0 = mt * 128 + (wid >> 1) * 64;
    const float* b2p = b2 + (size_t)e * F_;
    float fwv[4]; int mrow[4];
    #pragma unroll
    for (int tm = 0; tm < 4; ++tm) {
        int m = ml0 + 16 * tm + (lane & 15);      // group-local row
        int re = m - em * ME_;                    // expert-local
        float fw = 0.f;
        if (re < MR_) {
            int g = re / CAP_;
            int slot = re - g * CAP_;
            int bn = g * N_ + e;
            if (slot < counts[bn]) fw = wts[bn * CAP_ + slot];
        }
        fwv[tm] = fw;
        mrow[tm] = e0 * ME_ + m;                  // global Og row
    }
    #pragma unroll
    for (int tf = 0; tf < 4; ++tf) {
        int f = fl0 + 16 * tf + ((lane >> 4) << 2);
        float c0 = b2p[f], c1 = b2p[f + 1], c2 = b2p[f + 2], c3 = b2p[f + 3];
        #pragma unroll
        for (int tm = 0; tm < 4; ++tm) {
            f32x4 a = acc[tf][tm];
            float fw = fwv[tm];
            unsigned int u0 = f2bf(fw * (a[0] + c0)) | ((unsigned)f2bf(fw * (a[1] + c1)) << 16);
            unsigned int u1 = f2bf(fw * (a[2] + c2)) | ((unsigned)f2bf(fw * (a[3] + c3)) << 16);
            *(uint2*)((char*)Og + (size_t)mrow[tm] * (F_ * 2) + f * 2) = make_uint2(u0, u1);
        }
    }
}

// ---------------- combine: out[t,b,:] = sum(og entries) - x ----------------
__global__ __launch_bounds__(256) void k_combine(
        const float* __restrict__ x, const unsigned short* __restrict__ Og,
        const int* __restrict__ ecnt, const int* __restrict__ erow,
        float* __restrict__ out) {
    int idx = blockIdx.x * 256 + threadIdx.x;     // TB_*192 float4 units
    int row = idx / 192, c4 = idx - row * 192;
    float4 s = make_float4(0.f, 0.f, 0.f, 0.f);
    int c = ecnt[row];
    if (c > 0) {
        ushort4 u = *(const ushort4*)(Og + (size_t)erow[row * 2] * F_ + c4 * 4);
        s.x += bf2f(u.x); s.y += bf2f(u.y); s.z += bf2f(u.z); s.w += bf2f(u.w);
    }
    if (c > 1) {
        ushort4 u = *(const ushort4*)(Og + (size_t)erow[row * 2 + 1] * F_ + c4 * 4);
        s.x += bf2f(u.x); s.y += bf2f(u.y); s.z += bf2f(u.z); s.w += bf2f(u.w);
    }
    float4 xv = ((const float4*)x)[idx];
    ((float4*)out)[idx] = make_float4(s.x - xv.x, s.y - xv.y, s.z - xv.z, s.w - xv.w);
}

// ================= round-1 fallback kernels (tiny ws only) =================
__global__ __launch_bounds__(HCF_) void k_fc1(
        const float* __restrict__ x, const float* __restrict__ W1,
        const float* __restrict__ b1, const int* __restrict__ toks,
        const int* __restrict__ counts, __hip_bfloat16* __restrict__ h, int pass) {
    __shared__ float xs[25][F_];
    int tid = threadIdx.x;
    int bn = blockIdx.x >> 1;
    int half = blockIdx.x & 1;
    int r0 = half * 25;
    int b = bn >> 3, n = bn & 7;
    int c = counts[bn];
    for (int idx = tid; idx < 25 * (F_/4); idx += HCF_) {
        int r = idx / (F_/4), k4 = idx % (F_/4);
        int gr = r0 + r;
        float4 val = make_float4(0.f, 0.f, 0.f, 0.f);
        if (gr < c) {
            int t = toks[bn * CAP_ + gr];
            val = ((const float4*)(x + ((size_t)(t * B_ + b)) * F_))[k4];
        }
        ((float4*)&xs[r][0])[k4] = val;
    }
    __syncthreads();
    int j = pass * HCF_ + tid;
    const float* w1p = W1 + (size_t)n * F_ * H_ + j;
    float bias = b1[n * H_ + j];
    float acc[25];
    #pragma unroll
    for (int r = 0; r < 25; ++r) acc[r] = bias;
    const float4* xsv = (const float4*)&xs[0][0];
    for (int k4 = 0; k4 < F_/4; ++k4) {
        float w0 = w1p[(size_t)(4*k4+0) * H_];
        float w1v = w1p[(size_t)(4*k4+1) * H_];
        float w2v = w1p[(size_t)(4*k4+2) * H_];
        float w3v = w1p[(size_t)(4*k4+3) * H_];
        #pragma unroll
        for (int r = 0; r < 25; ++r) {
            float4 xv = xsv[r * (F_/4) + k4];
            acc[r] += xv.x*w0 + xv.y*w1v + xv.z*w2v + xv.w*w3v;
        }
    }
    __hip_bfloat16* hp = h + ((size_t)bn * CAP_ + r0) * HCF_ + tid;
    #pragma unroll
    for (int r = 0; r < 25; ++r) {
        int gr = r0 + r;
        if (gr < CAP_) hp[(size_t)r * HCF_] = __float2bfloat16(fmaxf(acc[r], 0.f));
    }
}

__global__ __launch_bounds__(768) void k_fc2(
        const float* __restrict__ W2, const float* __restrict__ b2,
        const int* __restrict__ toks, const float* __restrict__ wts,
        const int* __restrict__ counts, const __hip_bfloat16* __restrict__ h,
        float* __restrict__ out, int pass) {
    __shared__ float hs[CAP_][HCF_];
    int tid = threadIdx.x;
    int bn = blockIdx.x;
    int c = counts[bn];
    if (c == 0) return;
    int b = bn >> 3, n = bn & 7;
    const ushort4* hv = (const ushort4*)(h + (size_t)bn * CAP_ * HCF_);
    for (int idx = tid; idx < CAP_ * (HCF_/4); idx += 768) {
        ushort4 u = hv[idx];
        float4 fv;
        fv.x = __bfloat162float(*(const __hip_bfloat16*)&u.x);
        fv.y = __bfloat162float(*(const __hip_bfloat16*)&u.y);
        fv.z = __bfloat162float(*(const __hip_bfloat16*)&u.z);
        fv.w = __bfloat162float(*(const __hip_bfloat16*)&u.w);
        ((float4*)&hs[0][0])[idx] = fv;
    }
    __syncthreads();
    int f = tid;
    const float* w2p = W2 + (size_t)n * H_ * F_ + (size_t)(pass * HCF_) * F_ + f;
    float acc[CAP_];
    #pragma unroll
    for (int r = 0; r < CAP_; ++r) acc[r] = 0.f;
    for (int j4 = 0; j4 < HCF_/4; ++j4) {
        float w0 = w2p[(size_t)(4*j4+0) * F_];
        float w1v = w2p[(size_t)(4*j4+1) * F_];
        float w2v = w2p[(size_t)(4*j4+2) * F_];
        float w3v = w2p[(size_t)(4*j4+3) * F_];
        #pragma unroll
        for (int r = 0; r < CAP_; ++r) {
            float4 hh = ((const float4*)&hs[r][0])[j4];
            acc[r] += hh.x*w0 + hh.y*w1v + hh.z*w2v + hh.w*w3v;
        }
    }
    float bias = (pass == 0) ? b2[n * F_ + f] : 0.f;
    #pragma unroll
    for (int r = 0; r < CAP_; ++r) {
        if (r < c) {
            int t = toks[bn * CAP_ + r];
            float fw = wts[bn * CAP_ + r];
            atomicAdd(&out[((size_t)(t * B_ + b)) * F_ + f], fw * (acc[r] + bias));
        }
    }
}

extern "C" void kernel_launch(void* const* d_in, const int* in_sizes, int n_in,
                              void* d_out, int out_size, void* d_ws, size_t ws_size,
                              hipStream_t stream) {
    const float* x   = (const float*)d_in[0];
    const float* Wg1 = (const float*)d_in[1];
    const float* bg1 = (const float*)d_in[2];
    const float* Wg2 = (const float*)d_in[3];
    const float* bg2 = (const float*)d_in[4];
    const float* W1  = (const float*)d_in[5];
    const float* b1  = (const float*)d_in[6];
    const float* W2  = (const float*)d_in[7];
    const float* b2  = (const float*)d_in[8];
    float* out = (float*)d_out;

    // ws layout
    size_t oW1T  = 0;
    size_t oW2T  = oW1T + (size_t)N_ * H_ * F_ * 2;
    size_t oXg   = oW2T + (size_t)N_ * H_ * F_ * 2;
    size_t oCw   = oXg  + (size_t)MT_ * F_ * 2;
    size_t oWts  = oCw  + (size_t)NBN_ * T_ * 4;
    size_t oTok  = oWts + (size_t)NBN_ * CAP_ * 4;
    size_t oCnt  = oTok + (size_t)NBN_ * CAP_ * 4;
    size_t oEcnt = oCnt + (size_t)NBN_ * 4;
    size_t oErow = oEcnt + (size_t)TB_ * 4;
    size_t oOg   = oErow + (size_t)TB_ * 8;
    size_t oHg   = oOg  + (size_t)MT_ * F_ * 2;
    size_t hgPerExpert = (size_t)ME_ * H_ * 2;

    int grp = 0;
    if (ws_size >= oHg + 8 * hgPerExpert) grp = 8;
    else if (ws_size >= oHg + 4 * hgPerExpert) grp = 4;
    else if (ws_size >= oHg + 2 * hgPerExpert) grp = 2;

    if (grp > 0) {
        unsigned short* W1T = (unsigned short*)((char*)d_ws + oW1T);
        unsigned short* W2T = (unsigned short*)((char*)d_ws + oW2T);
        unsigned short* Xg  = (unsigned short*)((char*)d_ws + oXg);
        unsigned short* Og  = (unsigned short*)((char*)d_ws + oOg);
        unsigned short* Hg  = (unsigned short*)((char*)d_ws + oHg);
        float* cw   = (float*)((char*)d_ws + oCw);
        float* wts  = (float*)((char*)d_ws + oWts);
        int* toks   = (int*)((char*)d_ws + oTok);
        int* counts = (int*)((char*)d_ws + oCnt);
        int* ecnt   = (int*)((char*)d_ws + oEcnt);
        int* erow   = (int*)((char*)d_ws + oErow);

        k_gate<<<TB_ / 8, 256, 0, stream>>>(x, Wg1, bg1, Wg2, bg2, cw, ecnt);
        k_capacity<<<NBN_, 256, 0, stream>>>(cw, toks, wts, counts, ecnt, erow);
        k_repack<<<N_ * (H_/256) * (F_/256), 256, 0, stream>>>(W1, W1T, F_, H_);
        k_repack<<<N_ * (F_/256) * (H_/256), 256, 0, stream>>>(W2, W2T, H_, F_);
        k_gather<<<(MT_ * 96) / 256, 256, 0, stream>>>(x, toks, counts, Xg);
        for (int e0 = 0; e0 < N_; e0 += grp) {
            int nblk1 = grp * 25 * 24;
            int nblk2 = grp * 25 * 6;
            k_gemm1<<<nblk1, 256, 0, stream>>>(W1T, Xg, b1, Hg, e0, nblk1);
            k_gemm2<<<nblk2, 256, 0, stream>>>(W2T, Hg, b2, wts, counts, Og, e0, nblk2);
        }
        k_combine<<<(TB_ * 192) / 256, 256, 0, stream>>>(x, Og, ecnt, erow, out);
    } else {
        // round-1 fallback (~20 MB ws)
        __hip_bfloat16* h = (__hip_bfloat16*)d_ws;
        float* cw  = (float*)((char*)d_ws + (size_t)NBN_ * CAP_ * HCF_ * 2);
        float* wts = cw + (size_t)NBN_ * T_;
        int* toks  = (int*)(wts + NBN_ * CAP_);
        int* counts = toks + NBN_ * CAP_;
        k_init_out<<<(TB_ * F_) / 1024, 256, 0, stream>>>(x, out);
        k_gate<<<TB_ / 8, 256, 0, stream>>>(x, Wg1, bg1, Wg2, bg2, cw, nullptr);
        k_capacity<<<NBN_, 256, 0, stream>>>(cw, toks, wts, counts, nullptr, nullptr);
        for (int p = 0; p < NPF_; ++p) {
            k_fc1<<<NBN_ * 2, HCF_, 0, stream>>>(x, W1, b1, toks, counts, h, p);
            k_fc2<<<NBN_, 768, 0, stream>>>(W2, b2, toks, wts, counts, h, out, p);
        }
    }
}

// Round 5
// 589.484 us; speedup vs baseline: 10.5322x; 1.0411x over previous
//
#include <hip/hip_runtime.h>
#include <hip/hip_bf16.h>
#include <math.h>
#include <stdint.h>

#define T_ 197
#define B_ 64
#define F_ 768
#define N_ 8
#define CAP_ 49
#define H_ 3072
#define G_ 192
#define TB_ (T_*B_)       // 12608
#define NBN_ (B_*N_)      // 512
#define ME_ 3200          // padded rows per expert (25 * 128)
#define MR_ 3136          // real rows per expert (64 * 49)
#define MT_ 25600         // total padded rows
#define HCF_ 384          // fallback (round-1) H chunk
#define NPF_ 8

using bf16x8 = __attribute__((ext_vector_type(8))) short;
using f32x4  = __attribute__((ext_vector_type(4))) float;

__device__ __forceinline__ unsigned short f2bf(float v) {
    __hip_bfloat16 h = __float2bfloat16(v);
    return __builtin_bit_cast(unsigned short, h);
}
__device__ __forceinline__ float bf2f(unsigned short u) {
    unsigned int w = ((unsigned int)u) << 16;
    return __builtin_bit_cast(float, w);
}

// async global->LDS, 16B per lane; LDS dest = wave-uniform base + lane*16
#define GLL16(g, l) __builtin_amdgcn_global_load_lds( \
    (const __attribute__((address_space(1))) unsigned int*)(uintptr_t)(g), \
    (__attribute__((address_space(3))) unsigned int*)(uintptr_t)(l), 16, 0, 0)

// m204 bijective XCD swizzle
__device__ __forceinline__ int xcd_swz(int bid, int nblk) {
    int q = nblk >> 3, r = nblk & 7;
    int xcd = bid & 7, idx = bid >> 3;
    int base = (xcd < r) ? xcd * (q + 1) : r * (q + 1) + (xcd - r) * q;
    return base + idx;
}

// ---------------- out = -x (fallback path only) ----------------
__global__ void k_init_out(const float* __restrict__ x, float* __restrict__ out) {
    int i = blockIdx.x * blockDim.x + threadIdx.x;
    const float4* xv = (const float4*)x;
    float4* ov = (float4*)out;
    float4 v = xv[i];
    ov[i] = make_float4(-v.x, -v.y, -v.z, -v.w);
}

// ---------------- gate layer1 (fp32 tiled GEMM): gs = relu(x @ Wg1 + bg1) ----------------
// 64x64 tile, BK=32, 256 thr, 4x4 acc/thread. stride-36 LDS pad -> conflict-free b128.
__global__ __launch_bounds__(256) void k_gate1(
        const float* __restrict__ x, const float* __restrict__ Wg1,
        const float* __restrict__ bg1, float* __restrict__ gs) {
    __shared__ float xs[64][36];
    __shared__ float wt[64][36];
    int tid = threadIdx.x;
    int bm = blockIdx.x % 197, bn = blockIdx.x / 197;
    int m0 = bm * 64, n0 = bn * 64;
    int tc = tid & 15, tr = tid >> 4;
    float acc[4][4] = {};

    for (int kb = 0; kb < F_; kb += 32) {
        #pragma unroll
        for (int i = 0; i < 2; ++i) {                       // x tile: 64x32
            int idx = tid + i * 256;
            int r = idx >> 3, k4 = (idx & 7) << 2;
            *(float4*)&xs[r][k4] = *(const float4*)(x + (size_t)(m0 + r) * F_ + kb + k4);
        }
        #pragma unroll
        for (int i = 0; i < 8; ++i) {                       // Wg1^T tile: wt[n][k]
            int idx = tid + i * 256;
            int kk = idx >> 6, nn = idx & 63;
            wt[nn][kk] = Wg1[(size_t)(kb + kk) * G_ + n0 + nn];
        }
        __syncthreads();
        #pragma unroll
        for (int kq = 0; kq < 8; ++kq) {
            float4 a[4], b[4];
            #pragma unroll
            for (int i = 0; i < 4; ++i) a[i] = *(const float4*)&xs[tr * 4 + i][kq * 4];
            #pragma unroll
            for (int j = 0; j < 4; ++j) b[j] = *(const float4*)&wt[tc + 16 * j][kq * 4];
            #pragma unroll
            for (int i = 0; i < 4; ++i)
                #pragma unroll
                for (int j = 0; j < 4; ++j)
                    acc[i][j] += a[i].x * b[j].x + a[i].y * b[j].y + a[i].z * b[j].z + a[i].w * b[j].w;
        }
        __syncthreads();
    }
    #pragma unroll
    for (int j = 0; j < 4; ++j) {
        int c = n0 + tc + 16 * j;
        float bb = bg1[c];
        #pragma unroll
        for (int i = 0; i < 4; ++i) {
            int r = m0 + tr * 4 + i;
            gs[(size_t)r * G_ + c] = fmaxf(acc[i][j] + bb, 0.f);
        }
    }
}

// ---------------- gate layer2: logits -> softmax -> top2 -> cw; zeroes ecnt ----------------
__global__ __launch_bounds__(256) void k_gate2(
        const float* __restrict__ gs, const float* __restrict__ Wg2,
        const float* __restrict__ bg2, float* __restrict__ cw,
        int* __restrict__ ecnt) {
    __shared__ float gsh[32][200];     // stride-200 pad: conflict-free broadcast reads
    __shared__ float wg2s[G_ * N_];
    __shared__ float lg[32][8];
    int tid = threadIdx.x;
    int id0 = blockIdx.x * 32;

    for (int i = tid; i < 32 * 48; i += 256) {
        int r = i / 48, c4 = i % 48;
        ((float4*)&gsh[r][0])[c4] = *(const float4*)(gs + ((size_t)(id0 + r)) * G_ + c4 * 4);
    }
    for (int i = tid; i < G_ * N_; i += 256) wg2s[i] = Wg2[i];
    __syncthreads();

    int tk = tid >> 3, n = tid & 7;
    float a = bg2[n];
    for (int k = 0; k < G_; ++k) a += gsh[tk][k] * wg2s[k * N_ + n];
    lg[tk][n] = a;
    __syncthreads();

    if (tid < 32) {
        int tk2 = tid;
        float p[8];
        float m = lg[tk2][0];
        #pragma unroll
        for (int nn = 1; nn < 8; ++nn) m = fmaxf(m, lg[tk2][nn]);
        float s = 0.f;
        #pragma unroll
        for (int nn = 0; nn < 8; ++nn) { p[nn] = expf(lg[tk2][nn] - m); s += p[nn]; }
        float inv = 1.f / s;
        #pragma unroll
        for (int nn = 0; nn < 8; ++nn) p[nn] *= inv;
        int i1 = 0; float v1 = p[0];
        #pragma unroll
        for (int nn = 1; nn < 8; ++nn) if (p[nn] > v1) { v1 = p[nn]; i1 = nn; }
        int i2 = -1; float v2 = -1.f;
        #pragma unroll
        for (int nn = 0; nn < 8; ++nn) if (nn != i1 && p[nn] > v2) { v2 = p[nn]; i2 = nn; }
        int id = id0 + tk2;
        int t = id / B_, b = id % B_;
        ecnt[id] = 0;
        #pragma unroll
        for (int nn = 0; nn < 8; ++nn) {
            float v = (nn == i1 || nn == i2) ? p[nn] : 0.f;
            cw[((size_t)(b * N_ + nn)) * T_ + t] = v;
        }
    }
}

// ---------------- gate (fallback path only) ----------------
__global__ __launch_bounds__(256) void k_gate(
        const float* __restrict__ x, const float* __restrict__ Wg1,
        const float* __restrict__ bg1, const float* __restrict__ Wg2,
        const float* __restrict__ bg2, float* __restrict__ cw,
        int* __restrict__ ecnt) {
    __shared__ float xsh[8][F_];
    __shared__ float gsl[8][G_];
    __shared__ float lg[8][N_];
    int tid = threadIdx.x;
    int id0 = blockIdx.x * 8;

    int gid = blockIdx.x * 256 + tid;
    if (gid < TB_ && ecnt) ecnt[gid] = 0;

    const float4* xv = (const float4*)(x + (size_t)id0 * F_);
    float4* xshv = (float4*)&xsh[0][0];
    for (int idx = tid; idx < 8 * (F_/4); idx += 256) xshv[idx] = xv[idx];
    __syncthreads();

    if (tid < G_) {
        float acc[8];
        float bb = bg1[tid];
        #pragma unroll
        for (int tk = 0; tk < 8; ++tk) acc[tk] = bb;
        for (int k = 0; k < F_; ++k) {
            float w = Wg1[k * G_ + tid];
            #pragma unroll
            for (int tk = 0; tk < 8; ++tk) acc[tk] += xsh[tk][k] * w;
        }
        #pragma unroll
        for (int tk = 0; tk < 8; ++tk) gsl[tk][tid] = fmaxf(acc[tk], 0.f);
    }
    __syncthreads();

    if (tid < 64) {
        int tk = tid >> 3, n = tid & 7;
        float acc = bg2[n];
        for (int k = 0; k < G_; ++k) acc += gsl[tk][k] * Wg2[k * N_ + n];
        lg[tk][n] = acc;
    }
    __syncthreads();

    if (tid < 8) {
        int tk = tid;
        float p[8];
        float m = lg[tk][0];
        #pragma unroll
        for (int n = 1; n < 8; ++n) m = fmaxf(m, lg[tk][n]);
        float s = 0.f;
        #pragma unroll
        for (int n = 0; n < 8; ++n) { p[n] = expf(lg[tk][n] - m); s += p[n]; }
        float inv = 1.f / s;
        #pragma unroll
        for (int n = 0; n < 8; ++n) p[n] *= inv;
        int i1 = 0; float v1 = p[0];
        #pragma unroll
        for (int n = 1; n < 8; ++n) if (p[n] > v1) { v1 = p[n]; i1 = n; }
        int i2 = -1; float v2 = -1.f;
        #pragma unroll
        for (int n = 0; n < 8; ++n) if (n != i1 && p[n] > v2) { v2 = p[n]; i2 = n; }
        int id = id0 + tk;
        int t = id / B_, b = id % B_;
        #pragma unroll
        for (int n = 0; n < 8; ++n) {
            float v = (n == i1 || n == i2) ? p[n] : 0.f;
            cw[((size_t)(b * N_ + n)) * T_ + t] = v;
        }
    }
}

// ---------------- capacity: exact top-CAP rank per (b,n); builds inverse map ----------------
__global__ __launch_bounds__(256) void k_capacity(
        const float* __restrict__ cw, int* __restrict__ toks,
        float* __restrict__ wts, int* __restrict__ counts,
        int* __restrict__ ecnt, int* __restrict__ erow) {
    __shared__ float v[T_];
    __shared__ int keep[T_];
    int tid = threadIdx.x;
    int bn = blockIdx.x;
    int b = bn >> 3, n = bn & 7;
    if (tid < T_) v[tid] = cw[(size_t)bn * T_ + tid];
    __syncthreads();
    int kp = 0; float my = 0.f;
    if (tid < T_) {
        my = v[tid];
        int rank = 0;
        for (int t2 = 0; t2 < T_; ++t2) {
            float vt = v[t2];
            rank += (vt > my) || (vt == my && t2 < tid);
        }
        kp = (rank < CAP_) && (my > 0.f);
    }
    if (tid < T_) keep[tid] = kp;
    __syncthreads();
    if (tid < T_ && kp) {
        int slot = 0;
        for (int t2 = 0; t2 < T_; ++t2) slot += (t2 < tid) ? keep[t2] : 0;
        toks[bn * CAP_ + slot] = tid;
        wts[bn * CAP_ + slot] = my;
        if (ecnt) {
            int orow = tid * B_ + b;
            int pos = atomicAdd(&ecnt[orow], 1);
            erow[orow * 2 + pos] = n * ME_ + b * CAP_ + slot;
        }
    }
    if (tid == 0) {
        int tot = 0;
        for (int t2 = 0; t2 < T_; ++t2) tot += keep[t2];
        counts[bn] = tot;
    }
}

// ---------------- repack W [E][K][J] fp32 -> WT [E][J][K] bf16, pre-swizzled ----------------
__global__ __launch_bounds__(256) void k_repack(
        const float* __restrict__ W, unsigned short* __restrict__ WT, int K, int J) {
    int bid = blockIdx.x;
    int nk = K >> 8, nj = J >> 8;
    int kt = bid % nk; bid /= nk;
    int jt = bid % nj; int e = bid / nj;
    int j = jt * 256 + threadIdx.x;
    const float* src = W + ((size_t)e * K + (size_t)kt * 256) * J + j;
    char* drow = (char*)WT + ((size_t)e * J + j) * (size_t)K * 2 + (size_t)kt * 512;
    int swz = (j & 7) << 4;
    for (int c = 0; c < 32; ++c) {
        float f[8];
        #pragma unroll
        for (int s = 0; s < 8; ++s) f[s] = src[(size_t)(c * 8 + s) * J];
        uint4 u;
        u.x = f2bf(f[0]) | ((unsigned)f2bf(f[1]) << 16);
        u.y = f2bf(f[2]) | ((unsigned)f2bf(f[3]) << 16);
        u.z = f2bf(f[4]) | ((unsigned)f2bf(f[5]) << 16);
        u.w = f2bf(f[6]) | ((unsigned)f2bf(f[7]) << 16);
        *(uint4*)(drow + (c >> 3) * 128 + (((c & 7) * 16) ^ swz)) = u;
    }
}

// ---------------- gather x rows -> Xg [MT_][768] bf16, pre-swizzled, zero-padded ----------------
__global__ __launch_bounds__(256) void k_gather(
        const float* __restrict__ x, const int* __restrict__ toks,
        const int* __restrict__ counts, unsigned short* __restrict__ Xg) {
    int gi = blockIdx.x * 256 + threadIdx.x;     // MT_*96 total
    int R = gi / 96, c = gi - R * 96;            // c: 16B chunk (8 bf16)
    int e = R / ME_, re = R - e * ME_;
    uint4 val = make_uint4(0u, 0u, 0u, 0u);
    if (re < MR_) {
        int g = re / CAP_, slot = re - g * CAP_;
        int bn = g * N_ + e;
        if (slot < counts[bn]) {
            int t = toks[bn * CAP_ + slot];
            const float* xp = x + ((size_t)t * B_ + g) * F_ + c * 8;
            float4 v0 = *(const float4*)xp;
            float4 v1 = *(const float4*)(xp + 4);
            val.x = f2bf(v0.x) | ((unsigned)f2bf(v0.y) << 16);
            val.y = f2bf(v0.z) | ((unsigned)f2bf(v0.w) << 16);
            val.z = f2bf(v1.x) | ((unsigned)f2bf(v1.y) << 16);
            val.w = f2bf(v1.z) | ((unsigned)f2bf(v1.w) << 16);
        }
    }
    int w = (c * 16) & 127;
    char* dst = (char*)Xg + (size_t)R * 1536 + (c >> 3) * 128 + (w ^ ((R & 7) << 4));
    *(uint4*)dst = val;
}

// ---------------- GEMM1: Hg = relu(W1T . Xg^T + b1), 2-phase dbuf ----------------
__global__ __launch_bounds__(256) void k_gemm1(
        const unsigned short* __restrict__ W1T, const unsigned short* __restrict__ Xg,
        const float* __restrict__ b1, unsigned short* __restrict__ Hg,
        int e0, int nblk) {
    __shared__ char ldsA[2][16384];
    __shared__ char ldsB[2][16384];
    int swzb = xcd_swz(blockIdx.x, nblk);
    int mt = swzb / 24;
    int jt = swzb % 24;
    int em = mt / 25;
    int e = e0 + em;
    int tid = threadIdx.x, lane = tid & 63, wid = tid >> 6;
    int lr8 = lane >> 3, sl = (lane & 7) << 4;
    const char* Ab = (const char*)W1T + ((size_t)e * H_ + (size_t)jt * 128) * (F_ * 2);
    const char* Bb = (const char*)Xg + ((size_t)e * ME_ + (size_t)(mt % 25) * 128) * (F_ * 2);
    f32x4 acc[4][4] = {};
    int swz = (lane & 7) << 4;
    int q16 = (lane >> 4) << 4;

    auto stage = [&](int buf, int it) {
        int kb = it << 7;
        #pragma unroll
        for (int i = 0; i < 4; ++i) {
            int lr = wid * 32 + i * 8 + lr8;
            GLL16(Ab + (size_t)lr * 1536 + kb + sl, ldsA[buf] + (wid * 32 + i * 8) * 128);
            GLL16(Bb + (size_t)lr * 1536 + kb + sl, ldsB[buf] + (wid * 32 + i * 8) * 128);
        }
    };

    stage(0, 0);
    __syncthreads();
    int cur = 0;
    for (int it = 0; it < 12; ++it) {
        if (it < 11) stage(cur ^ 1, it + 1);
        const char* la = ldsA[cur] + ((wid & 1) * 64) * 128;
        const char* lb = ldsB[cur] + ((wid >> 1) * 64) * 128;
        #pragma unroll
        for (int ks = 0; ks < 2; ++ks) {
            bf16x8 af[4], bfr[4];
            int kk = (ks * 64 + q16) ^ swz;
            #pragma unroll
            for (int t = 0; t < 4; ++t) {
                int ro = (16 * t + (lane & 15)) * 128;
                af[t]  = *(const bf16x8*)(la + ro + kk);
                bfr[t] = *(const bf16x8*)(lb + ro + kk);
            }
            #pragma unroll
            for (int ti = 0; ti < 4; ++ti)
                #pragma unroll
                for (int tm = 0; tm < 4; ++tm)
                    acc[ti][tm] = __builtin_amdgcn_mfma_f32_16x16x32_bf16(af[ti], bfr[tm], acc[ti][tm], 0, 0, 0);
        }
        __syncthreads();
        cur ^= 1;
    }
    int jl0 = jt * 128 + (wid & 1) * 64;
    int ml0 = mt * 128 + (wid >> 1) * 64;
    const float* b1p = b1 + (size_t)e * H_;
    #pragma unroll
    for (int tj = 0; tj < 4; ++tj) {
        int jc = jl0 + 16 * tj + ((lane >> 4) << 2);
        float bb0 = b1p[jc], bb1 = b1p[jc + 1], bb2 = b1p[jc + 2], bb3 = b1p[jc + 3];
        #pragma unroll
        for (int tm = 0; tm < 4; ++tm) {
            int m = ml0 + 16 * tm + (lane & 15);
            f32x4 a = acc[tj][tm];
            unsigned int u0 = f2bf(fmaxf(a[0] + bb0, 0.f)) | ((unsigned)f2bf(fmaxf(a[1] + bb1, 0.f)) << 16);
            unsigned int u1 = f2bf(fmaxf(a[2] + bb2, 0.f)) | ((unsigned)f2bf(fmaxf(a[3] + bb3, 0.f)) << 16);
            int w = (jc * 2) & 127;
            char* dst = (char*)Hg + (size_t)m * (H_ * 2) + ((jc * 2) & ~127) + (w ^ ((m & 7) << 4));
            *(uint2*)dst = make_uint2(u0, u1);
        }
    }
}

// ---------------- GEMM2: Og = fw * (W2T . Hg^T + b2), 2-phase dbuf, clean stores ----------------
__global__ __launch_bounds__(256) void k_gemm2(
        const unsigned short* __restrict__ W2T, const unsigned short* __restrict__ Hg,
        const float* __restrict__ b2, const float* __restrict__ wts,
        const int* __restrict__ counts, unsigned short* __restrict__ Og,
        int e0, int nblk) {
    __shared__ char ldsA[2][16384];
    __shared__ char ldsB[2][16384];
    int swzb = xcd_swz(blockIdx.x, nblk);
    int mt = swzb / 6;
    int ft = swzb % 6;
    int em = mt / 25;
    int e = e0 + em;
    int tid = threadIdx.x, lane = tid & 63, wid = tid >> 6;
    int lr8 = lane >> 3, sl = (lane & 7) << 4;
    const char* Ab = (const char*)W2T + ((size_t)e * F_ + (size_t)ft * 128) * (H_ * 2);
    const char* Bb = (const char*)Hg + (size_t)mt * 128 * (H_ * 2);
    f32x4 acc[4][4] = {};
    int swz = (lane & 7) << 4;
    int q16 = (lane >> 4) << 4;

    auto stage = [&](int buf, int it) {
        int kb = it << 7;
        #pragma unroll
        for (int i = 0; i < 4; ++i) {
            int lr = wid * 32 + i * 8 + lr8;
            GLL16(Ab + (size_t)lr * 6144 + kb + sl, ldsA[buf] + (wid * 32 + i * 8) * 128);
            GLL16(Bb + (size_t)lr * 6144 + kb + sl, ldsB[buf] + (wid * 32 + i * 8) * 128);
        }
    };

    stage(0, 0);
    __syncthreads();
    int cur = 0;
    for (int it = 0; it < 48; ++it) {
        if (it < 47) stage(cur ^ 1, it + 1);
        const char* la = ldsA[cur] + ((wid & 1) * 64) * 128;
        const char* lb = ldsB[cur] + ((wid >> 1) * 64) * 128;
        #pragma unroll
        for (int ks = 0; ks < 2; ++ks) {
            bf16x8 af[4], bfr[4];
            int kk = (ks * 64 + q16) ^ swz;
            #pragma unroll
            for (int t = 0; t < 4; ++t) {
                int ro = (16 * t + (lane & 15)) * 128;
                af[t]  = *(const bf16x8*)(la + ro + kk);
                bfr[t] = *(const bf16x8*)(lb + ro + kk);
            }
            #pragma unroll
            for (int ti = 0; ti < 4; ++ti)
                #pragma unroll
                for (int tm = 0; tm < 4; ++tm)
                    acc[ti][tm] = __builtin_amdgcn_mfma_f32_16x16x32_bf16(af[ti], bfr[tm], acc[ti][tm], 0, 0, 0);
        }
        __syncthreads();
        cur ^= 1;
    }
    int fl0 = ft * 128 + (wid & 1) * 64;
    int ml0 = mt * 128 + (wid >> 1) * 64;
    const float* b2p = b2 + (size_t)e * F_;
    float fwv[4]; int mrow[4];
    #pragma unroll
    for (int tm = 0; tm < 4; ++tm) {
        int m = ml0 + 16 * tm + (lane & 15);
        int re = m - em * ME_;
        float fw = 0.f;
        if (re < MR_) {
            int g = re / CAP_;
            int slot = re - g * CAP_;
            int bn = g * N_ + e;
            if (slot < counts[bn]) fw = wts[bn * CAP_ + slot];
        }
        fwv[tm] = fw;
        mrow[tm] = e0 * ME_ + m;
    }
    #pragma unroll
    for (int tf = 0; tf < 4; ++tf) {
        int f = fl0 + 16 * tf + ((lane >> 4) << 2);
        float c0 = b2p[f], c1 = b2p[f + 1], c2 = b2p[f + 2], c3 = b2p[f + 3];
        #pragma unroll
        for (int tm = 0; tm < 4; ++tm) {
            f32x4 a = acc[tf][tm];
            float fw = fwv[tm];
            unsigned int u0 = f2bf(fw * (a[0] + c0)) | ((unsigned)f2bf(fw * (a[1] + c1)) << 16);
            unsigned int u1 = f2bf(fw * (a[2] + c2)) | ((unsigned)f2bf(fw * (a[3] + c3)) << 16);
            *(uint2*)((char*)Og + (size_t)mrow[tm] * (F_ * 2) + f * 2) = make_uint2(u0, u1);
        }
    }
}

// ---------------- combine: out[t,b,:] = sum(og entries) - x ----------------
__global__ __launch_bounds__(256) void k_combine(
        const float* __restrict__ x, const unsigned short* __restrict__ Og,
        const int* __restrict__ ecnt, const int* __restrict__ erow,
        float* __restrict__ out) {
    int idx = blockIdx.x * 256 + threadIdx.x;     // TB_*192 float4 units
    int row = idx / 192, c4 = idx - row * 192;
    float4 s = make_float4(0.f, 0.f, 0.f, 0.f);
    int c = ecnt[row];
    if (c > 0) {
        ushort4 u = *(const ushort4*)(Og + (size_t)erow[row * 2] * F_ + c4 * 4);
        s.x += bf2f(u.x); s.y += bf2f(u.y); s.z += bf2f(u.z); s.w += bf2f(u.w);
    }
    if (c > 1) {
        ushort4 u = *(const ushort4*)(Og + (size_t)erow[row * 2 + 1] * F_ + c4 * 4);
        s.x += bf2f(u.x); s.y += bf2f(u.y); s.z += bf2f(u.z); s.w += bf2f(u.w);
    }
    float4 xv = ((const float4*)x)[idx];
    ((float4*)out)[idx] = make_float4(s.x - xv.x, s.y - xv.y, s.z - xv.z, s.w - xv.w);
}

// ================= round-1 fallback kernels (tiny ws only) =================
__global__ __launch_bounds__(HCF_) void k_fc1(
        const float* __restrict__ x, const float* __restrict__ W1,
        const float* __restrict__ b1, const int* __restrict__ toks,
        const int* __restrict__ counts, __hip_bfloat16* __restrict__ h, int pass) {
    __shared__ float xs[25][F_];
    int tid = threadIdx.x;
    int bn = blockIdx.x >> 1;
    int half = blockIdx.x & 1;
    int r0 = half * 25;
    int b = bn >> 3, n = bn & 7;
    int c = counts[bn];
    for (int idx = tid; idx < 25 * (F_/4); idx += HCF_) {
        int r = idx / (F_/4), k4 = idx % (F_/4);
        int gr = r0 + r;
        float4 val = make_float4(0.f, 0.f, 0.f, 0.f);
        if (gr < c) {
            int t = toks[bn * CAP_ + gr];
            val = ((const float4*)(x + ((size_t)(t * B_ + b)) * F_))[k4];
        }
        ((float4*)&xs[r][0])[k4] = val;
    }
    __syncthreads();
    int j = pass * HCF_ + tid;
    const float* w1p = W1 + (size_t)n * F_ * H_ + j;
    float bias = b1[n * H_ + j];
    float acc[25];
    #pragma unroll
    for (int r = 0; r < 25; ++r) acc[r] = bias;
    const float4* xsv = (const float4*)&xs[0][0];
    for (int k4 = 0; k4 < F_/4; ++k4) {
        float w0 = w1p[(size_t)(4*k4+0) * H_];
        float w1v = w1p[(size_t)(4*k4+1) * H_];
        float w2v = w1p[(size_t)(4*k4+2) * H_];
        float w3v = w1p[(size_t)(4*k4+3) * H_];
        #pragma unroll
        for (int r = 0; r < 25; ++r) {
            float4 xv = xsv[r * (F_/4) + k4];
            acc[r] += xv.x*w0 + xv.y*w1v + xv.z*w2v + xv.w*w3v;
        }
    }
    __hip_bfloat16* hp = h + ((size_t)bn * CAP_ + r0) * HCF_ + tid;
    #pragma unroll
    for (int r = 0; r < 25; ++r) {
        int gr = r0 + r;
        if (gr < CAP_) hp[(size_t)r * HCF_] = __float2bfloat16(fmaxf(acc[r], 0.f));
    }
}

__global__ __launch_bounds__(768) void k_fc2(
        const float* __restrict__ W2, const float* __restrict__ b2,
        const int* __restrict__ toks, const float* __restrict__ wts,
        const int* __restrict__ counts, const __hip_bfloat16* __restrict__ h,
        float* __restrict__ out, int pass) {
    __shared__ float hs[CAP_][HCF_];
    int tid = threadIdx.x;
    int bn = blockIdx.x;
    int c = counts[bn];
    if (c == 0) return;
    int b = bn >> 3, n = bn & 7;
    const ushort4* hv = (const ushort4*)(h + (size_t)bn * CAP_ * HCF_);
    for (int idx = tid; idx < CAP_ * (HCF_/4); idx += 768) {
        ushort4 u = hv[idx];
        float4 fv;
        fv.x = __bfloat162float(*(const __hip_bfloat16*)&u.x);
        fv.y = __bfloat162float(*(const __hip_bfloat16*)&u.y);
        fv.z = __bfloat162float(*(const __hip_bfloat16*)&u.z);
        fv.w = __bfloat162float(*(const __hip_bfloat16*)&u.w);
        ((float4*)&hs[0][0])[idx] = fv;
    }
    __syncthreads();
    int f = tid;
    const float* w2p = W2 + (size_t)n * H_ * F_ + (size_t)(pass * HCF_) * F_ + f;
    float acc[CAP_];
    #pragma unroll
    for (int r = 0; r < CAP_; ++r) acc[r] = 0.f;
    for (int j4 = 0; j4 < HCF_/4; ++j4) {
        float w0 = w2p[(size_t)(4*j4+0) * F_];
        float w1v = w2p[(size_t)(4*j4+1) * F_];
        float w2v = w2p[(size_t)(4*j4+2) * F_];
        float w3v = w2p[(size_t)(4*j4+3) * F_];
        #pragma unroll
        for (int r = 0; r < CAP_; ++r) {
            float4 hh = ((const float4*)&hs[r][0])[j4];
            acc[r] += hh.x*w0 + hh.y*w1v + hh.z*w2v + hh.w*w3v;
        }
    }
    float bias = (pass == 0) ? b2[n * F_ + f] : 0.f;
    #pragma unroll
    for (int r = 0; r < CAP_; ++r) {
        if (r < c) {
            int t = toks[bn * CAP_ + r];
            float fw = wts[bn * CAP_ + r];
            atomicAdd(&out[((size_t)(t * B_ + b)) * F_ + f], fw * (acc[r] + bias));
        }
    }
}

extern "C" void kernel_launch(void* const* d_in, const int* in_sizes, int n_in,
                              void* d_out, int out_size, void* d_ws, size_t ws_size,
                              hipStream_t stream) {
    const float* x   = (const float*)d_in[0];
    const float* Wg1 = (const float*)d_in[1];
    const float* bg1 = (const float*)d_in[2];
    const float* Wg2 = (const float*)d_in[3];
    const float* bg2 = (const float*)d_in[4];
    const float* W1  = (const float*)d_in[5];
    const float* b1  = (const float*)d_in[6];
    const float* W2  = (const float*)d_in[7];
    const float* b2  = (const float*)d_in[8];
    float* out = (float*)d_out;

    // ws layout
    size_t oW1T  = 0;
    size_t oW2T  = oW1T + (size_t)N_ * H_ * F_ * 2;
    size_t oXg   = oW2T + (size_t)N_ * H_ * F_ * 2;
    size_t oCw   = oXg  + (size_t)MT_ * F_ * 2;
    size_t oWts  = oCw  + (size_t)NBN_ * T_ * 4;
    size_t oTok  = oWts + (size_t)NBN_ * CAP_ * 4;
    size_t oCnt  = oTok + (size_t)NBN_ * CAP_ * 4;
    size_t oEcnt = oCnt + (size_t)NBN_ * 4;
    size_t oErow = oEcnt + (size_t)TB_ * 4;
    size_t oOg   = oErow + (size_t)TB_ * 8;
    size_t oHg   = oOg  + (size_t)MT_ * F_ * 2;
    size_t hgPerExpert = (size_t)ME_ * H_ * 2;

    int grp = 0;
    if (ws_size >= oHg + 8 * hgPerExpert) grp = 8;
    else if (ws_size >= oHg + 4 * hgPerExpert) grp = 4;
    else if (ws_size >= oHg + 2 * hgPerExpert) grp = 2;

    if (grp > 0) {
        unsigned short* W1T = (unsigned short*)((char*)d_ws + oW1T);
        unsigned short* W2T = (unsigned short*)((char*)d_ws + oW2T);
        unsigned short* Xg  = (unsigned short*)((char*)d_ws + oXg);
        unsigned short* Og  = (unsigned short*)((char*)d_ws + oOg);
        unsigned short* Hg  = (unsigned short*)((char*)d_ws + oHg);
        float* gs   = (float*)((char*)d_ws + oHg);    // aliases Hg: consumed before gemm1 writes Hg
        float* cw   = (float*)((char*)d_ws + oCw);
        float* wts  = (float*)((char*)d_ws + oWts);
        int* toks   = (int*)((char*)d_ws + oTok);
        int* counts = (int*)((char*)d_ws + oCnt);
        int* ecnt   = (int*)((char*)d_ws + oEcnt);
        int* erow   = (int*)((char*)d_ws + oErow);

        k_gate1<<<197 * 3, 256, 0, stream>>>(x, Wg1, bg1, gs);
        k_gate2<<<TB_ / 32, 256, 0, stream>>>(gs, Wg2, bg2, cw, ecnt);
        k_capacity<<<NBN_, 256, 0, stream>>>(cw, toks, wts, counts, ecnt, erow);
        k_repack<<<N_ * (H_/256) * (F_/256), 256, 0, stream>>>(W1, W1T, F_, H_);
        k_repack<<<N_ * (F_/256) * (H_/256), 256, 0, stream>>>(W2, W2T, H_, F_);
        k_gather<<<(MT_ * 96) / 256, 256, 0, stream>>>(x, toks, counts, Xg);
        for (int e0 = 0; e0 < N_; e0 += grp) {
            int nblk1 = grp * 25 * 24;
            int nblk2 = grp * 25 * 6;
            k_gemm1<<<nblk1, 256, 0, stream>>>(W1T, Xg, b1, Hg, e0, nblk1);
            k_gemm2<<<nblk2, 256, 0, stream>>>(W2T, Hg, b2, wts, counts, Og, e0, nblk2);
        }
        k_combine<<<(TB_ * 192) / 256, 256, 0, stream>>>(x, Og, ecnt, erow, out);
    } else {
        // round-1 fallback (~20 MB ws)
        __hip_bfloat16* h = (__hip_bfloat16*)d_ws;
        float* cw  = (float*)((char*)d_ws + (size_t)NBN_ * CAP_ * HCF_ * 2);
        float* wts = cw + (size_t)NBN_ * T_;
        int* toks  = (int*)(wts + NBN_ * CAP_);
        int* counts = toks + NBN_ * CAP_;
        k_init_out<<<(TB_ * F_) / 1024, 256, 0, stream>>>(x, out);
        k_gate<<<TB_ / 8, 256, 0, stream>>>(x, Wg1, bg1, Wg2, bg2, cw, nullptr);
        k_capacity<<<NBN_, 256, 0, stream>>>(cw, toks, wts, counts, nullptr, nullptr);
        for (int p = 0; p < NPF_; ++p) {
            k_fc1<<<NBN_ * 2, HCF_, 0, stream>>>(x, W1, b1, toks, counts, h, p);
            k_fc2<<<NBN_, 768, 0, stream>>>(W2, b2, toks, wts, counts, h, out, p);
        }
    }
}

// Round 6
// 553.004 us; speedup vs baseline: 11.2270x; 1.0660x over previous
//
#include <hip/hip_runtime.h>
#include <hip/hip_bf16.h>
#include <math.h>
#include <stdint.h>

#define T_ 197
#define B_ 64
#define F_ 768
#define N_ 8
#define CAP_ 49
#define H_ 3072
#define G_ 192
#define TB_ (T_*B_)       // 12608
#define NBN_ (B_*N_)      // 512
#define ME_ 3200          // padded rows per expert (25 * 128)
#define MR_ 3136          // real rows per expert (64 * 49)
#define MT_ 25600         // total padded rows
#define HCF_ 384          // fallback (round-1) H chunk
#define NPF_ 8

using bf16x8 = __attribute__((ext_vector_type(8))) short;
using f32x4  = __attribute__((ext_vector_type(4))) float;

__device__ __forceinline__ unsigned short f2bf(float v) {
    __hip_bfloat16 h = __float2bfloat16(v);
    return __builtin_bit_cast(unsigned short, h);
}
__device__ __forceinline__ float bf2f(unsigned short u) {
    unsigned int w = ((unsigned int)u) << 16;
    return __builtin_bit_cast(float, w);
}

// async global->LDS, 16B per lane; LDS dest = wave-uniform base + lane*16
#define GLL16(g, l) __builtin_amdgcn_global_load_lds( \
    (const __attribute__((address_space(1))) unsigned int*)(uintptr_t)(g), \
    (__attribute__((address_space(3))) unsigned int*)(uintptr_t)(l), 16, 0, 0)

// m204 bijective XCD swizzle
__device__ __forceinline__ int xcd_swz(int bid, int nblk) {
    int q = nblk >> 3, r = nblk & 7;
    int xcd = bid & 7, idx = bid >> 3;
    int base = (xcd < r) ? xcd * (q + 1) : r * (q + 1) + (xcd - r) * q;
    return base + idx;
}

// ---------------- out = -x (fallback path only) ----------------
__global__ void k_init_out(const float* __restrict__ x, float* __restrict__ out) {
    int i = blockIdx.x * blockDim.x + threadIdx.x;
    const float4* xv = (const float4*)x;
    float4* ov = (float4*)out;
    float4 v = xv[i];
    ov[i] = make_float4(-v.x, -v.y, -v.z, -v.w);
}

// ---------------- gate layer1: raw partial sums, K-split x2 ----------------
// grid = 197 mt x 3 nt x 2 kh = 1182 blocks. 64x64 tile, K-half 384, BK=32.
// 2-buf: x staged via global_load_lds, Wg1^T reg-staged. No bias/relu here.
__global__ __launch_bounds__(256) void k_gate1(
        const float* __restrict__ x, const float* __restrict__ Wg1,
        float* __restrict__ gs_part) {
    __shared__ float xs[2][64 * 32];
    __shared__ float wt[2][64][36];
    int bid = blockIdx.x;
    int bm = bid % 197; int rest = bid / 197;
    int bn = rest % 3, kh = rest / 3;
    int m0 = bm * 64, n0 = bn * 64, k0 = kh * 384;
    int tid = threadIdx.x, lane = tid & 63, wid = tid >> 6;
    int tc = tid & 15, tr = tid >> 4;
    float acc[4][4] = {};
    const float* xbase = x + (size_t)m0 * F_ + k0;
    float wreg[8];

    // issue x-tile stage for K-step t into buf (linear LDS, GLL16)
    auto issueX = [&](int buf, int t) {
        int kb = t * 32;
        #pragma unroll
        for (int i = 0; i < 2; ++i) {
            int r0 = wid * 16 + i * 8;
            GLL16(xbase + (size_t)(r0 + (lane >> 3)) * F_ + kb + (lane & 7) * 4,
                  &xs[buf][r0 * 32]);
        }
    };
    auto loadW = [&](int t) {
        int kb = k0 + t * 32;
        #pragma unroll
        for (int i = 0; i < 8; ++i) {
            int idx = tid + i * 256;
            int kk = idx >> 6, nn = idx & 63;
            wreg[i] = Wg1[(size_t)(kb + kk) * G_ + n0 + nn];
        }
    };
    auto writeW = [&](int buf) {
        #pragma unroll
        for (int i = 0; i < 8; ++i) {
            int idx = tid + i * 256;
            int kk = idx >> 6, nn = idx & 63;
            wt[buf][nn][kk] = wreg[i];
        }
    };

    loadW(0); issueX(0, 0); writeW(0);
    __syncthreads();
    int cur = 0;
    for (int t = 0; t < 12; ++t) {
        if (t < 11) { loadW(t + 1); issueX(cur ^ 1, t + 1); }
        const float* xc = &xs[cur][0];
        #pragma unroll
        for (int kq = 0; kq < 8; ++kq) {
            float4 a[4], b[4];
            #pragma unroll
            for (int i = 0; i < 4; ++i) a[i] = *(const float4*)(xc + (tr * 4 + i) * 32 + kq * 4);
            #pragma unroll
            for (int j = 0; j < 4; ++j) b[j] = *(const float4*)&wt[cur][tc + 16 * j][kq * 4];
            #pragma unroll
            for (int i = 0; i < 4; ++i)
                #pragma unroll
                for (int j = 0; j < 4; ++j)
                    acc[i][j] += a[i].x * b[j].x + a[i].y * b[j].y + a[i].z * b[j].z + a[i].w * b[j].w;
        }
        if (t < 11) writeW(cur ^ 1);
        __syncthreads();
        cur ^= 1;
    }
    float* gp = gs_part + (size_t)kh * TB_ * G_;
    #pragma unroll
    for (int j = 0; j < 4; ++j) {
        int c = n0 + tc + 16 * j;
        #pragma unroll
        for (int i = 0; i < 4; ++i) {
            int r = m0 + tr * 4 + i;
            gp[(size_t)r * G_ + c] = acc[i][j];
        }
    }
}

// ---------------- gate layer2: reduce partials + bias + relu -> logits -> softmax -> top2 ----------------
__global__ __launch_bounds__(256) void k_gate2(
        const float* __restrict__ gs_part, const float* __restrict__ bg1,
        const float* __restrict__ Wg2, const float* __restrict__ bg2,
        float* __restrict__ cw, int* __restrict__ ecnt) {
    __shared__ float gsh[32][200];     // stride-200 pad: conflict-free broadcast reads
    __shared__ float wg2s[G_ * N_];
    __shared__ float lg[32][8];
    int tid = threadIdx.x;
    int id0 = blockIdx.x * 32;

    for (int i = tid; i < 32 * 48; i += 256) {
        int r = i / 48, c4 = i % 48;
        const float* p0 = gs_part + (size_t)(id0 + r) * G_ + c4 * 4;
        float4 a = *(const float4*)p0;
        float4 b = *(const float4*)(p0 + (size_t)TB_ * G_);
        float4 g = *(const float4*)(bg1 + c4 * 4);
        float4 v;
        v.x = fmaxf(a.x + b.x + g.x, 0.f);
        v.y = fmaxf(a.y + b.y + g.y, 0.f);
        v.z = fmaxf(a.z + b.z + g.z, 0.f);
        v.w = fmaxf(a.w + b.w + g.w, 0.f);
        ((float4*)&gsh[r][0])[c4] = v;
    }
    for (int i = tid; i < G_ * N_; i += 256) wg2s[i] = Wg2[i];
    __syncthreads();

    int tk = tid >> 3, n = tid & 7;
    float a = bg2[n];
    for (int k = 0; k < G_; ++k) a += gsh[tk][k] * wg2s[k * N_ + n];
    lg[tk][n] = a;
    __syncthreads();

    if (tid < 32) {
        int tk2 = tid;
        float p[8];
        float m = lg[tk2][0];
        #pragma unroll
        for (int nn = 1; nn < 8; ++nn) m = fmaxf(m, lg[tk2][nn]);
        float s = 0.f;
        #pragma unroll
        for (int nn = 0; nn < 8; ++nn) { p[nn] = expf(lg[tk2][nn] - m); s += p[nn]; }
        float inv = 1.f / s;
        #pragma unroll
        for (int nn = 0; nn < 8; ++nn) p[nn] *= inv;
        int i1 = 0; float v1 = p[0];
        #pragma unroll
        for (int nn = 1; nn < 8; ++nn) if (p[nn] > v1) { v1 = p[nn]; i1 = nn; }
        int i2 = -1; float v2 = -1.f;
        #pragma unroll
        for (int nn = 0; nn < 8; ++nn) if (nn != i1 && p[nn] > v2) { v2 = p[nn]; i2 = nn; }
        int id = id0 + tk2;
        int t = id / B_, b = id % B_;
        ecnt[id] = 0;
        #pragma unroll
        for (int nn = 0; nn < 8; ++nn) {
            float v = (nn == i1 || nn == i2) ? p[nn] : 0.f;
            cw[((size_t)(b * N_ + nn)) * T_ + t] = v;
        }
    }
}

// ---------------- gate (fallback path only) ----------------
__global__ __launch_bounds__(256) void k_gate(
        const float* __restrict__ x, const float* __restrict__ Wg1,
        const float* __restrict__ bg1, const float* __restrict__ Wg2,
        const float* __restrict__ bg2, float* __restrict__ cw,
        int* __restrict__ ecnt) {
    __shared__ float xsh[8][F_];
    __shared__ float gsl[8][G_];
    __shared__ float lg[8][N_];
    int tid = threadIdx.x;
    int id0 = blockIdx.x * 8;

    int gid = blockIdx.x * 256 + tid;
    if (gid < TB_ && ecnt) ecnt[gid] = 0;

    const float4* xv = (const float4*)(x + (size_t)id0 * F_);
    float4* xshv = (float4*)&xsh[0][0];
    for (int idx = tid; idx < 8 * (F_/4); idx += 256) xshv[idx] = xv[idx];
    __syncthreads();

    if (tid < G_) {
        float acc[8];
        float bb = bg1[tid];
        #pragma unroll
        for (int tk = 0; tk < 8; ++tk) acc[tk] = bb;
        for (int k = 0; k < F_; ++k) {
            float w = Wg1[k * G_ + tid];
            #pragma unroll
            for (int tk = 0; tk < 8; ++tk) acc[tk] += xsh[tk][k] * w;
        }
        #pragma unroll
        for (int tk = 0; tk < 8; ++tk) gsl[tk][tid] = fmaxf(acc[tk], 0.f);
    }
    __syncthreads();

    if (tid < 64) {
        int tk = tid >> 3, n = tid & 7;
        float acc = bg2[n];
        for (int k = 0; k < G_; ++k) acc += gsl[tk][k] * Wg2[k * N_ + n];
        lg[tk][n] = acc;
    }
    __syncthreads();

    if (tid < 8) {
        int tk = tid;
        float p[8];
        float m = lg[tk][0];
        #pragma unroll
        for (int n = 1; n < 8; ++n) m = fmaxf(m, lg[tk][n]);
        float s = 0.f;
        #pragma unroll
        for (int n = 0; n < 8; ++n) { p[n] = expf(lg[tk][n] - m); s += p[n]; }
        float inv = 1.f / s;
        #pragma unroll
        for (int n = 0; n < 8; ++n) p[n] *= inv;
        int i1 = 0; float v1 = p[0];
        #pragma unroll
        for (int n = 1; n < 8; ++n) if (p[n] > v1) { v1 = p[n]; i1 = n; }
        int i2 = -1; float v2 = -1.f;
        #pragma unroll
        for (int n = 0; n < 8; ++n) if (n != i1 && p[n] > v2) { v2 = p[n]; i2 = n; }
        int id = id0 + tk;
        int t = id / B_, b = id % B_;
        #pragma unroll
        for (int n = 0; n < 8; ++n) {
            float v = (n == i1 || n == i2) ? p[n] : 0.f;
            cw[((size_t)(b * N_ + n)) * T_ + t] = v;
        }
    }
}

// ---------------- capacity: exact top-CAP rank per (b,n); builds inverse map ----------------
__global__ __launch_bounds__(256) void k_capacity(
        const float* __restrict__ cw, int* __restrict__ toks,
        float* __restrict__ wts, int* __restrict__ counts,
        int* __restrict__ ecnt, int* __restrict__ erow) {
    __shared__ float v[T_];
    __shared__ int keep[T_];
    int tid = threadIdx.x;
    int bn = blockIdx.x;
    int b = bn >> 3, n = bn & 7;
    if (tid < T_) v[tid] = cw[(size_t)bn * T_ + tid];
    __syncthreads();
    int kp = 0; float my = 0.f;
    if (tid < T_) {
        my = v[tid];
        int rank = 0;
        for (int t2 = 0; t2 < T_; ++t2) {
            float vt = v[t2];
            rank += (vt > my) || (vt == my && t2 < tid);
        }
        kp = (rank < CAP_) && (my > 0.f);
    }
    if (tid < T_) keep[tid] = kp;
    __syncthreads();
    if (tid < T_ && kp) {
        int slot = 0;
        for (int t2 = 0; t2 < T_; ++t2) slot += (t2 < tid) ? keep[t2] : 0;
        toks[bn * CAP_ + slot] = tid;
        wts[bn * CAP_ + slot] = my;
        if (ecnt) {
            int orow = tid * B_ + b;
            int pos = atomicAdd(&ecnt[orow], 1);
            erow[orow * 2 + pos] = n * ME_ + b * CAP_ + slot;
        }
    }
    if (tid == 0) {
        int tot = 0;
        for (int t2 = 0; t2 < T_; ++t2) tot += keep[t2];
        counts[bn] = tot;
    }
}

// ---------------- repack W [E][K][J] fp32 -> WT [E][J][K] bf16, pre-swizzled ----------------
// LDS-transpose: 64x64 tile, coalesced reads AND writes (128B output chunks).
__global__ __launch_bounds__(256) void k_repack(
        const float* __restrict__ W, unsigned short* __restrict__ WT, int K, int J) {
    __shared__ float tile[64][65];
    int bid = blockIdx.x;
    int nk = K >> 6, nj = J >> 6;
    int kt = bid % nk; bid /= nk;
    int jt = bid % nj; int e = bid / nj;
    int k0 = kt * 64, j0 = jt * 64;
    int tid = threadIdx.x;
    int jr = (tid & 15) << 2;
    int kr = tid >> 4;
    const float* src = W + ((size_t)e * K + k0) * J + j0;
    #pragma unroll
    for (int i = 0; i < 4; ++i) {
        float4 v = *(const float4*)(src + (size_t)(kr + 16 * i) * J + jr);
        *(float4*)&tile[kr + 16 * i][jr] = v;
    }
    __syncthreads();
    int c = tid & 7;           // 16B k-chunk (8 bf16) within 64-k group
    int jrow = tid >> 3;       // 0..31
    #pragma unroll
    for (int i = 0; i < 2; ++i) {
        int j = jrow + 32 * i;
        float f[8];
        #pragma unroll
        for (int s = 0; s < 8; ++s) f[s] = tile[c * 8 + s][j];
        uint4 u;
        u.x = f2bf(f[0]) | ((unsigned)f2bf(f[1]) << 16);
        u.y = f2bf(f[2]) | ((unsigned)f2bf(f[3]) << 16);
        u.z = f2bf(f[4]) | ((unsigned)f2bf(f[5]) << 16);
        u.w = f2bf(f[6]) | ((unsigned)f2bf(f[7]) << 16);
        int jg = j0 + j;
        char* drow = (char*)WT + ((size_t)e * J + jg) * (size_t)K * 2 + (size_t)(k0 >> 6) * 128;
        *(uint4*)(drow + ((c << 4) ^ ((jg & 7) << 4))) = u;
    }
}

// ---------------- gather x rows -> Xg [MT_][768] bf16, pre-swizzled, zero-padded ----------------
__global__ __launch_bounds__(256) void k_gather(
        const float* __restrict__ x, const int* __restrict__ toks,
        const int* __restrict__ counts, unsigned short* __restrict__ Xg) {
    int gi = blockIdx.x * 256 + threadIdx.x;     // MT_*96 total
    int R = gi / 96, c = gi - R * 96;            // c: 16B chunk (8 bf16)
    int e = R / ME_, re = R - e * ME_;
    uint4 val = make_uint4(0u, 0u, 0u, 0u);
    if (re < MR_) {
        int g = re / CAP_, slot = re - g * CAP_;
        int bn = g * N_ + e;
        if (slot < counts[bn]) {
            int t = toks[bn * CAP_ + slot];
            const float* xp = x + ((size_t)t * B_ + g) * F_ + c * 8;
            float4 v0 = *(const float4*)xp;
            float4 v1 = *(const float4*)(xp + 4);
            val.x = f2bf(v0.x) | ((unsigned)f2bf(v0.y) << 16);
            val.y = f2bf(v0.z) | ((unsigned)f2bf(v0.w) << 16);
            val.z = f2bf(v1.x) | ((unsigned)f2bf(v1.y) << 16);
            val.w = f2bf(v1.z) | ((unsigned)f2bf(v1.w) << 16);
        }
    }
    int w = (c * 16) & 127;
    char* dst = (char*)Xg + (size_t)R * 1536 + (c >> 3) * 128 + (w ^ ((R & 7) << 4));
    *(uint4*)dst = val;
}

// ---------------- GEMM1: Hg = relu(W1T . Xg^T + b1), 2-phase dbuf ----------------
__global__ __launch_bounds__(256) void k_gemm1(
        const unsigned short* __restrict__ W1T, const unsigned short* __restrict__ Xg,
        const float* __restrict__ b1, unsigned short* __restrict__ Hg,
        int e0, int nblk) {
    __shared__ char ldsA[2][16384];
    __shared__ char ldsB[2][16384];
    int swzb = xcd_swz(blockIdx.x, nblk);
    int mt = swzb / 24;
    int jt = swzb % 24;
    int em = mt / 25;
    int e = e0 + em;
    int tid = threadIdx.x, lane = tid & 63, wid = tid >> 6;
    int lr8 = lane >> 3, sl = (lane & 7) << 4;
    const char* Ab = (const char*)W1T + ((size_t)e * H_ + (size_t)jt * 128) * (F_ * 2);
    const char* Bb = (const char*)Xg + ((size_t)e * ME_ + (size_t)(mt % 25) * 128) * (F_ * 2);
    f32x4 acc[4][4] = {};
    int swz = (lane & 7) << 4;
    int q16 = (lane >> 4) << 4;

    auto stage = [&](int buf, int it) {
        int kb = it << 7;
        #pragma unroll
        for (int i = 0; i < 4; ++i) {
            int lr = wid * 32 + i * 8 + lr8;
            GLL16(Ab + (size_t)lr * 1536 + kb + sl, ldsA[buf] + (wid * 32 + i * 8) * 128);
            GLL16(Bb + (size_t)lr * 1536 + kb + sl, ldsB[buf] + (wid * 32 + i * 8) * 128);
        }
    };

    stage(0, 0);
    __syncthreads();
    int cur = 0;
    for (int it = 0; it < 12; ++it) {
        if (it < 11) stage(cur ^ 1, it + 1);
        const char* la = ldsA[cur] + ((wid & 1) * 64) * 128;
        const char* lb = ldsB[cur] + ((wid >> 1) * 64) * 128;
        #pragma unroll
        for (int ks = 0; ks < 2; ++ks) {
            bf16x8 af[4], bfr[4];
            int kk = (ks * 64 + q16) ^ swz;
            #pragma unroll
            for (int t = 0; t < 4; ++t) {
                int ro = (16 * t + (lane & 15)) * 128;
                af[t]  = *(const bf16x8*)(la + ro + kk);
                bfr[t] = *(const bf16x8*)(lb + ro + kk);
            }
            #pragma unroll
            for (int ti = 0; ti < 4; ++ti)
                #pragma unroll
                for (int tm = 0; tm < 4; ++tm)
                    acc[ti][tm] = __builtin_amdgcn_mfma_f32_16x16x32_bf16(af[ti], bfr[tm], acc[ti][tm], 0, 0, 0);
        }
        __syncthreads();
        cur ^= 1;
    }
    int jl0 = jt * 128 + (wid & 1) * 64;
    int ml0 = mt * 128 + (wid >> 1) * 64;
    const float* b1p = b1 + (size_t)e * H_;
    #pragma unroll
    for (int tj = 0; tj < 4; ++tj) {
        int jc = jl0 + 16 * tj + ((lane >> 4) << 2);
        float bb0 = b1p[jc], bb1 = b1p[jc + 1], bb2 = b1p[jc + 2], bb3 = b1p[jc + 3];
        #pragma unroll
        for (int tm = 0; tm < 4; ++tm) {
            int m = ml0 + 16 * tm + (lane & 15);
            f32x4 a = acc[tj][tm];
            unsigned int u0 = f2bf(fmaxf(a[0] + bb0, 0.f)) | ((unsigned)f2bf(fmaxf(a[1] + bb1, 0.f)) << 16);
            unsigned int u1 = f2bf(fmaxf(a[2] + bb2, 0.f)) | ((unsigned)f2bf(fmaxf(a[3] + bb3, 0.f)) << 16);
            int w = (jc * 2) & 127;
            char* dst = (char*)Hg + (size_t)m * (H_ * 2) + ((jc * 2) & ~127) + (w ^ ((m & 7) << 4));
            *(uint2*)dst = make_uint2(u0, u1);
        }
    }
}

// ---------------- GEMM2: Og = fw * (W2T . Hg^T + b2), 2-phase dbuf, clean stores ----------------
__global__ __launch_bounds__(256) void k_gemm2(
        const unsigned short* __restrict__ W2T, const unsigned short* __restrict__ Hg,
        const float* __restrict__ b2, const float* __restrict__ wts,
        const int* __restrict__ counts, unsigned short* __restrict__ Og,
        int e0, int nblk) {
    __shared__ char ldsA[2][16384];
    __shared__ char ldsB[2][16384];
    int swzb = xcd_swz(blockIdx.x, nblk);
    int mt = swzb / 6;
    int ft = swzb % 6;
    int em = mt / 25;
    int e = e0 + em;
    int tid = threadIdx.x, lane = tid & 63, wid = tid >> 6;
    int lr8 = lane >> 3, sl = (lane & 7) << 4;
    const char* Ab = (const char*)W2T + ((size_t)e * F_ + (size_t)ft * 128) * (H_ * 2);
    const char* Bb = (const char*)Hg + (size_t)mt * 128 * (H_ * 2);
    f32x4 acc[4][4] = {};
    int swz = (lane & 7) << 4;
    int q16 = (lane >> 4) << 4;

    auto stage = [&](int buf, int it) {
        int kb = it << 7;
        #pragma unroll
        for (int i = 0; i < 4; ++i) {
            int lr = wid * 32 + i * 8 + lr8;
            GLL16(Ab + (size_t)lr * 6144 + kb + sl, ldsA[buf] + (wid * 32 + i * 8) * 128);
            GLL16(Bb + (size_t)lr * 6144 + kb + sl, ldsB[buf] + (wid * 32 + i * 8) * 128);
        }
    };

    stage(0, 0);
    __syncthreads();
    int cur = 0;
    for (int it = 0; it < 48; ++it) {
        if (it < 47) stage(cur ^ 1, it + 1);
        const char* la = ldsA[cur] + ((wid & 1) * 64) * 128;
        const char* lb = ldsB[cur] + ((wid >> 1) * 64) * 128;
        #pragma unroll
        for (int ks = 0; ks < 2; ++ks) {
            bf16x8 af[4], bfr[4];
            int kk = (ks * 64 + q16) ^ swz;
            #pragma unroll
            for (int t = 0; t < 4; ++t) {
                int ro = (16 * t + (lane & 15)) * 128;
                af[t]  = *(const bf16x8*)(la + ro + kk);
                bfr[t] = *(const bf16x8*)(lb + ro + kk);
            }
            #pragma unroll
            for (int ti = 0; ti < 4; ++ti)
                #pragma unroll
                for (int tm = 0; tm < 4; ++tm)
                    acc[ti][tm] = __builtin_amdgcn_mfma_f32_16x16x32_bf16(af[ti], bfr[tm], acc[ti][tm], 0, 0, 0);
        }
        __syncthreads();
        cur ^= 1;
    }
    int fl0 = ft * 128 + (wid & 1) * 64;
    int ml0 = mt * 128 + (wid >> 1) * 64;
    const float* b2p = b2 + (size_t)e * F_;
    float fwv[4]; int mrow[4];
    #pragma unroll
    for (int tm = 0; tm < 4; ++tm) {
        int m = ml0 + 16 * tm + (lane & 15);
        int re = m - em * ME_;
        float fw = 0.f;
        if (re < MR_) {
            int g = re / CAP_;
            int slot = re - g * CAP_;
            int bn = g * N_ + e;
            if (slot < counts[bn]) fw = wts[bn * CAP_ + slot];
        }
        fwv[tm] = fw;
        mrow[tm] = e0 * ME_ + m;
    }
    #pragma unroll
    for (int tf = 0; tf < 4; ++tf) {
        int f = fl0 + 16 * tf + ((lane >> 4) << 2);
        float c0 = b2p[f], c1 = b2p[f + 1], c2 = b2p[f + 2], c3 = b2p[f + 3];
        #pragma unroll
        for (int tm = 0; tm < 4; ++tm) {
            f32x4 a = acc[tf][tm];
            float fw = fwv[tm];
            unsigned int u0 = f2bf(fw * (a[0] + c0)) | ((unsigned)f2bf(fw * (a[1] + c1)) << 16);
            unsigned int u1 = f2bf(fw * (a[2] + c2)) | ((unsigned)f2bf(fw * (a[3] + c3)) << 16);
            *(uint2*)((char*)Og + (size_t)mrow[tm] * (F_ * 2) + f * 2) = make_uint2(u0, u1);
        }
    }
}

// ---------------- combine: out[t,b,:] = sum(og entries) - x ----------------
__global__ __launch_bounds__(256) void k_combine(
        const float* __restrict__ x, const unsigned short* __restrict__ Og,
        const int* __restrict__ ecnt, const int* __restrict__ erow,
        float* __restrict__ out) {
    int idx = blockIdx.x * 256 + threadIdx.x;     // TB_*192 float4 units
    int row = idx / 192, c4 = idx - row * 192;
    float4 s = make_float4(0.f, 0.f, 0.f, 0.f);
    int c = ecnt[row];
    if (c > 0) {
        ushort4 u = *(const ushort4*)(Og + (size_t)erow[row * 2] * F_ + c4 * 4);
        s.x += bf2f(u.x); s.y += bf2f(u.y); s.z += bf2f(u.z); s.w += bf2f(u.w);
    }
    if (c > 1) {
        ushort4 u = *(const ushort4*)(Og + (size_t)erow[row * 2 + 1] * F_ + c4 * 4);
        s.x += bf2f(u.x); s.y += bf2f(u.y); s.z += bf2f(u.z); s.w += bf2f(u.w);
    }
    float4 xv = ((const float4*)x)[idx];
    ((float4*)out)[idx] = make_float4(s.x - xv.x, s.y - xv.y, s.z - xv.z, s.w - xv.w);
}

// ================= round-1 fallback kernels (tiny ws only) =================
__global__ __launch_bounds__(HCF_) void k_fc1(
        const float* __restrict__ x, const float* __restrict__ W1,
        const float* __restrict__ b1, const int* __restrict__ toks,
        const int* __restrict__ counts, __hip_bfloat16* __restrict__ h, int pass) {
    __shared__ float xs[25][F_];
    int tid = threadIdx.x;
    int bn = blockIdx.x >> 1;
    int half = blockIdx.x & 1;
    int r0 = half * 25;
    int b = bn >> 3, n = bn & 7;
    int c = counts[bn];
    for (int idx = tid; idx < 25 * (F_/4); idx += HCF_) {
        int r = idx / (F_/4), k4 = idx % (F_/4);
        int gr = r0 + r;
        float4 val = make_float4(0.f, 0.f, 0.f, 0.f);
        if (gr < c) {
            int t = toks[bn * CAP_ + gr];
            val = ((const float4*)(x + ((size_t)(t * B_ + b)) * F_))[k4];
        }
        ((float4*)&xs[r][0])[k4] = val;
    }
    __syncthreads();
    int j = pass * HCF_ + tid;
    const float* w1p = W1 + (size_t)n * F_ * H_ + j;
    float bias = b1[n * H_ + j];
    float acc[25];
    #pragma unroll
    for (int r = 0; r < 25; ++r) acc[r] = bias;
    const float4* xsv = (const float4*)&xs[0][0];
    for (int k4 = 0; k4 < F_/4; ++k4) {
        float w0 = w1p[(size_t)(4*k4+0) * H_];
        float w1v = w1p[(size_t)(4*k4+1) * H_];
        float w2v = w1p[(size_t)(4*k4+2) * H_];
        float w3v = w1p[(size_t)(4*k4+3) * H_];
        #pragma unroll
        for (int r = 0; r < 25; ++r) {
            float4 xv = xsv[r * (F_/4) + k4];
            acc[r] += xv.x*w0 + xv.y*w1v + xv.z*w2v + xv.w*w3v;
        }
    }
    __hip_bfloat16* hp = h + ((size_t)bn * CAP_ + r0) * HCF_ + tid;
    #pragma unroll
    for (int r = 0; r < 25; ++r) {
        int gr = r0 + r;
        if (gr < CAP_) hp[(size_t)r * HCF_] = __float2bfloat16(fmaxf(acc[r], 0.f));
    }
}

__global__ __launch_bounds__(768) void k_fc2(
        const float* __restrict__ W2, const float* __restrict__ b2,
        const int* __restrict__ toks, const float* __restrict__ wts,
        const int* __restrict__ counts, const __hip_bfloat16* __restrict__ h,
        float* __restrict__ out, int pass) {
    __shared__ float hs[CAP_][HCF_];
    int tid = threadIdx.x;
    int bn = blockIdx.x;
    int c = counts[bn];
    if (c == 0) return;
    int b = bn >> 3, n = bn & 7;
    const ushort4* hv = (const ushort4*)(h + (size_t)bn * CAP_ * HCF_);
    for (int idx = tid; idx < CAP_ * (HCF_/4); idx += 768) {
        ushort4 u = hv[idx];
        float4 fv;
        fv.x = __bfloat162float(*(const __hip_bfloat16*)&u.x);
        fv.y = __bfloat162float(*(const __hip_bfloat16*)&u.y);
        fv.z = __bfloat162float(*(const __hip_bfloat16*)&u.z);
        fv.w = __bfloat162float(*(const __hip_bfloat16*)&u.w);
        ((float4*)&hs[0][0])[idx] = fv;
    }
    __syncthreads();
    int f = tid;
    const float* w2p = W2 + (size_t)n * H_ * F_ + (size_t)(pass * HCF_) * F_ + f;
    float acc[CAP_];
    #pragma unroll
    for (int r = 0; r < CAP_; ++r) acc[r] = 0.f;
    for (int j4 = 0; j4 < HCF_/4; ++j4) {
        float w0 = w2p[(size_t)(4*j4+0) * F_];
        float w1v = w2p[(size_t)(4*j4+1) * F_];
        float w2v = w2p[(size_t)(4*j4+2) * F_];
        float w3v = w2p[(size_t)(4*j4+3) * F_];
        #pragma unroll
        for (int r = 0; r < CAP_; ++r) {
            float4 hh = ((const float4*)&hs[r][0])[j4];
            acc[r] += hh.x*w0 + hh.y*w1v + hh.z*w2v + hh.w*w3v;
        }
    }
    float bias = (pass == 0) ? b2[n * F_ + f] : 0.f;
    #pragma unroll
    for (int r = 0; r < CAP_; ++r) {
        if (r < c) {
            int t = toks[bn * CAP_ + r];
            float fw = wts[bn * CAP_ + r];
            atomicAdd(&out[((size_t)(t * B_ + b)) * F_ + f], fw * (acc[r] + bias));
        }
    }
}

extern "C" void kernel_launch(void* const* d_in, const int* in_sizes, int n_in,
                              void* d_out, int out_size, void* d_ws, size_t ws_size,
                              hipStream_t stream) {
    const float* x   = (const float*)d_in[0];
    const float* Wg1 = (const float*)d_in[1];
    const float* bg1 = (const float*)d_in[2];
    const float* Wg2 = (const float*)d_in[3];
    const float* bg2 = (const float*)d_in[4];
    const float* W1  = (const float*)d_in[5];
    const float* b1  = (const float*)d_in[6];
    const float* W2  = (const float*)d_in[7];
    const float* b2  = (const float*)d_in[8];
    float* out = (float*)d_out;

    // ws layout
    size_t oW1T  = 0;
    size_t oW2T  = oW1T + (size_t)N_ * H_ * F_ * 2;
    size_t oXg   = oW2T + (size_t)N_ * H_ * F_ * 2;
    size_t oCw   = oXg  + (size_t)MT_ * F_ * 2;
    size_t oWts  = oCw  + (size_t)NBN_ * T_ * 4;
    size_t oTok  = oWts + (size_t)NBN_ * CAP_ * 4;
    size_t oCnt  = oTok + (size_t)NBN_ * CAP_ * 4;
    size_t oEcnt = oCnt + (size_t)NBN_ * 4;
    size_t oErow = oEcnt + (size_t)TB_ * 4;
    size_t oOg   = oErow + (size_t)TB_ * 8;
    size_t oHg   = oOg  + (size_t)MT_ * F_ * 2;
    size_t hgPerExpert = (size_t)ME_ * H_ * 2;

    int grp = 0;
    if (ws_size >= oHg + 8 * hgPerExpert) grp = 8;
    else if (ws_size >= oHg + 4 * hgPerExpert) grp = 4;
    else if (ws_size >= oHg + 2 * hgPerExpert) grp = 2;

    if (grp > 0) {
        unsigned short* W1T = (unsigned short*)((char*)d_ws + oW1T);
        unsigned short* W2T = (unsigned short*)((char*)d_ws + oW2T);
        unsigned short* Xg  = (unsigned short*)((char*)d_ws + oXg);
        unsigned short* Og  = (unsigned short*)((char*)d_ws + oOg);
        unsigned short* Hg  = (unsigned short*)((char*)d_ws + oHg);
        float* gs_part = (float*)((char*)d_ws + oHg);   // aliases Hg: dead before gemm1 writes Hg
        float* cw   = (float*)((char*)d_ws + oCw);
        float* wts  = (float*)((char*)d_ws + oWts);
        int* toks   = (int*)((char*)d_ws + oTok);
        int* counts = (int*)((char*)d_ws + oCnt);
        int* ecnt   = (int*)((char*)d_ws + oEcnt);
        int* erow   = (int*)((char*)d_ws + oErow);

        k_gate1<<<197 * 3 * 2, 256, 0, stream>>>(x, Wg1, gs_part);
        k_gate2<<<TB_ / 32, 256, 0, stream>>>(gs_part, bg1, Wg2, bg2, cw, ecnt);
        k_capacity<<<NBN_, 256, 0, stream>>>(cw, toks, wts, counts, ecnt, erow);
        k_repack<<<N_ * (F_/64) * (H_/64), 256, 0, stream>>>(W1, W1T, F_, H_);
        k_repack<<<N_ * (H_/64) * (F_/64), 256, 0, stream>>>(W2, W2T, H_, F_);
        k_gather<<<(MT_ * 96) / 256, 256, 0, stream>>>(x, toks, counts, Xg);
        for (int e0 = 0; e0 < N_; e0 += grp) {
            int nblk1 = grp * 25 * 24;
            int nblk2 = grp * 25 * 6;
            k_gemm1<<<nblk1, 256, 0, stream>>>(W1T, Xg, b1, Hg, e0, nblk1);
            k_gemm2<<<nblk2, 256, 0, stream>>>(W2T, Hg, b2, wts, counts, Og, e0, nblk2);
        }
        k_combine<<<(TB_ * 192) / 256, 256, 0, stream>>>(x, Og, ecnt, erow, out);
    } else {
        // round-1 fallback (~20 MB ws)
        __hip_bfloat16* h = (__hip_bfloat16*)d_ws;
        float* cw  = (float*)((char*)d_ws + (size_t)NBN_ * CAP_ * HCF_ * 2);
        float* wts = cw + (size_t)NBN_ * T_;
        int* toks  = (int*)(wts + NBN_ * CAP_);
        int* counts = toks + NBN_ * CAP_;
        k_init_out<<<(TB_ * F_) / 1024, 256, 0, stream>>>(x, out);
        k_gate<<<TB_ / 8, 256, 0, stream>>>(x, Wg1, bg1, Wg2, bg2, cw, nullptr);
        k_capacity<<<NBN_, 256, 0, stream>>>(cw, toks, wts, counts, nullptr, nullptr);
        for (int p = 0; p < NPF_; ++p) {
            k_fc1<<<NBN_ * 2, HCF_, 0, stream>>>(x, W1, b1, toks, counts, h, p);
            k_fc2<<<NBN_, 768, 0, stream>>>(W2, b2, toks, wts, counts, h, out, p);
        }
    }
}

// Round 7
// 513.250 us; speedup vs baseline: 12.0965x; 1.0775x over previous
//
#include <hip/hip_runtime.h>
#include <hip/hip_bf16.h>
#include <math.h>
#include <stdint.h>

#define T_ 197
#define B_ 64
#define F_ 768
#define N_ 8
#define CAP_ 49
#define H_ 3072
#define G_ 192
#define TB_ (T_*B_)       // 12608
#define NBN_ (B_*N_)      // 512
#define ME_ 3200          // padded rows per expert (25 * 128)
#define MR_ 3136          // real rows per expert (64 * 49)
#define MT_ 25600         // total padded rows
#define KH_ 4             // gate1 K-split
#define HCF_ 384          // fallback (round-1) H chunk
#define NPF_ 8

using bf16x8 = __attribute__((ext_vector_type(8))) short;
using f32x4  = __attribute__((ext_vector_type(4))) float;

__device__ __forceinline__ unsigned short f2bf(float v) {
    __hip_bfloat16 h = __float2bfloat16(v);
    return __builtin_bit_cast(unsigned short, h);
}
__device__ __forceinline__ float bf2f(unsigned short u) {
    unsigned int w = ((unsigned int)u) << 16;
    return __builtin_bit_cast(float, w);
}

// async global->LDS, 16B per lane; LDS dest = wave-uniform base + lane*16
#define GLL16(g, l) __builtin_amdgcn_global_load_lds( \
    (const __attribute__((address_space(1))) unsigned int*)(uintptr_t)(g), \
    (__attribute__((address_space(3))) unsigned int*)(uintptr_t)(l), 16, 0, 0)

// m204 bijective XCD swizzle
__device__ __forceinline__ int xcd_swz(int bid, int nblk) {
    int q = nblk >> 3, r = nblk & 7;
    int xcd = bid & 7, idx = bid >> 3;
    int base = (xcd < r) ? xcd * (q + 1) : r * (q + 1) + (xcd - r) * q;
    return base + idx;
}

// ---------------- out = -x (fallback path only) ----------------
__global__ void k_init_out(const float* __restrict__ x, float* __restrict__ out) {
    int i = blockIdx.x * blockDim.x + threadIdx.x;
    const float4* xv = (const float4*)x;
    float4* ov = (float4*)out;
    float4 v = xv[i];
    ov[i] = make_float4(-v.x, -v.y, -v.z, -v.w);
}

// ---------------- gate layer1: raw partial sums, K-split x4 ----------------
// grid = 197 mt x 3 nt x 4 kh = 2364 blocks. 64x64 tile, K-chunk 192, BK=32.
// Single-buffer LDS pad-35 (all access patterns <=2-way); loads issued before compute (T14).
__global__ __launch_bounds__(256) void k_gate1(
        const float* __restrict__ x, const float* __restrict__ Wg1,
        float* __restrict__ gs_part) {
    __shared__ float xs[64][35];
    __shared__ float wt[64][35];
    int bid = blockIdx.x;
    int bm = bid % 197; int rest = bid / 197;
    int bn = rest % 3, kh = rest / 3;
    int m0 = bm * 64, n0 = bn * 64, k0 = kh * (F_ / KH_);
    int tid = threadIdx.x;
    int tc = tid & 15, tr = tid >> 4;
    float acc[4][4] = {};

    // x staging: thread -> (row = tid>>3, c4 = tid&7), 2 float4 per thread
    int xr0 = tid >> 3, xc4 = (tid & 7) << 2;
    // w staging: thread -> (nn = tid&63, kw = tid>>6), 2 float4-along-k per thread
    int wnn = tid & 63, wkw = tid >> 6;

    float4 xreg[2];
    float4 wreg[2];

    auto loadRegs = [&](int t) {
        int kb = k0 + t * 32;
        #pragma unroll
        for (int i = 0; i < 2; ++i) {
            int r = xr0 + i * 32;
            xreg[i] = *(const float4*)(x + (size_t)(m0 + r) * F_ + kb + xc4);
        }
        #pragma unroll
        for (int i = 0; i < 2; ++i) {
            int kkg = (wkw * 2 + i) * 4;
            const float* wp = Wg1 + (size_t)(kb + kkg) * G_ + n0 + wnn;
            wreg[i].x = wp[0];
            wreg[i].y = wp[G_];
            wreg[i].z = wp[2 * G_];
            wreg[i].w = wp[3 * G_];
        }
    };
    auto writeLDS = [&]() {
        #pragma unroll
        for (int i = 0; i < 2; ++i)
            *(float4*)&xs[xr0 + i * 32][xc4] = xreg[i];
        #pragma unroll
        for (int i = 0; i < 2; ++i)
            *(float4*)&wt[wnn][(wkw * 2 + i) * 4] = wreg[i];
    };

    loadRegs(0);
    for (int t = 0; t < 6; ++t) {
        __syncthreads();                  // prev compute done -> LDS reusable
        writeLDS();                       // waits on vmcnt internally
        __syncthreads();
        if (t < 5) loadRegs(t + 1);       // next loads overlap compute below
        #pragma unroll
        for (int kq = 0; kq < 8; ++kq) {
            float4 a[4], b[4];
            #pragma unroll
            for (int i = 0; i < 4; ++i) a[i] = *(const float4*)&xs[tr * 4 + i][kq * 4];
            #pragma unroll
            for (int j = 0; j < 4; ++j) b[j] = *(const float4*)&wt[tc + 16 * j][kq * 4];
            #pragma unroll
            for (int i = 0; i < 4; ++i)
                #pragma unroll
                for (int j = 0; j < 4; ++j)
                    acc[i][j] += a[i].x * b[j].x + a[i].y * b[j].y + a[i].z * b[j].z + a[i].w * b[j].w;
        }
    }
    float* gp = gs_part + (size_t)kh * TB_ * G_;
    #pragma unroll
    for (int j = 0; j < 4; ++j) {
        int c = n0 + tc + 16 * j;
        #pragma unroll
        for (int i = 0; i < 4; ++i) {
            int r = m0 + tr * 4 + i;
            gp[(size_t)r * G_ + c] = acc[i][j];
        }
    }
}

// ---------------- gate layer2: reduce 4 partials + bias + relu -> logits -> softmax -> top2 ----------------
__global__ __launch_bounds__(256) void k_gate2(
        const float* __restrict__ gs_part, const float* __restrict__ bg1,
        const float* __restrict__ Wg2, const float* __restrict__ bg2,
        float* __restrict__ cw, int* __restrict__ ecnt) {
    __shared__ float gsh[32][200];     // stride-200 pad: conflict-free broadcast reads
    __shared__ float wg2s[G_ * N_];
    __shared__ float lg[32][8];
    int tid = threadIdx.x;
    int id0 = blockIdx.x * 32;

    for (int i = tid; i < 32 * 48; i += 256) {
        int r = i / 48, c4 = i % 48;
        const float* p0 = gs_part + (size_t)(id0 + r) * G_ + c4 * 4;
        float4 a = *(const float4*)p0;
        float4 b = *(const float4*)(p0 + (size_t)TB_ * G_);
        float4 c = *(const float4*)(p0 + 2 * (size_t)TB_ * G_);
        float4 d = *(const float4*)(p0 + 3 * (size_t)TB_ * G_);
        float4 g = *(const float4*)(bg1 + c4 * 4);
        float4 v;
        v.x = fmaxf(a.x + b.x + c.x + d.x + g.x, 0.f);
        v.y = fmaxf(a.y + b.y + c.y + d.y + g.y, 0.f);
        v.z = fmaxf(a.z + b.z + c.z + d.z + g.z, 0.f);
        v.w = fmaxf(a.w + b.w + c.w + d.w + g.w, 0.f);
        ((float4*)&gsh[r][0])[c4] = v;
    }
    for (int i = tid; i < G_ * N_; i += 256) wg2s[i] = Wg2[i];
    __syncthreads();

    int tk = tid >> 3, n = tid & 7;
    float a = bg2[n];
    for (int k = 0; k < G_; ++k) a += gsh[tk][k] * wg2s[k * N_ + n];
    lg[tk][n] = a;
    __syncthreads();

    if (tid < 32) {
        int tk2 = tid;
        float p[8];
        float m = lg[tk2][0];
        #pragma unroll
        for (int nn = 1; nn < 8; ++nn) m = fmaxf(m, lg[tk2][nn]);
        float s = 0.f;
        #pragma unroll
        for (int nn = 0; nn < 8; ++nn) { p[nn] = expf(lg[tk2][nn] - m); s += p[nn]; }
        float inv = 1.f / s;
        #pragma unroll
        for (int nn = 0; nn < 8; ++nn) p[nn] *= inv;
        int i1 = 0; float v1 = p[0];
        #pragma unroll
        for (int nn = 1; nn < 8; ++nn) if (p[nn] > v1) { v1 = p[nn]; i1 = nn; }
        int i2 = -1; float v2 = -1.f;
        #pragma unroll
        for (int nn = 0; nn < 8; ++nn) if (nn != i1 && p[nn] > v2) { v2 = p[nn]; i2 = nn; }
        int id = id0 + tk2;
        int t = id / B_, b = id % B_;
        ecnt[id] = 0;
        #pragma unroll
        for (int nn = 0; nn < 8; ++nn) {
            float v = (nn == i1 || nn == i2) ? p[nn] : 0.f;
            cw[((size_t)(b * N_ + nn)) * T_ + t] = v;
        }
    }
}

// ---------------- gate (fallback path only) ----------------
__global__ __launch_bounds__(256) void k_gate(
        const float* __restrict__ x, const float* __restrict__ Wg1,
        const float* __restrict__ bg1, const float* __restrict__ Wg2,
        const float* __restrict__ bg2, float* __restrict__ cw,
        int* __restrict__ ecnt) {
    __shared__ float xsh[8][F_];
    __shared__ float gsl[8][G_];
    __shared__ float lg[8][N_];
    int tid = threadIdx.x;
    int id0 = blockIdx.x * 8;

    int gid = blockIdx.x * 256 + tid;
    if (gid < TB_ && ecnt) ecnt[gid] = 0;

    const float4* xv = (const float4*)(x + (size_t)id0 * F_);
    float4* xshv = (float4*)&xsh[0][0];
    for (int idx = tid; idx < 8 * (F_/4); idx += 256) xshv[idx] = xv[idx];
    __syncthreads();

    if (tid < G_) {
        float acc[8];
        float bb = bg1[tid];
        #pragma unroll
        for (int tk = 0; tk < 8; ++tk) acc[tk] = bb;
        for (int k = 0; k < F_; ++k) {
            float w = Wg1[k * G_ + tid];
            #pragma unroll
            for (int tk = 0; tk < 8; ++tk) acc[tk] += xsh[tk][k] * w;
        }
        #pragma unroll
        for (int tk = 0; tk < 8; ++tk) gsl[tk][tid] = fmaxf(acc[tk], 0.f);
    }
    __syncthreads();

    if (tid < 64) {
        int tk = tid >> 3, n = tid & 7;
        float acc = bg2[n];
        for (int k = 0; k < G_; ++k) acc += gsl[tk][k] * Wg2[k * N_ + n];
        lg[tk][n] = acc;
    }
    __syncthreads();

    if (tid < 8) {
        int tk = tid;
        float p[8];
        float m = lg[tk][0];
        #pragma unroll
        for (int n = 1; n < 8; ++n) m = fmaxf(m, lg[tk][n]);
        float s = 0.f;
        #pragma unroll
        for (int n = 0; n < 8; ++n) { p[n] = expf(lg[tk][n] - m); s += p[n]; }
        float inv = 1.f / s;
        #pragma unroll
        for (int n = 0; n < 8; ++n) p[n] *= inv;
        int i1 = 0; float v1 = p[0];
        #pragma unroll
        for (int n = 1; n < 8; ++n) if (p[n] > v1) { v1 = p[n]; i1 = n; }
        int i2 = -1; float v2 = -1.f;
        #pragma unroll
        for (int n = 0; n < 8; ++n) if (n != i1 && p[n] > v2) { v2 = p[n]; i2 = n; }
        int id = id0 + tk;
        int t = id / B_, b = id % B_;
        #pragma unroll
        for (int n = 0; n < 8; ++n) {
            float v = (n == i1 || n == i2) ? p[n] : 0.f;
            cw[((size_t)(b * N_ + n)) * T_ + t] = v;
        }
    }
}

// ---------------- capacity: exact top-CAP rank per (b,n); builds inverse map ----------------
__global__ __launch_bounds__(256) void k_capacity(
        const float* __restrict__ cw, int* __restrict__ toks,
        float* __restrict__ wts, int* __restrict__ counts,
        int* __restrict__ ecnt, int* __restrict__ erow) {
    __shared__ float v[T_];
    __shared__ int keep[T_];
    int tid = threadIdx.x;
    int bn = blockIdx.x;
    int b = bn >> 3, n = bn & 7;
    if (tid < T_) v[tid] = cw[(size_t)bn * T_ + tid];
    __syncthreads();
    int kp = 0; float my = 0.f;
    if (tid < T_) {
        my = v[tid];
        int rank = 0;
        for (int t2 = 0; t2 < T_; ++t2) {
            float vt = v[t2];
            rank += (vt > my) || (vt == my && t2 < tid);
        }
        kp = (rank < CAP_) && (my > 0.f);
    }
    if (tid < T_) keep[tid] = kp;
    __syncthreads();
    if (tid < T_ && kp) {
        int slot = 0;
        for (int t2 = 0; t2 < T_; ++t2) slot += (t2 < tid) ? keep[t2] : 0;
        toks[bn * CAP_ + slot] = tid;
        wts[bn * CAP_ + slot] = my;
        if (ecnt) {
            int orow = tid * B_ + b;
            int pos = atomicAdd(&ecnt[orow], 1);
            erow[orow * 2 + pos] = n * ME_ + b * CAP_ + slot;
        }
    }
    if (tid == 0) {
        int tot = 0;
        for (int t2 = 0; t2 < T_; ++t2) tot += keep[t2];
        counts[bn] = tot;
    }
}

// ---------------- repack W [E][K][J] fp32 -> WT [E][J][K] bf16, pre-swizzled ----------------
// LDS-transpose: 64x64 tile, coalesced reads AND writes (128B output chunks).
__global__ __launch_bounds__(256) void k_repack(
        const float* __restrict__ W, unsigned short* __restrict__ WT, int K, int J) {
    __shared__ float tile[64][65];
    int bid = blockIdx.x;
    int nk = K >> 6, nj = J >> 6;
    int kt = bid % nk; bid /= nk;
    int jt = bid % nj; int e = bid / nj;
    int k0 = kt * 64, j0 = jt * 64;
    int tid = threadIdx.x;
    int jr = (tid & 15) << 2;
    int kr = tid >> 4;
    const float* src = W + ((size_t)e * K + k0) * J + j0;
    #pragma unroll
    for (int i = 0; i < 4; ++i) {
        float4 v = *(const float4*)(src + (size_t)(kr + 16 * i) * J + jr);
        *(float4*)&tile[kr + 16 * i][jr] = v;
    }
    __syncthreads();
    int c = tid & 7;           // 16B k-chunk (8 bf16) within 64-k group
    int jrow = tid >> 3;       // 0..31
    #pragma unroll
    for (int i = 0; i < 2; ++i) {
        int j = jrow + 32 * i;
        float f[8];
        #pragma unroll
        for (int s = 0; s < 8; ++s) f[s] = tile[c * 8 + s][j];
        uint4 u;
        u.x = f2bf(f[0]) | ((unsigned)f2bf(f[1]) << 16);
        u.y = f2bf(f[2]) | ((unsigned)f2bf(f[3]) << 16);
        u.z = f2bf(f[4]) | ((unsigned)f2bf(f[5]) << 16);
        u.w = f2bf(f[6]) | ((unsigned)f2bf(f[7]) << 16);
        int jg = j0 + j;
        char* drow = (char*)WT + ((size_t)e * J + jg) * (size_t)K * 2 + (size_t)(k0 >> 6) * 128;
        *(uint4*)(drow + ((c << 4) ^ ((jg & 7) << 4))) = u;
    }
}

// ---------------- gather x rows -> Xg [MT_][768] bf16, pre-swizzled, zero-padded ----------------
__global__ __launch_bounds__(256) void k_gather(
        const float* __restrict__ x, const int* __restrict__ toks,
        const int* __restrict__ counts, unsigned short* __restrict__ Xg) {
    int gi = blockIdx.x * 256 + threadIdx.x;     // MT_*96 total
    int R = gi / 96, c = gi - R * 96;            // c: 16B chunk (8 bf16)
    int e = R / ME_, re = R - e * ME_;
    uint4 val = make_uint4(0u, 0u, 0u, 0u);
    if (re < MR_) {
        int g = re / CAP_, slot = re - g * CAP_;
        int bn = g * N_ + e;
        if (slot < counts[bn]) {
            int t = toks[bn * CAP_ + slot];
            const float* xp = x + ((size_t)t * B_ + g) * F_ + c * 8;
            float4 v0 = *(const float4*)xp;
            float4 v1 = *(const float4*)(xp + 4);
            val.x = f2bf(v0.x) | ((unsigned)f2bf(v0.y) << 16);
            val.y = f2bf(v0.z) | ((unsigned)f2bf(v0.w) << 16);
            val.z = f2bf(v1.x) | ((unsigned)f2bf(v1.y) << 16);
            val.w = f2bf(v1.z) | ((unsigned)f2bf(v1.w) << 16);
        }
    }
    int w = (c * 16) & 127;
    char* dst = (char*)Xg + (size_t)R * 1536 + (c >> 3) * 128 + (w ^ ((R & 7) << 4));
    *(uint4*)dst = val;
}

// ---------------- GEMM1: Hg = relu(W1T . Xg^T + b1), 2-phase dbuf ----------------
__global__ __launch_bounds__(256) void k_gemm1(
        const unsigned short* __restrict__ W1T, const unsigned short* __restrict__ Xg,
        const float* __restrict__ b1, unsigned short* __restrict__ Hg,
        int e0, int nblk) {
    __shared__ char ldsA[2][16384];
    __shared__ char ldsB[2][16384];
    int swzb = xcd_swz(blockIdx.x, nblk);
    int mt = swzb / 24;
    int jt = swzb % 24;
    int em = mt / 25;
    int e = e0 + em;
    int tid = threadIdx.x, lane = tid & 63, wid = tid >> 6;
    int lr8 = lane >> 3, sl = (lane & 7) << 4;
    const char* Ab = (const char*)W1T + ((size_t)e * H_ + (size_t)jt * 128) * (F_ * 2);
    const char* Bb = (const char*)Xg + ((size_t)e * ME_ + (size_t)(mt % 25) * 128) * (F_ * 2);
    f32x4 acc[4][4] = {};
    int swz = (lane & 7) << 4;
    int q16 = (lane >> 4) << 4;

    auto stage = [&](int buf, int it) {
        int kb = it << 7;
        #pragma unroll
        for (int i = 0; i < 4; ++i) {
            int lr = wid * 32 + i * 8 + lr8;
            GLL16(Ab + (size_t)lr * 1536 + kb + sl, ldsA[buf] + (wid * 32 + i * 8) * 128);
            GLL16(Bb + (size_t)lr * 1536 + kb + sl, ldsB[buf] + (wid * 32 + i * 8) * 128);
        }
    };

    stage(0, 0);
    __syncthreads();
    int cur = 0;
    for (int it = 0; it < 12; ++it) {
        if (it < 11) stage(cur ^ 1, it + 1);
        const char* la = ldsA[cur] + ((wid & 1) * 64) * 128;
        const char* lb = ldsB[cur] + ((wid >> 1) * 64) * 128;
        #pragma unroll
        for (int ks = 0; ks < 2; ++ks) {
            bf16x8 af[4], bfr[4];
            int kk = (ks * 64 + q16) ^ swz;
            #pragma unroll
            for (int t = 0; t < 4; ++t) {
                int ro = (16 * t + (lane & 15)) * 128;
                af[t]  = *(const bf16x8*)(la + ro + kk);
                bfr[t] = *(const bf16x8*)(lb + ro + kk);
            }
            #pragma unroll
            for (int ti = 0; ti < 4; ++ti)
                #pragma unroll
                for (int tm = 0; tm < 4; ++tm)
                    acc[ti][tm] = __builtin_amdgcn_mfma_f32_16x16x32_bf16(af[ti], bfr[tm], acc[ti][tm], 0, 0, 0);
        }
        __syncthreads();
        cur ^= 1;
    }
    int jl0 = jt * 128 + (wid & 1) * 64;
    int ml0 = mt * 128 + (wid >> 1) * 64;
    const float* b1p = b1 + (size_t)e * H_;
    #pragma unroll
    for (int tj = 0; tj < 4; ++tj) {
        int jc = jl0 + 16 * tj + ((lane >> 4) << 2);
        float bb0 = b1p[jc], bb1 = b1p[jc + 1], bb2 = b1p[jc + 2], bb3 = b1p[jc + 3];
        #pragma unroll
        for (int tm = 0; tm < 4; ++tm) {
            int m = ml0 + 16 * tm + (lane & 15);
            f32x4 a = acc[tj][tm];
            unsigned int u0 = f2bf(fmaxf(a[0] + bb0, 0.f)) | ((unsigned)f2bf(fmaxf(a[1] + bb1, 0.f)) << 16);
            unsigned int u1 = f2bf(fmaxf(a[2] + bb2, 0.f)) | ((unsigned)f2bf(fmaxf(a[3] + bb3, 0.f)) << 16);
            int w = (jc * 2) & 127;
            char* dst = (char*)Hg + (size_t)m * (H_ * 2) + ((jc * 2) & ~127) + (w ^ ((m & 7) << 4));
            *(uint2*)dst = make_uint2(u0, u1);
        }
    }
}

// ---------------- GEMM2: Og = fw * (W2T . Hg^T + b2), 2-phase dbuf, clean stores ----------------
__global__ __launch_bounds__(256) void k_gemm2(
        const unsigned short* __restrict__ W2T, const unsigned short* __restrict__ Hg,
        const float* __restrict__ b2, const float* __restrict__ wts,
        const int* __restrict__ counts, unsigned short* __restrict__ Og,
        int e0, int nblk) {
    __shared__ char ldsA[2][16384];
    __shared__ char ldsB[2][16384];
    int swzb = xcd_swz(blockIdx.x, nblk);
    int mt = swzb / 6;
    int ft = swzb % 6;
    int em = mt / 25;
    int e = e0 + em;
    int tid = threadIdx.x, lane = tid & 63, wid = tid >> 6;
    int lr8 = lane >> 3, sl = (lane & 7) << 4;
    const char* Ab = (const char*)W2T + ((size_t)e * F_ + (size_t)ft * 128) * (H_ * 2);
    const char* Bb = (const char*)Hg + (size_t)mt * 128 * (H_ * 2);
    f32x4 acc[4][4] = {};
    int swz = (lane & 7) << 4;
    int q16 = (lane >> 4) << 4;

    auto stage = [&](int buf, int it) {
        int kb = it << 7;
        #pragma unroll
        for (int i = 0; i < 4; ++i) {
            int lr = wid * 32 + i * 8 + lr8;
            GLL16(Ab + (size_t)lr * 6144 + kb + sl, ldsA[buf] + (wid * 32 + i * 8) * 128);
            GLL16(Bb + (size_t)lr * 6144 + kb + sl, ldsB[buf] + (wid * 32 + i * 8) * 128);
        }
    };

    stage(0, 0);
    __syncthreads();
    int cur = 0;
    for (int it = 0; it < 48; ++it) {
        if (it < 47) stage(cur ^ 1, it + 1);
        const char* la = ldsA[cur] + ((wid & 1) * 64) * 128;
        const char* lb = ldsB[cur] + ((wid >> 1) * 64) * 128;
        #pragma unroll
        for (int ks = 0; ks < 2; ++ks) {
            bf16x8 af[4], bfr[4];
            int kk = (ks * 64 + q16) ^ swz;
            #pragma unroll
            for (int t = 0; t < 4; ++t) {
                int ro = (16 * t + (lane & 15)) * 128;
                af[t]  = *(const bf16x8*)(la + ro + kk);
                bfr[t] = *(const bf16x8*)(lb + ro + kk);
            }
            #pragma unroll
            for (int ti = 0; ti < 4; ++ti)
                #pragma unroll
                for (int tm = 0; tm < 4; ++tm)
                    acc[ti][tm] = __builtin_amdgcn_mfma_f32_16x16x32_bf16(af[ti], bfr[tm], acc[ti][tm], 0, 0, 0);
        }
        __syncthreads();
        cur ^= 1;
    }
    int fl0 = ft * 128 + (wid & 1) * 64;
    int ml0 = mt * 128 + (wid >> 1) * 64;
    const float* b2p = b2 + (size_t)e * F_;
    float fwv[4]; int mrow[4];
    #pragma unroll
    for (int tm = 0; tm < 4; ++tm) {
        int m = ml0 + 16 * tm + (lane & 15);
        int re = m - em * ME_;
        float fw = 0.f;
        if (re < MR_) {
            int g = re / CAP_;
            int slot = re - g * CAP_;
            int bn = g * N_ + e;
            if (slot < counts[bn]) fw = wts[bn * CAP_ + slot];
        }
        fwv[tm] = fw;
        mrow[tm] = e0 * ME_ + m;
    }
    #pragma unroll
    for (int tf = 0; tf < 4; ++tf) {
        int f = fl0 + 16 * tf + ((lane >> 4) << 2);
        float c0 = b2p[f], c1 = b2p[f + 1], c2 = b2p[f + 2], c3 = b2p[f + 3];
        #pragma unroll
        for (int tm = 0; tm < 4; ++tm) {
            f32x4 a = acc[tf][tm];
            float fw = fwv[tm];
            unsigned int u0 = f2bf(fw * (a[0] + c0)) | ((unsigned)f2bf(fw * (a[1] + c1)) << 16);
            unsigned int u1 = f2bf(fw * (a[2] + c2)) | ((unsigned)f2bf(fw * (a[3] + c3)) << 16);
            *(uint2*)((char*)Og + (size_t)mrow[tm] * (F_ * 2) + f * 2) = make_uint2(u0, u1);
        }
    }
}

// ---------------- combine: out[t,b,:] = sum(og entries) - x ----------------
__global__ __launch_bounds__(256) void k_combine(
        const float* __restrict__ x, const unsigned short* __restrict__ Og,
        const int* __restrict__ ecnt, const int* __restrict__ erow,
        float* __restrict__ out) {
    int idx = blockIdx.x * 256 + threadIdx.x;     // TB_*192 float4 units
    int row = idx / 192, c4 = idx - row * 192;
    float4 s = make_float4(0.f, 0.f, 0.f, 0.f);
    int c = ecnt[row];
    if (c > 0) {
        ushort4 u = *(const ushort4*)(Og + (size_t)erow[row * 2] * F_ + c4 * 4);
        s.x += bf2f(u.x); s.y += bf2f(u.y); s.z += bf2f(u.z); s.w += bf2f(u.w);
    }
    if (c > 1) {
        ushort4 u = *(const ushort4*)(Og + (size_t)erow[row * 2 + 1] * F_ + c4 * 4);
        s.x += bf2f(u.x); s.y += bf2f(u.y); s.z += bf2f(u.z); s.w += bf2f(u.w);
    }
    float4 xv = ((const float4*)x)[idx];
    ((float4*)out)[idx] = make_float4(s.x - xv.x, s.y - xv.y, s.z - xv.z, s.w - xv.w);
}

// ================= round-1 fallback kernels (tiny ws only) =================
__global__ __launch_bounds__(HCF_) void k_fc1(
        const float* __restrict__ x, const float* __restrict__ W1,
        const float* __restrict__ b1, const int* __restrict__ toks,
        const int* __restrict__ counts, __hip_bfloat16* __restrict__ h, int pass) {
    __shared__ float xs[25][F_];
    int tid = threadIdx.x;
    int bn = blockIdx.x >> 1;
    int half = blockIdx.x & 1;
    int r0 = half * 25;
    int b = bn >> 3, n = bn & 7;
    int c = counts[bn];
    for (int idx = tid; idx < 25 * (F_/4); idx += HCF_) {
        int r = idx / (F_/4), k4 = idx % (F_/4);
        int gr = r0 + r;
        float4 val = make_float4(0.f, 0.f, 0.f, 0.f);
        if (gr < c) {
            int t = toks[bn * CAP_ + gr];
            val = ((const float4*)(x + ((size_t)(t * B_ + b)) * F_))[k4];
        }
        ((float4*)&xs[r][0])[k4] = val;
    }
    __syncthreads();
    int j = pass * HCF_ + tid;
    const float* w1p = W1 + (size_t)n * F_ * H_ + j;
    float bias = b1[n * H_ + j];
    float acc[25];
    #pragma unroll
    for (int r = 0; r < 25; ++r) acc[r] = bias;
    const float4* xsv = (const float4*)&xs[0][0];
    for (int k4 = 0; k4 < F_/4; ++k4) {
        float w0 = w1p[(size_t)(4*k4+0) * H_];
        float w1v = w1p[(size_t)(4*k4+1) * H_];
        float w2v = w1p[(size_t)(4*k4+2) * H_];
        float w3v = w1p[(size_t)(4*k4+3) * H_];
        #pragma unroll
        for (int r = 0; r < 25; ++r) {
            float4 xv = xsv[r * (F_/4) + k4];
            acc[r] += xv.x*w0 + xv.y*w1v + xv.z*w2v + xv.w*w3v;
        }
    }
    __hip_bfloat16* hp = h + ((size_t)bn * CAP_ + r0) * HCF_ + tid;
    #pragma unroll
    for (int r = 0; r < 25; ++r) {
        int gr = r0 + r;
        if (gr < CAP_) hp[(size_t)r * HCF_] = __float2bfloat16(fmaxf(acc[r], 0.f));
    }
}

__global__ __launch_bounds__(768) void k_fc2(
        const float* __restrict__ W2, const float* __restrict__ b2,
        const int* __restrict__ toks, const float* __restrict__ wts,
        const int* __restrict__ counts, const __hip_bfloat16* __restrict__ h,
        float* __restrict__ out, int pass) {
    __shared__ float hs[CAP_][HCF_];
    int tid = threadIdx.x;
    int bn = blockIdx.x;
    int c = counts[bn];
    if (c == 0) return;
    int b = bn >> 3, n = bn & 7;
    const ushort4* hv = (const ushort4*)(h + (size_t)bn * CAP_ * HCF_);
    for (int idx = tid; idx < CAP_ * (HCF_/4); idx += 768) {
        ushort4 u = hv[idx];
        float4 fv;
        fv.x = __bfloat162float(*(const __hip_bfloat16*)&u.x);
        fv.y = __bfloat162float(*(const __hip_bfloat16*)&u.y);
        fv.z = __bfloat162float(*(const __hip_bfloat16*)&u.z);
        fv.w = __bfloat162float(*(const __hip_bfloat16*)&u.w);
        ((float4*)&hs[0][0])[idx] = fv;
    }
    __syncthreads();
    int f = tid;
    const float* w2p = W2 + (size_t)n * H_ * F_ + (size_t)(pass * HCF_) * F_ + f;
    float acc[CAP_];
    #pragma unroll
    for (int r = 0; r < CAP_; ++r) acc[r] = 0.f;
    for (int j4 = 0; j4 < HCF_/4; ++j4) {
        float w0 = w2p[(size_t)(4*j4+0) * F_];
        float w1v = w2p[(size_t)(4*j4+1) * F_];
        float w2v = w2p[(size_t)(4*j4+2) * F_];
        float w3v = w2p[(size_t)(4*j4+3) * F_];
        #pragma unroll
        for (int r = 0; r < CAP_; ++r) {
            float4 hh = ((const float4*)&hs[r][0])[j4];
            acc[r] += hh.x*w0 + hh.y*w1v + hh.z*w2v + hh.w*w3v;
        }
    }
    float bias = (pass == 0) ? b2[n * F_ + f] : 0.f;
    #pragma unroll
    for (int r = 0; r < CAP_; ++r) {
        if (r < c) {
            int t = toks[bn * CAP_ + r];
            float fw = wts[bn * CAP_ + r];
            atomicAdd(&out[((size_t)(t * B_ + b)) * F_ + f], fw * (acc[r] + bias));
        }
    }
}

extern "C" void kernel_launch(void* const* d_in, const int* in_sizes, int n_in,
                              void* d_out, int out_size, void* d_ws, size_t ws_size,
                              hipStream_t stream) {
    const float* x   = (const float*)d_in[0];
    const float* Wg1 = (const float*)d_in[1];
    const float* bg1 = (const float*)d_in[2];
    const float* Wg2 = (const float*)d_in[3];
    const float* bg2 = (const float*)d_in[4];
    const float* W1  = (const float*)d_in[5];
    const float* b1  = (const float*)d_in[6];
    const float* W2  = (const float*)d_in[7];
    const float* b2  = (const float*)d_in[8];
    float* out = (float*)d_out;

    // ws layout
    size_t oW1T  = 0;
    size_t oW2T  = oW1T + (size_t)N_ * H_ * F_ * 2;
    size_t oXg   = oW2T + (size_t)N_ * H_ * F_ * 2;
    size_t oCw   = oXg  + (size_t)MT_ * F_ * 2;
    size_t oWts  = oCw  + (size_t)NBN_ * T_ * 4;
    size_t oTok  = oWts + (size_t)NBN_ * CAP_ * 4;
    size_t oCnt  = oTok + (size_t)NBN_ * CAP_ * 4;
    size_t oEcnt = oCnt + (size_t)NBN_ * 4;
    size_t oErow = oEcnt + (size_t)TB_ * 4;
    size_t oOg   = oErow + (size_t)TB_ * 8;
    size_t oHg   = oOg  + (size_t)MT_ * F_ * 2;
    size_t hgPerExpert = (size_t)ME_ * H_ * 2;

    int grp = 0;
    if (ws_size >= oHg + 8 * hgPerExpert) grp = 8;
    else if (ws_size >= oHg + 4 * hgPerExpert) grp = 4;
    else if (ws_size >= oHg + 2 * hgPerExpert) grp = 2;

    if (grp > 0) {
        unsigned short* W1T = (unsigned short*)((char*)d_ws + oW1T);
        unsigned short* W2T = (unsigned short*)((char*)d_ws + oW2T);
        unsigned short* Xg  = (unsigned short*)((char*)d_ws + oXg);
        unsigned short* Og  = (unsigned short*)((char*)d_ws + oOg);
        unsigned short* Hg  = (unsigned short*)((char*)d_ws + oHg);
        float* gs_part = (float*)((char*)d_ws + oHg);   // aliases Hg: dead before gemm1 writes Hg
        float* cw   = (float*)((char*)d_ws + oCw);
        float* wts  = (float*)((char*)d_ws + oWts);
        int* toks   = (int*)((char*)d_ws + oTok);
        int* counts = (int*)((char*)d_ws + oCnt);
        int* ecnt   = (int*)((char*)d_ws + oEcnt);
        int* erow   = (int*)((char*)d_ws + oErow);

        k_gate1<<<197 * 3 * KH_, 256, 0, stream>>>(x, Wg1, gs_part);
        k_gate2<<<TB_ / 32, 256, 0, stream>>>(gs_part, bg1, Wg2, bg2, cw, ecnt);
        k_capacity<<<NBN_, 256, 0, stream>>>(cw, toks, wts, counts, ecnt, erow);
        k_repack<<<N_ * (F_/64) * (H_/64), 256, 0, stream>>>(W1, W1T, F_, H_);
        k_repack<<<N_ * (H_/64) * (F_/64), 256, 0, stream>>>(W2, W2T, H_, F_);
        k_gather<<<(MT_ * 96) / 256, 256, 0, stream>>>(x, toks, counts, Xg);
        for (int e0 = 0; e0 < N_; e0 += grp) {
            int nblk1 = grp * 25 * 24;
            int nblk2 = grp * 25 * 6;
            k_gemm1<<<nblk1, 256, 0, stream>>>(W1T, Xg, b1, Hg, e0, nblk1);
            k_gemm2<<<nblk2, 256, 0, stream>>>(W2T, Hg, b2, wts, counts, Og, e0, nblk2);
        }
        k_combine<<<(TB_ * 192) / 256, 256, 0, stream>>>(x, Og, ecnt, erow, out);
    } else {
        // round-1 fallback (~20 MB ws)
        __hip_bfloat16* h = (__hip_bfloat16*)d_ws;
        float* cw  = (float*)((char*)d_ws + (size_t)NBN_ * CAP_ * HCF_ * 2);
        float* wts = cw + (size_t)NBN_ * T_;
        int* toks  = (int*)(wts + NBN_ * CAP_);
        int* counts = toks + NBN_ * CAP_;
        k_init_out<<<(TB_ * F_) / 1024, 256, 0, stream>>>(x, out);
        k_gate<<<TB_ / 8, 256, 0, stream>>>(x, Wg1, bg1, Wg2, bg2, cw, nullptr);
        k_capacity<<<NBN_, 256, 0, stream>>>(cw, toks, wts, counts, nullptr, nullptr);
        for (int p = 0; p < NPF_; ++p) {
            k_fc1<<<NBN_ * 2, HCF_, 0, stream>>>(x, W1, b1, toks, counts, h, p);
            k_fc2<<<NBN_, 768, 0, stream>>>(W2, b2, toks, wts, counts, h, out, p);
        }
    }
}

// Round 8
// 507.157 us; speedup vs baseline: 12.2419x; 1.0120x over previous
//
#include <hip/hip_runtime.h>
#include <hip/hip_bf16.h>
#include <math.h>
#include <stdint.h>

#define T_ 197
#define B_ 64
#define F_ 768
#define N_ 8
#define CAP_ 49
#define H_ 3072
#define G_ 192
#define TB_ (T_*B_)       // 12608
#define NBN_ (B_*N_)      // 512
#define ME_ 3200          // padded rows per expert (25 * 128)
#define MR_ 3136          // real rows per expert (64 * 49)
#define MT_ 25600         // total padded rows
#define KH_ 4             // gate1 K-split
#define HCF_ 384          // fallback (round-1) H chunk
#define NPF_ 8

using bf16x8 = __attribute__((ext_vector_type(8))) short;
using f32x4  = __attribute__((ext_vector_type(4))) float;

__device__ __forceinline__ unsigned short f2bf(float v) {
    __hip_bfloat16 h = __float2bfloat16(v);
    return __builtin_bit_cast(unsigned short, h);
}
__device__ __forceinline__ float bf2f(unsigned short u) {
    unsigned int w = ((unsigned int)u) << 16;
    return __builtin_bit_cast(float, w);
}

// async global->LDS, 16B per lane; LDS dest = wave-uniform base + lane*16
#define GLL16(g, l) __builtin_amdgcn_global_load_lds( \
    (const __attribute__((address_space(1))) unsigned int*)(uintptr_t)(g), \
    (__attribute__((address_space(3))) unsigned int*)(uintptr_t)(l), 16, 0, 0)

// m204 bijective XCD swizzle
__device__ __forceinline__ int xcd_swz(int bid, int nblk) {
    int q = nblk >> 3, r = nblk & 7;
    int xcd = bid & 7, idx = bid >> 3;
    int base = (xcd < r) ? xcd * (q + 1) : r * (q + 1) + (xcd - r) * q;
    return base + idx;
}

// ---------------- out = -x (fallback path only) ----------------
__global__ void k_init_out(const float* __restrict__ x, float* __restrict__ out) {
    int i = blockIdx.x * blockDim.x + threadIdx.x;
    const float4* xv = (const float4*)x;
    float4* ov = (float4*)out;
    float4 v = xv[i];
    ov[i] = make_float4(-v.x, -v.y, -v.z, -v.w);
}

// ---------------- gate layer1 v3: 64m x 192n per block, K-split 4 ----------------
// a-reads stride-1 (free), b-reads broadcast (free) -> VALU-bound.
// xs transposed [k][m]; wt [k][n] both staged via registers.
__global__ __launch_bounds__(256) void k_gate1(
        const float* __restrict__ x, const float* __restrict__ Wg1,
        float* __restrict__ gs_part) {
    __shared__ float xs[32][68];     // [k][m], pad 68
    __shared__ float wt[32][200];    // [k][n], pad 200
    int bm = blockIdx.x % 197, kh = blockIdx.x / 197;
    int m0 = bm * 64, k0 = kh * (F_ / KH_);
    int tid = threadIdx.x, lane = tid & 63, wid = tid >> 6;
    int mg = lane & 15;              // m-group: rows 4mg..4mg+3
    int ng = (lane >> 4) + 4 * wid;  // n-group: cols 12ng..12ng+11
    f32x4 acc[4][3] = {};            // [mi][jv(4n)]

    int xr = tid >> 3, xc = tid & 7; // x loader: rows xr, xr+32; k-chunk xc
    float4 xreg0, xreg1;
    float4 wreg[6];

    auto loadRegs = [&](int t) {
        int kb = k0 + t * 32;
        xreg0 = *(const float4*)(x + (size_t)(m0 + xr) * F_ + kb + xc * 4);
        xreg1 = *(const float4*)(x + (size_t)(m0 + xr + 32) * F_ + kb + xc * 4);
        #pragma unroll
        for (int i = 0; i < 6; ++i) {
            int idx = tid + i * 256;
            int kr = idx / 48, nc = idx % 48;
            wreg[i] = *(const float4*)(Wg1 + (size_t)(kb + kr) * G_ + nc * 4);
        }
    };
    auto writeLDS = [&]() {
        xs[xc * 4 + 0][xr] = xreg0.x;  xs[xc * 4 + 1][xr] = xreg0.y;
        xs[xc * 4 + 2][xr] = xreg0.z;  xs[xc * 4 + 3][xr] = xreg0.w;
        xs[xc * 4 + 0][xr + 32] = xreg1.x;  xs[xc * 4 + 1][xr + 32] = xreg1.y;
        xs[xc * 4 + 2][xr + 32] = xreg1.z;  xs[xc * 4 + 3][xr + 32] = xreg1.w;
        #pragma unroll
        for (int i = 0; i < 6; ++i) {
            int idx = tid + i * 256;
            int kr = idx / 48, nc = idx % 48;
            *(float4*)&wt[kr][nc * 4] = wreg[i];
        }
    };

    loadRegs(0);
    for (int t = 0; t < 6; ++t) {
        __syncthreads();
        writeLDS();
        __syncthreads();
        if (t < 5) loadRegs(t + 1);
        #pragma unroll
        for (int k = 0; k < 32; ++k) {
            float4 av = *(const float4*)&xs[k][mg * 4];
            float4 b0 = *(const float4*)&wt[k][ng * 12];
            float4 b1 = *(const float4*)&wt[k][ng * 12 + 4];
            float4 b2 = *(const float4*)&wt[k][ng * 12 + 8];
            float am[4] = {av.x, av.y, av.z, av.w};
            #pragma unroll
            for (int mi = 0; mi < 4; ++mi) {
                acc[mi][0][0] += am[mi] * b0.x; acc[mi][0][1] += am[mi] * b0.y;
                acc[mi][0][2] += am[mi] * b0.z; acc[mi][0][3] += am[mi] * b0.w;
                acc[mi][1][0] += am[mi] * b1.x; acc[mi][1][1] += am[mi] * b1.y;
                acc[mi][1][2] += am[mi] * b1.z; acc[mi][1][3] += am[mi] * b1.w;
                acc[mi][2][0] += am[mi] * b2.x; acc[mi][2][1] += am[mi] * b2.y;
                acc[mi][2][2] += am[mi] * b2.z; acc[mi][2][3] += am[mi] * b2.w;
            }
        }
    }
    float* gp = gs_part + (size_t)kh * TB_ * G_;
    #pragma unroll
    for (int mi = 0; mi < 4; ++mi) {
        int r = m0 + mg * 4 + mi;
        #pragma unroll
        for (int jv = 0; jv < 3; ++jv)
            *(f32x4*)(gp + (size_t)r * G_ + ng * 12 + jv * 4) = acc[mi][jv];
    }
}

// ---------------- gate layer2: reduce 4 partials + bias + relu -> logits -> softmax -> top2 ----------------
__global__ __launch_bounds__(256) void k_gate2(
        const float* __restrict__ gs_part, const float* __restrict__ bg1,
        const float* __restrict__ Wg2, const float* __restrict__ bg2,
        float* __restrict__ cw, int* __restrict__ ecnt) {
    __shared__ float gsh[32][200];
    __shared__ float wg2s[G_ * N_];
    __shared__ float lg[32][8];
    int tid = threadIdx.x;
    int id0 = blockIdx.x * 32;

    for (int i = tid; i < 32 * 48; i += 256) {
        int r = i / 48, c4 = i % 48;
        const float* p0 = gs_part + (size_t)(id0 + r) * G_ + c4 * 4;
        float4 a = *(const float4*)p0;
        float4 b = *(const float4*)(p0 + (size_t)TB_ * G_);
        float4 c = *(const float4*)(p0 + 2 * (size_t)TB_ * G_);
        float4 d = *(const float4*)(p0 + 3 * (size_t)TB_ * G_);
        float4 g = *(const float4*)(bg1 + c4 * 4);
        float4 v;
        v.x = fmaxf(a.x + b.x + c.x + d.x + g.x, 0.f);
        v.y = fmaxf(a.y + b.y + c.y + d.y + g.y, 0.f);
        v.z = fmaxf(a.z + b.z + c.z + d.z + g.z, 0.f);
        v.w = fmaxf(a.w + b.w + c.w + d.w + g.w, 0.f);
        ((float4*)&gsh[r][0])[c4] = v;
    }
    for (int i = tid; i < G_ * N_; i += 256) wg2s[i] = Wg2[i];
    __syncthreads();

    int tk = tid >> 3, n = tid & 7;
    float a = bg2[n];
    for (int k = 0; k < G_; ++k) a += gsh[tk][k] * wg2s[k * N_ + n];
    lg[tk][n] = a;
    __syncthreads();

    if (tid < 32) {
        int tk2 = tid;
        float p[8];
        float m = lg[tk2][0];
        #pragma unroll
        for (int nn = 1; nn < 8; ++nn) m = fmaxf(m, lg[tk2][nn]);
        float s = 0.f;
        #pragma unroll
        for (int nn = 0; nn < 8; ++nn) { p[nn] = expf(lg[tk2][nn] - m); s += p[nn]; }
        float inv = 1.f / s;
        #pragma unroll
        for (int nn = 0; nn < 8; ++nn) p[nn] *= inv;
        int i1 = 0; float v1 = p[0];
        #pragma unroll
        for (int nn = 1; nn < 8; ++nn) if (p[nn] > v1) { v1 = p[nn]; i1 = nn; }
        int i2 = -1; float v2 = -1.f;
        #pragma unroll
        for (int nn = 0; nn < 8; ++nn) if (nn != i1 && p[nn] > v2) { v2 = p[nn]; i2 = nn; }
        int id = id0 + tk2;
        int t = id / B_, b = id % B_;
        ecnt[id] = 0;
        #pragma unroll
        for (int nn = 0; nn < 8; ++nn) {
            float v = (nn == i1 || nn == i2) ? p[nn] : 0.f;
            cw[((size_t)(b * N_ + nn)) * T_ + t] = v;
        }
    }
}

// ---------------- gate (fallback path only) ----------------
__global__ __launch_bounds__(256) void k_gate(
        const float* __restrict__ x, const float* __restrict__ Wg1,
        const float* __restrict__ bg1, const float* __restrict__ Wg2,
        const float* __restrict__ bg2, float* __restrict__ cw,
        int* __restrict__ ecnt) {
    __shared__ float xsh[8][F_];
    __shared__ float gsl[8][G_];
    __shared__ float lg[8][N_];
    int tid = threadIdx.x;
    int id0 = blockIdx.x * 8;

    int gid = blockIdx.x * 256 + tid;
    if (gid < TB_ && ecnt) ecnt[gid] = 0;

    const float4* xv = (const float4*)(x + (size_t)id0 * F_);
    float4* xshv = (float4*)&xsh[0][0];
    for (int idx = tid; idx < 8 * (F_/4); idx += 256) xshv[idx] = xv[idx];
    __syncthreads();

    if (tid < G_) {
        float acc[8];
        float bb = bg1[tid];
        #pragma unroll
        for (int tk = 0; tk < 8; ++tk) acc[tk] = bb;
        for (int k = 0; k < F_; ++k) {
            float w = Wg1[k * G_ + tid];
            #pragma unroll
            for (int tk = 0; tk < 8; ++tk) acc[tk] += xsh[tk][k] * w;
        }
        #pragma unroll
        for (int tk = 0; tk < 8; ++tk) gsl[tk][tid] = fmaxf(acc[tk], 0.f);
    }
    __syncthreads();

    if (tid < 64) {
        int tk = tid >> 3, n = tid & 7;
        float acc = bg2[n];
        for (int k = 0; k < G_; ++k) acc += gsl[tk][k] * Wg2[k * N_ + n];
        lg[tk][n] = acc;
    }
    __syncthreads();

    if (tid < 8) {
        int tk = tid;
        float p[8];
        float m = lg[tk][0];
        #pragma unroll
        for (int n = 1; n < 8; ++n) m = fmaxf(m, lg[tk][n]);
        float s = 0.f;
        #pragma unroll
        for (int n = 0; n < 8; ++n) { p[n] = expf(lg[tk][n] - m); s += p[n]; }
        float inv = 1.f / s;
        #pragma unroll
        for (int n = 0; n < 8; ++n) p[n] *= inv;
        int i1 = 0; float v1 = p[0];
        #pragma unroll
        for (int n = 1; n < 8; ++n) if (p[n] > v1) { v1 = p[n]; i1 = n; }
        int i2 = -1; float v2 = -1.f;
        #pragma unroll
        for (int n = 0; n < 8; ++n) if (n != i1 && p[n] > v2) { v2 = p[n]; i2 = n; }
        int id = id0 + tk;
        int t = id / B_, b = id % B_;
        #pragma unroll
        for (int n = 0; n < 8; ++n) {
            float v = (n == i1 || n == i2) ? p[n] : 0.f;
            cw[((size_t)(b * N_ + n)) * T_ + t] = v;
        }
    }
}

// ---------------- capacity: exact top-CAP rank per (b,n); builds inverse map ----------------
__global__ __launch_bounds__(256) void k_capacity(
        const float* __restrict__ cw, int* __restrict__ toks,
        float* __restrict__ wts, int* __restrict__ counts,
        int* __restrict__ ecnt, int* __restrict__ erow) {
    __shared__ float v[T_];
    __shared__ int keep[T_];
    int tid = threadIdx.x;
    int bn = blockIdx.x;
    int b = bn >> 3, n = bn & 7;
    if (tid < T_) v[tid] = cw[(size_t)bn * T_ + tid];
    __syncthreads();
    int kp = 0; float my = 0.f;
    if (tid < T_) {
        my = v[tid];
        int rank = 0;
        for (int t2 = 0; t2 < T_; ++t2) {
            float vt = v[t2];
            rank += (vt > my) || (vt == my && t2 < tid);
        }
        kp = (rank < CAP_) && (my > 0.f);
    }
    if (tid < T_) keep[tid] = kp;
    __syncthreads();
    if (tid < T_ && kp) {
        int slot = 0;
        for (int t2 = 0; t2 < T_; ++t2) slot += (t2 < tid) ? keep[t2] : 0;
        toks[bn * CAP_ + slot] = tid;
        wts[bn * CAP_ + slot] = my;
        if (ecnt) {
            int orow = tid * B_ + b;
            int pos = atomicAdd(&ecnt[orow], 1);
            erow[orow * 2 + pos] = n * ME_ + b * CAP_ + slot;
        }
    }
    if (tid == 0) {
        int tot = 0;
        for (int t2 = 0; t2 < T_; ++t2) tot += keep[t2];
        counts[bn] = tot;
    }
}

// ---------------- repack W [E][K][J] fp32 -> WT [E][J][K] bf16, pre-swizzled ----------------
__global__ __launch_bounds__(256) void k_repack(
        const float* __restrict__ W, unsigned short* __restrict__ WT, int K, int J) {
    __shared__ float tile[64][65];
    int bid = blockIdx.x;
    int nk = K >> 6, nj = J >> 6;
    int kt = bid % nk; bid /= nk;
    int jt = bid % nj; int e = bid / nj;
    int k0 = kt * 64, j0 = jt * 64;
    int tid = threadIdx.x;
    int jr = (tid & 15) << 2;
    int kr = tid >> 4;
    const float* src = W + ((size_t)e * K + k0) * J + j0;
    #pragma unroll
    for (int i = 0; i < 4; ++i) {
        float4 v = *(const float4*)(src + (size_t)(kr + 16 * i) * J + jr);
        *(float4*)&tile[kr + 16 * i][jr] = v;
    }
    __syncthreads();
    int c = tid & 7;
    int jrow = tid >> 3;
    #pragma unroll
    for (int i = 0; i < 2; ++i) {
        int j = jrow + 32 * i;
        float f[8];
        #pragma unroll
        for (int s = 0; s < 8; ++s) f[s] = tile[c * 8 + s][j];
        uint4 u;
        u.x = f2bf(f[0]) | ((unsigned)f2bf(f[1]) << 16);
        u.y = f2bf(f[2]) | ((unsigned)f2bf(f[3]) << 16);
        u.z = f2bf(f[4]) | ((unsigned)f2bf(f[5]) << 16);
        u.w = f2bf(f[6]) | ((unsigned)f2bf(f[7]) << 16);
        int jg = j0 + j;
        char* drow = (char*)WT + ((size_t)e * J + jg) * (size_t)K * 2 + (size_t)(k0 >> 6) * 128;
        *(uint4*)(drow + ((c << 4) ^ ((jg & 7) << 4))) = u;
    }
}

// ---------------- gather x rows -> Xg [MT_][768] bf16, pre-swizzled, zero-padded ----------------
__global__ __launch_bounds__(256) void k_gather(
        const float* __restrict__ x, const int* __restrict__ toks,
        const int* __restrict__ counts, unsigned short* __restrict__ Xg) {
    int gi = blockIdx.x * 256 + threadIdx.x;
    int R = gi / 96, c = gi - R * 96;
    int e = R / ME_, re = R - e * ME_;
    uint4 val = make_uint4(0u, 0u, 0u, 0u);
    if (re < MR_) {
        int g = re / CAP_, slot = re - g * CAP_;
        int bn = g * N_ + e;
        if (slot < counts[bn]) {
            int t = toks[bn * CAP_ + slot];
            const float* xp = x + ((size_t)t * B_ + g) * F_ + c * 8;
            float4 v0 = *(const float4*)xp;
            float4 v1 = *(const float4*)(xp + 4);
            val.x = f2bf(v0.x) | ((unsigned)f2bf(v0.y) << 16);
            val.y = f2bf(v0.z) | ((unsigned)f2bf(v0.w) << 16);
            val.z = f2bf(v1.x) | ((unsigned)f2bf(v1.y) << 16);
            val.w = f2bf(v1.z) | ((unsigned)f2bf(v1.w) << 16);
        }
    }
    int w = (c * 16) & 127;
    char* dst = (char*)Xg + (size_t)R * 1536 + (c >> 3) * 128 + (w ^ ((R & 7) << 4));
    *(uint4*)dst = val;
}

// ---------------- GEMM1: Hg = relu(W1T . Xg^T + b1), 2-phase dbuf, LDS-transposed epilogue ----------------
__global__ __launch_bounds__(256) void k_gemm1(
        const unsigned short* __restrict__ W1T, const unsigned short* __restrict__ Xg,
        const float* __restrict__ b1, unsigned short* __restrict__ Hg,
        int e0, int nblk) {
    __shared__ char ldsA[2][16384];
    __shared__ char ldsB[2][16384];
    int swzb = xcd_swz(blockIdx.x, nblk);
    int mt = swzb / 24;
    int jt = swzb % 24;
    int em = mt / 25;
    int e = e0 + em;
    int tid = threadIdx.x, lane = tid & 63, wid = tid >> 6;
    int lr8 = lane >> 3, sl = (lane & 7) << 4;
    const char* Ab = (const char*)W1T + ((size_t)e * H_ + (size_t)jt * 128) * (F_ * 2);
    const char* Bb = (const char*)Xg + ((size_t)e * ME_ + (size_t)(mt % 25) * 128) * (F_ * 2);
    f32x4 acc[4][4] = {};
    int swz = (lane & 7) << 4;
    int q16 = (lane >> 4) << 4;

    auto stage = [&](int buf, int it) {
        int kb = it << 7;
        #pragma unroll
        for (int i = 0; i < 4; ++i) {
            int lr = wid * 32 + i * 8 + lr8;
            GLL16(Ab + (size_t)lr * 1536 + kb + sl, ldsA[buf] + (wid * 32 + i * 8) * 128);
            GLL16(Bb + (size_t)lr * 1536 + kb + sl, ldsB[buf] + (wid * 32 + i * 8) * 128);
        }
    };

    stage(0, 0);
    __syncthreads();
    int cur = 0;
    for (int it = 0; it < 12; ++it) {
        if (it < 11) stage(cur ^ 1, it + 1);
        const char* la = ldsA[cur] + ((wid & 1) * 64) * 128;
        const char* lb = ldsB[cur] + ((wid >> 1) * 64) * 128;
        #pragma unroll
        for (int ks = 0; ks < 2; ++ks) {
            bf16x8 af[4], bfr[4];
            int kk = (ks * 64 + q16) ^ swz;
            #pragma unroll
            for (int t = 0; t < 4; ++t) {
                int ro = (16 * t + (lane & 15)) * 128;
                af[t]  = *(const bf16x8*)(la + ro + kk);
                bfr[t] = *(const bf16x8*)(lb + ro + kk);
            }
            #pragma unroll
            for (int ti = 0; ti < 4; ++ti)
                #pragma unroll
                for (int tm = 0; tm < 4; ++tm)
                    acc[ti][tm] = __builtin_amdgcn_mfma_f32_16x16x32_bf16(af[ti], bfr[tm], acc[ti][tm], 0, 0, 0);
        }
        __syncthreads();
        cur ^= 1;
    }
    // epilogue: bias+relu -> bf16 into LDS tile (exact Hg byte layout incl. swizzle), then coalesced copy
    char* tile = &ldsA[0][0];                     // 32 KB = 128 x 256B
    int jl0 = (wid & 1) * 64;
    int ml0 = (wid >> 1) * 64;
    const float* b1p = b1 + (size_t)e * H_ + (size_t)jt * 128;
    #pragma unroll
    for (int tj = 0; tj < 4; ++tj) {
        int jc = jl0 + 16 * tj + ((lane >> 4) << 2);       // local col 0..127
        float bb0 = b1p[jc], bb1 = b1p[jc + 1], bb2 = b1p[jc + 2], bb3 = b1p[jc + 3];
        #pragma unroll
        for (int tm = 0; tm < 4; ++tm) {
            int m = ml0 + 16 * tm + (lane & 15);           // local row 0..127
            f32x4 a = acc[tj][tm];
            unsigned int u0 = f2bf(fmaxf(a[0] + bb0, 0.f)) | ((unsigned)f2bf(fmaxf(a[1] + bb1, 0.f)) << 16);
            unsigned int u1 = f2bf(fmaxf(a[2] + bb2, 0.f)) | ((unsigned)f2bf(fmaxf(a[3] + bb3, 0.f)) << 16);
            int bcol = jc * 2;
            int w = bcol & 127;
            *(uint2*)(tile + m * 256 + (bcol & ~127) + (w ^ ((m & 7) << 4))) = make_uint2(u0, u1);
        }
    }
    __syncthreads();
    char* Hrow = (char*)Hg + (size_t)(mt * 128) * (H_ * 2) + (size_t)jt * 256;
    #pragma unroll
    for (int i = 0; i < 8; ++i) {
        int idx = tid + i * 256;
        int r = idx >> 4, c = (idx & 15) << 4;
        *(uint4*)(Hrow + (size_t)r * (H_ * 2) + c) = *(const uint4*)(tile + r * 256 + c);
    }
}

// ---------------- GEMM2: Og = fw * (W2T . Hg^T + b2), 2-phase dbuf, LDS-transposed epilogue ----------------
__global__ __launch_bounds__(256) void k_gemm2(
        const unsigned short* __restrict__ W2T, const unsigned short* __restrict__ Hg,
        const float* __restrict__ b2, const float* __restrict__ wts,
        const int* __restrict__ counts, unsigned short* __restrict__ Og,
        int e0, int nblk) {
    __shared__ char ldsA[2][16384];
    __shared__ char ldsB[2][16384];
    int swzb = xcd_swz(blockIdx.x, nblk);
    int mt = swzb / 6;
    int ft = swzb % 6;
    int em = mt / 25;
    int e = e0 + em;
    int tid = threadIdx.x, lane = tid & 63, wid = tid >> 6;
    int lr8 = lane >> 3, sl = (lane & 7) << 4;
    const char* Ab = (const char*)W2T + ((size_t)e * F_ + (size_t)ft * 128) * (H_ * 2);
    const char* Bb = (const char*)Hg + (size_t)mt * 128 * (H_ * 2);
    f32x4 acc[4][4] = {};
    int swz = (lane & 7) << 4;
    int q16 = (lane >> 4) << 4;

    auto stage = [&](int buf, int it) {
        int kb = it << 7;
        #pragma unroll
        for (int i = 0; i < 4; ++i) {
            int lr = wid * 32 + i * 8 + lr8;
            GLL16(Ab + (size_t)lr * 6144 + kb + sl, ldsA[buf] + (wid * 32 + i * 8) * 128);
            GLL16(Bb + (size_t)lr * 6144 + kb + sl, ldsB[buf] + (wid * 32 + i * 8) * 128);
        }
    };

    stage(0, 0);
    __syncthreads();
    int cur = 0;
    for (int it = 0; it < 48; ++it) {
        if (it < 47) stage(cur ^ 1, it + 1);
        const char* la = ldsA[cur] + ((wid & 1) * 64) * 128;
        const char* lb = ldsB[cur] + ((wid >> 1) * 64) * 128;
        #pragma unroll
        for (int ks = 0; ks < 2; ++ks) {
            bf16x8 af[4], bfr[4];
            int kk = (ks * 64 + q16) ^ swz;
            #pragma unroll
            for (int t = 0; t < 4; ++t) {
                int ro = (16 * t + (lane & 15)) * 128;
                af[t]  = *(const bf16x8*)(la + ro + kk);
                bfr[t] = *(const bf16x8*)(lb + ro + kk);
            }
            #pragma unroll
            for (int ti = 0; ti < 4; ++ti)
                #pragma unroll
                for (int tm = 0; tm < 4; ++tm)
                    acc[ti][tm] = __builtin_amdgcn_mfma_f32_16x16x32_bf16(af[ti], bfr[tm], acc[ti][tm], 0, 0, 0);
        }
        __syncthreads();
        cur ^= 1;
    }
    // epilogue: fw*(acc+b2) -> bf16 into swizzled LDS tile, then unswizzled coalesced copy
    char* tile = &ldsA[0][0];
    int fl0 = (wid & 1) * 64;
    int ml0 = (wid >> 1) * 64;
    const float* b2p = b2 + (size_t)e * F_ + (size_t)ft * 128;
    float fwv[4];
    #pragma unroll
    for (int tm = 0; tm < 4; ++tm) {
        int mloc = ml0 + 16 * tm + (lane & 15);
        int re = mt * 128 + mloc - em * ME_;
        float fw = 0.f;
        if (re < MR_) {
            int g = re / CAP_;
            int slot = re - g * CAP_;
            int bn = g * N_ + e;
            if (slot < counts[bn]) fw = wts[bn * CAP_ + slot];
        }
        fwv[tm] = fw;
    }
    #pragma unroll
    for (int tf = 0; tf < 4; ++tf) {
        int fc = fl0 + 16 * tf + ((lane >> 4) << 2);        // local col 0..127
        float c0 = b2p[fc], c1 = b2p[fc + 1], c2 = b2p[fc + 2], c3 = b2p[fc + 3];
        #pragma unroll
        for (int tm = 0; tm < 4; ++tm) {
            int mloc = ml0 + 16 * tm + (lane & 15);
            f32x4 a = acc[tf][tm];
            float fw = fwv[tm];
            unsigned int u0 = f2bf(fw * (a[0] + c0)) | ((unsigned)f2bf(fw * (a[1] + c1)) << 16);
            unsigned int u1 = f2bf(fw * (a[2] + c2)) | ((unsigned)f2bf(fw * (a[3] + c3)) << 16);
            int bcol = fc * 2;
            int w = bcol & 127;
            *(uint2*)(tile + mloc * 256 + (bcol & ~127) + (w ^ ((mloc & 7) << 4))) = make_uint2(u0, u1);
        }
    }
    __syncthreads();
    char* Orow = (char*)Og + ((size_t)(e0 * ME_ + mt * 128)) * (F_ * 2) + (size_t)ft * 256;
    #pragma unroll
    for (int i = 0; i < 8; ++i) {
        int idx = tid + i * 256;
        int r = idx >> 4, c = (idx & 15) << 4;
        const char* src = tile + r * 256 + (c & ~127) + ((c & 127) ^ ((r & 7) << 4));
        *(uint4*)(Orow + (size_t)r * (F_ * 2) + c) = *(const uint4*)src;
    }
}

// ---------------- combine: out[t,b,:] = sum(og entries) - x ----------------
__global__ __launch_bounds__(256) void k_combine(
        const float* __restrict__ x, const unsigned short* __restrict__ Og,
        const int* __restrict__ ecnt, const int* __restrict__ erow,
        float* __restrict__ out) {
    int idx = blockIdx.x * 256 + threadIdx.x;
    int row = idx / 192, c4 = idx - row * 192;
    float4 s = make_float4(0.f, 0.f, 0.f, 0.f);
    int c = ecnt[row];
    if (c > 0) {
        ushort4 u = *(const ushort4*)(Og + (size_t)erow[row * 2] * F_ + c4 * 4);
        s.x += bf2f(u.x); s.y += bf2f(u.y); s.z += bf2f(u.z); s.w += bf2f(u.w);
    }
    if (c > 1) {
        ushort4 u = *(const ushort4*)(Og + (size_t)erow[row * 2 + 1] * F_ + c4 * 4);
        s.x += bf2f(u.x); s.y += bf2f(u.y); s.z += bf2f(u.z); s.w += bf2f(u.w);
    }
    float4 xv = ((const float4*)x)[idx];
    ((float4*)out)[idx] = make_float4(s.x - xv.x, s.y - xv.y, s.z - xv.z, s.w - xv.w);
}

// ================= round-1 fallback kernels (tiny ws only) =================
__global__ __launch_bounds__(HCF_) void k_fc1(
        const float* __restrict__ x, const float* __restrict__ W1,
        const float* __restrict__ b1, const int* __restrict__ toks,
        const int* __restrict__ counts, __hip_bfloat16* __restrict__ h, int pass) {
    __shared__ float xs[25][F_];
    int tid = threadIdx.x;
    int bn = blockIdx.x >> 1;
    int half = blockIdx.x & 1;
    int r0 = half * 25;
    int b = bn >> 3, n = bn & 7;
    int c = counts[bn];
    for (int idx = tid; idx < 25 * (F_/4); idx += HCF_) {
        int r = idx / (F_/4), k4 = idx % (F_/4);
        int gr = r0 + r;
        float4 val = make_float4(0.f, 0.f, 0.f, 0.f);
        if (gr < c) {
            int t = toks[bn * CAP_ + gr];
            val = ((const float4*)(x + ((size_t)(t * B_ + b)) * F_))[k4];
        }
        ((float4*)&xs[r][0])[k4] = val;
    }
    __syncthreads();
    int j = pass * HCF_ + tid;
    const float* w1p = W1 + (size_t)n * F_ * H_ + j;
    float bias = b1[n * H_ + j];
    float acc[25];
    #pragma unroll
    for (int r = 0; r < 25; ++r) acc[r] = bias;
    const float4* xsv = (const float4*)&xs[0][0];
    for (int k4 = 0; k4 < F_/4; ++k4) {
        float w0 = w1p[(size_t)(4*k4+0) * H_];
        float w1v = w1p[(size_t)(4*k4+1) * H_];
        float w2v = w1p[(size_t)(4*k4+2) * H_];
        float w3v = w1p[(size_t)(4*k4+3) * H_];
        #pragma unroll
        for (int r = 0; r < 25; ++r) {
            float4 xv = xsv[r * (F_/4) + k4];
            acc[r] += xv.x*w0 + xv.y*w1v + xv.z*w2v + xv.w*w3v;
        }
    }
    __hip_bfloat16* hp = h + ((size_t)bn * CAP_ + r0) * HCF_ + tid;
    #pragma unroll
    for (int r = 0; r < 25; ++r) {
        int gr = r0 + r;
        if (gr < CAP_) hp[(size_t)r * HCF_] = __float2bfloat16(fmaxf(acc[r], 0.f));
    }
}

__global__ __launch_bounds__(768) void k_fc2(
        const float* __restrict__ W2, const float* __restrict__ b2,
        const int* __restrict__ toks, const float* __restrict__ wts,
        const int* __restrict__ counts, const __hip_bfloat16* __restrict__ h,
        float* __restrict__ out, int pass) {
    __shared__ float hs[CAP_][HCF_];
    int tid = threadIdx.x;
    int bn = blockIdx.x;
    int c = counts[bn];
    if (c == 0) return;
    int b = bn >> 3, n = bn & 7;
    const ushort4* hv = (const ushort4*)(h + (size_t)bn * CAP_ * HCF_);
    for (int idx = tid; idx < CAP_ * (HCF_/4); idx += 768) {
        ushort4 u = hv[idx];
        float4 fv;
        fv.x = __bfloat162float(*(const __hip_bfloat16*)&u.x);
        fv.y = __bfloat162float(*(const __hip_bfloat16*)&u.y);
        fv.z = __bfloat162float(*(const __hip_bfloat16*)&u.z);
        fv.w = __bfloat162float(*(const __hip_bfloat16*)&u.w);
        ((float4*)&hs[0][0])[idx] = fv;
    }
    __syncthreads();
    int f = tid;
    const float* w2p = W2 + (size_t)n * H_ * F_ + (size_t)(pass * HCF_) * F_ + f;
    float acc[CAP_];
    #pragma unroll
    for (int r = 0; r < CAP_; ++r) acc[r] = 0.f;
    for (int j4 = 0; j4 < HCF_/4; ++j4) {
        float w0 = w2p[(size_t)(4*j4+0) * F_];
        float w1v = w2p[(size_t)(4*j4+1) * F_];
        float w2v = w2p[(size_t)(4*j4+2) * F_];
        float w3v = w2p[(size_t)(4*j4+3) * F_];
        #pragma unroll
        for (int r = 0; r < CAP_; ++r) {
            float4 hh = ((const float4*)&hs[r][0])[j4];
            acc[r] += hh.x*w0 + hh.y*w1v + hh.z*w2v + hh.w*w3v;
        }
    }
    float bias = (pass == 0) ? b2[n * F_ + f] : 0.f;
    #pragma unroll
    for (int r = 0; r < CAP_; ++r) {
        if (r < c) {
            int t = toks[bn * CAP_ + r];
            float fw = wts[bn * CAP_ + r];
            atomicAdd(&out[((size_t)(t * B_ + b)) * F_ + f], fw * (acc[r] + bias));
        }
    }
}

extern "C" void kernel_launch(void* const* d_in, const int* in_sizes, int n_in,
                              void* d_out, int out_size, void* d_ws, size_t ws_size,
                              hipStream_t stream) {
    const float* x   = (const float*)d_in[0];
    const float* Wg1 = (const float*)d_in[1];
    const float* bg1 = (const float*)d_in[2];
    const float* Wg2 = (const float*)d_in[3];
    const float* bg2 = (const float*)d_in[4];
    const float* W1  = (const float*)d_in[5];
    const float* b1  = (const float*)d_in[6];
    const float* W2  = (const float*)d_in[7];
    const float* b2  = (const float*)d_in[8];
    float* out = (float*)d_out;

    // ws layout
    size_t oW1T  = 0;
    size_t oW2T  = oW1T + (size_t)N_ * H_ * F_ * 2;
    size_t oXg   = oW2T + (size_t)N_ * H_ * F_ * 2;
    size_t oCw   = oXg  + (size_t)MT_ * F_ * 2;
    size_t oWts  = oCw  + (size_t)NBN_ * T_ * 4;
    size_t oTok  = oWts + (size_t)NBN_ * CAP_ * 4;
    size_t oCnt  = oTok + (size_t)NBN_ * CAP_ * 4;
    size_t oEcnt = oCnt + (size_t)NBN_ * 4;
    size_t oErow = oEcnt + (size_t)TB_ * 4;
    size_t oOg   = oErow + (size_t)TB_ * 8;
    size_t oHg   = oOg  + (size_t)MT_ * F_ * 2;
    size_t hgPerExpert = (size_t)ME_ * H_ * 2;

    int grp = 0;
    if (ws_size >= oHg + 8 * hgPerExpert) grp = 8;
    else if (ws_size >= oHg + 4 * hgPerExpert) grp = 4;
    else if (ws_size >= oHg + 2 * hgPerExpert) grp = 2;

    if (grp > 0) {
        unsigned short* W1T = (unsigned short*)((char*)d_ws + oW1T);
        unsigned short* W2T = (unsigned short*)((char*)d_ws + oW2T);
        unsigned short* Xg  = (unsigned short*)((char*)d_ws + oXg);
        unsigned short* Og  = (unsigned short*)((char*)d_ws + oOg);
        unsigned short* Hg  = (unsigned short*)((char*)d_ws + oHg);
        float* gs_part = (float*)((char*)d_ws + oHg);   // aliases Hg: dead before gemm1 writes Hg
        float* cw   = (float*)((char*)d_ws + oCw);
        float* wts  = (float*)((char*)d_ws + oWts);
        int* toks   = (int*)((char*)d_ws + oTok);
        int* counts = (int*)((char*)d_ws + oCnt);
        int* ecnt   = (int*)((char*)d_ws + oEcnt);
        int* erow   = (int*)((char*)d_ws + oErow);

        k_gate1<<<197 * KH_, 256, 0, stream>>>(x, Wg1, gs_part);
        k_gate2<<<TB_ / 32, 256, 0, stream>>>(gs_part, bg1, Wg2, bg2, cw, ecnt);
        k_capacity<<<NBN_, 256, 0, stream>>>(cw, toks, wts, counts, ecnt, erow);
        k_repack<<<N_ * (F_/64) * (H_/64), 256, 0, stream>>>(W1, W1T, F_, H_);
        k_repack<<<N_ * (H_/64) * (F_/64), 256, 0, stream>>>(W2, W2T, H_, F_);
        k_gather<<<(MT_ * 96) / 256, 256, 0, stream>>>(x, toks, counts, Xg);
        for (int e0 = 0; e0 < N_; e0 += grp) {
            int nblk1 = grp * 25 * 24;
            int nblk2 = grp * 25 * 6;
            k_gemm1<<<nblk1, 256, 0, stream>>>(W1T, Xg, b1, Hg, e0, nblk1);
            k_gemm2<<<nblk2, 256, 0, stream>>>(W2T, Hg, b2, wts, counts, Og, e0, nblk2);
        }
        k_combine<<<(TB_ * 192) / 256, 256, 0, stream>>>(x, Og, ecnt, erow, out);
    } else {
        // round-1 fallback (~20 MB ws)
        __hip_bfloat16* h = (__hip_bfloat16*)d_ws;
        float* cw  = (float*)((char*)d_ws + (size_t)NBN_ * CAP_ * HCF_ * 2);
        float* wts = cw + (size_t)NBN_ * T_;
        int* toks  = (int*)(wts + NBN_ * CAP_);
        int* counts = toks + NBN_ * CAP_;
        k_init_out<<<(TB_ * F_) / 1024, 256, 0, stream>>>(x, out);
        k_gate<<<TB_ / 8, 256, 0, stream>>>(x, Wg1, bg1, Wg2, bg2, cw, nullptr);
        k_capacity<<<NBN_, 256, 0, stream>>>(cw, toks, wts, counts, nullptr, nullptr);
        for (int p = 0; p < NPF_; ++p) {
            k_fc1<<<NBN_ * 2, HCF_, 0, stream>>>(x, W1, b1, toks, counts, h, p);
            k_fc2<<<NBN_, 768, 0, stream>>>(W2, b2, toks, wts, counts, h, out, p);
        }
    }
}

// Round 9
// 506.951 us; speedup vs baseline: 12.2468x; 1.0004x over previous
//
#include <hip/hip_runtime.h>
#include <hip/hip_bf16.h>
#include <math.h>
#include <stdint.h>

#define T_ 197
#define B_ 64
#define F_ 768
#define N_ 8
#define CAP_ 49
#define H_ 3072
#define G_ 192
#define TB_ (T_*B_)       // 12608
#define NBN_ (B_*N_)      // 512
#define ME_ 3200          // padded rows per expert (25 * 128)
#define MR_ 3136          // real rows per expert (64 * 49)
#define MT_ 25600         // total padded rows
#define KH_ 4             // gate1 K-split
#define HP_ 768           // GEMM H-pass chunk (4 passes)
#define NBLK_ 1200        // 8 experts x 25 mt x 6 col-tiles
#define HCF_ 384          // fallback (round-1) H chunk
#define NPF_ 8

using bf16x8 = __attribute__((ext_vector_type(8))) short;
using f32x4  = __attribute__((ext_vector_type(4))) float;

__device__ __forceinline__ unsigned short f2bf(float v) {
    __hip_bfloat16 h = __float2bfloat16(v);
    return __builtin_bit_cast(unsigned short, h);
}
__device__ __forceinline__ float bf2f(unsigned short u) {
    unsigned int w = ((unsigned int)u) << 16;
    return __builtin_bit_cast(float, w);
}
__device__ __forceinline__ unsigned int add2bf(unsigned int a, unsigned int b) {
    float al = bf2f((unsigned short)(a & 0xffff)), ah = bf2f((unsigned short)(a >> 16));
    float bl = bf2f((unsigned short)(b & 0xffff)), bh = bf2f((unsigned short)(b >> 16));
    return (unsigned int)f2bf(al + bl) | ((unsigned int)f2bf(ah + bh) << 16);
}

// async global->LDS, 16B per lane; LDS dest = wave-uniform base + lane*16
#define GLL16(g, l) __builtin_amdgcn_global_load_lds( \
    (const __attribute__((address_space(1))) unsigned int*)(uintptr_t)(g), \
    (__attribute__((address_space(3))) unsigned int*)(uintptr_t)(l), 16, 0, 0)

// m204 bijective XCD swizzle
__device__ __forceinline__ int xcd_swz(int bid, int nblk) {
    int q = nblk >> 3, r = nblk & 7;
    int xcd = bid & 7, idx = bid >> 3;
    int base = (xcd < r) ? xcd * (q + 1) : r * (q + 1) + (xcd - r) * q;
    return base + idx;
}

// ---------------- out = -x (fallback path only) ----------------
__global__ void k_init_out(const float* __restrict__ x, float* __restrict__ out) {
    int i = blockIdx.x * blockDim.x + threadIdx.x;
    const float4* xv = (const float4*)x;
    float4* ov = (float4*)out;
    float4 v = xv[i];
    ov[i] = make_float4(-v.x, -v.y, -v.z, -v.w);
}

// ---------------- gate layer1 v3: 64m x 192n per block, K-split 4 ----------------
__global__ __launch_bounds__(256) void k_gate1(
        const float* __restrict__ x, const float* __restrict__ Wg1,
        float* __restrict__ gs_part) {
    __shared__ float xs[32][68];     // [k][m], pad 68
    __shared__ float wt[32][200];    // [k][n], pad 200
    int bm = blockIdx.x % 197, kh = blockIdx.x / 197;
    int m0 = bm * 64, k0 = kh * (F_ / KH_);
    int tid = threadIdx.x, lane = tid & 63, wid = tid >> 6;
    int mg = lane & 15;
    int ng = (lane >> 4) + 4 * wid;
    f32x4 acc[4][3] = {};

    int xr = tid >> 3, xc = tid & 7;
    float4 xreg0, xreg1;
    float4 wreg[6];

    auto loadRegs = [&](int t) {
        int kb = k0 + t * 32;
        xreg0 = *(const float4*)(x + (size_t)(m0 + xr) * F_ + kb + xc * 4);
        xreg1 = *(const float4*)(x + (size_t)(m0 + xr + 32) * F_ + kb + xc * 4);
        #pragma unroll
        for (int i = 0; i < 6; ++i) {
            int idx = tid + i * 256;
            int kr = idx / 48, nc = idx % 48;
            wreg[i] = *(const float4*)(Wg1 + (size_t)(kb + kr) * G_ + nc * 4);
        }
    };
    auto writeLDS = [&]() {
        xs[xc * 4 + 0][xr] = xreg0.x;  xs[xc * 4 + 1][xr] = xreg0.y;
        xs[xc * 4 + 2][xr] = xreg0.z;  xs[xc * 4 + 3][xr] = xreg0.w;
        xs[xc * 4 + 0][xr + 32] = xreg1.x;  xs[xc * 4 + 1][xr + 32] = xreg1.y;
        xs[xc * 4 + 2][xr + 32] = xreg1.z;  xs[xc * 4 + 3][xr + 32] = xreg1.w;
        #pragma unroll
        for (int i = 0; i < 6; ++i) {
            int idx = tid + i * 256;
            int kr = idx / 48, nc = idx % 48;
            *(float4*)&wt[kr][nc * 4] = wreg[i];
        }
    };

    loadRegs(0);
    for (int t = 0; t < 6; ++t) {
        __syncthreads();
        writeLDS();
        __syncthreads();
        if (t < 5) loadRegs(t + 1);
        #pragma unroll
        for (int k = 0; k < 32; ++k) {
            float4 av = *(const float4*)&xs[k][mg * 4];
            float4 b0 = *(const float4*)&wt[k][ng * 12];
            float4 b1 = *(const float4*)&wt[k][ng * 12 + 4];
            float4 b2 = *(const float4*)&wt[k][ng * 12 + 8];
            float am[4] = {av.x, av.y, av.z, av.w};
            #pragma unroll
            for (int mi = 0; mi < 4; ++mi) {
                acc[mi][0][0] += am[mi] * b0.x; acc[mi][0][1] += am[mi] * b0.y;
                acc[mi][0][2] += am[mi] * b0.z; acc[mi][0][3] += am[mi] * b0.w;
                acc[mi][1][0] += am[mi] * b1.x; acc[mi][1][1] += am[mi] * b1.y;
                acc[mi][1][2] += am[mi] * b1.z; acc[mi][1][3] += am[mi] * b1.w;
                acc[mi][2][0] += am[mi] * b2.x; acc[mi][2][1] += am[mi] * b2.y;
                acc[mi][2][2] += am[mi] * b2.z; acc[mi][2][3] += am[mi] * b2.w;
            }
        }
    }
    float* gp = gs_part + (size_t)kh * TB_ * G_;
    #pragma unroll
    for (int mi = 0; mi < 4; ++mi) {
        int r = m0 + mg * 4 + mi;
        #pragma unroll
        for (int jv = 0; jv < 3; ++jv)
            *(f32x4*)(gp + (size_t)r * G_ + ng * 12 + jv * 4) = acc[mi][jv];
    }
}

// ---------------- gate layer2: reduce 4 partials + bias + relu -> logits -> softmax -> top2 ----------------
__global__ __launch_bounds__(256) void k_gate2(
        const float* __restrict__ gs_part, const float* __restrict__ bg1,
        const float* __restrict__ Wg2, const float* __restrict__ bg2,
        float* __restrict__ cw, int* __restrict__ ecnt) {
    __shared__ float gsh[32][200];
    __shared__ float wg2s[G_ * N_];
    __shared__ float lg[32][8];
    int tid = threadIdx.x;
    int id0 = blockIdx.x * 32;

    for (int i = tid; i < 32 * 48; i += 256) {
        int r = i / 48, c4 = i % 48;
        const float* p0 = gs_part + (size_t)(id0 + r) * G_ + c4 * 4;
        float4 a = *(const float4*)p0;
        float4 b = *(const float4*)(p0 + (size_t)TB_ * G_);
        float4 c = *(const float4*)(p0 + 2 * (size_t)TB_ * G_);
        float4 d = *(const float4*)(p0 + 3 * (size_t)TB_ * G_);
        float4 g = *(const float4*)(bg1 + c4 * 4);
        float4 v;
        v.x = fmaxf(a.x + b.x + c.x + d.x + g.x, 0.f);
        v.y = fmaxf(a.y + b.y + c.y + d.y + g.y, 0.f);
        v.z = fmaxf(a.z + b.z + c.z + d.z + g.z, 0.f);
        v.w = fmaxf(a.w + b.w + c.w + d.w + g.w, 0.f);
        ((float4*)&gsh[r][0])[c4] = v;
    }
    for (int i = tid; i < G_ * N_; i += 256) wg2s[i] = Wg2[i];
    __syncthreads();

    int tk = tid >> 3, n = tid & 7;
    float a = bg2[n];
    for (int k = 0; k < G_; ++k) a += gsh[tk][k] * wg2s[k * N_ + n];
    lg[tk][n] = a;
    __syncthreads();

    if (tid < 32) {
        int tk2 = tid;
        float p[8];
        float m = lg[tk2][0];
        #pragma unroll
        for (int nn = 1; nn < 8; ++nn) m = fmaxf(m, lg[tk2][nn]);
        float s = 0.f;
        #pragma unroll
        for (int nn = 0; nn < 8; ++nn) { p[nn] = expf(lg[tk2][nn] - m); s += p[nn]; }
        float inv = 1.f / s;
        #pragma unroll
        for (int nn = 0; nn < 8; ++nn) p[nn] *= inv;
        int i1 = 0; float v1 = p[0];
        #pragma unroll
        for (int nn = 1; nn < 8; ++nn) if (p[nn] > v1) { v1 = p[nn]; i1 = nn; }
        int i2 = -1; float v2 = -1.f;
        #pragma unroll
        for (int nn = 0; nn < 8; ++nn) if (nn != i1 && p[nn] > v2) { v2 = p[nn]; i2 = nn; }
        int id = id0 + tk2;
        int t = id / B_, b = id % B_;
        ecnt[id] = 0;
        #pragma unroll
        for (int nn = 0; nn < 8; ++nn) {
            float v = (nn == i1 || nn == i2) ? p[nn] : 0.f;
            cw[((size_t)(b * N_ + nn)) * T_ + t] = v;
        }
    }
}

// ---------------- gate (fallback path only) ----------------
__global__ __launch_bounds__(256) void k_gate(
        const float* __restrict__ x, const float* __restrict__ Wg1,
        const float* __restrict__ bg1, const float* __restrict__ Wg2,
        const float* __restrict__ bg2, float* __restrict__ cw,
        int* __restrict__ ecnt) {
    __shared__ float xsh[8][F_];
    __shared__ float gsl[8][G_];
    __shared__ float lg[8][N_];
    int tid = threadIdx.x;
    int id0 = blockIdx.x * 8;

    int gid = blockIdx.x * 256 + tid;
    if (gid < TB_ && ecnt) ecnt[gid] = 0;

    const float4* xv = (const float4*)(x + (size_t)id0 * F_);
    float4* xshv = (float4*)&xsh[0][0];
    for (int idx = tid; idx < 8 * (F_/4); idx += 256) xshv[idx] = xv[idx];
    __syncthreads();

    if (tid < G_) {
        float acc[8];
        float bb = bg1[tid];
        #pragma unroll
        for (int tk = 0; tk < 8; ++tk) acc[tk] = bb;
        for (int k = 0; k < F_; ++k) {
            float w = Wg1[k * G_ + tid];
            #pragma unroll
            for (int tk = 0; tk < 8; ++tk) acc[tk] += xsh[tk][k] * w;
        }
        #pragma unroll
        for (int tk = 0; tk < 8; ++tk) gsl[tk][tid] = fmaxf(acc[tk], 0.f);
    }
    __syncthreads();

    if (tid < 64) {
        int tk = tid >> 3, n = tid & 7;
        float acc = bg2[n];
        for (int k = 0; k < G_; ++k) acc += gsl[tk][k] * Wg2[k * N_ + n];
        lg[tk][n] = acc;
    }
    __syncthreads();

    if (tid < 8) {
        int tk = tid;
        float p[8];
        float m = lg[tk][0];
        #pragma unroll
        for (int n = 1; n < 8; ++n) m = fmaxf(m, lg[tk][n]);
        float s = 0.f;
        #pragma unroll
        for (int n = 0; n < 8; ++n) { p[n] = expf(lg[tk][n] - m); s += p[n]; }
        float inv = 1.f / s;
        #pragma unroll
        for (int n = 0; n < 8; ++n) p[n] *= inv;
        int i1 = 0; float v1 = p[0];
        #pragma unroll
        for (int n = 1; n < 8; ++n) if (p[n] > v1) { v1 = p[n]; i1 = n; }
        int i2 = -1; float v2 = -1.f;
        #pragma unroll
        for (int n = 0; n < 8; ++n) if (n != i1 && p[n] > v2) { v2 = p[n]; i2 = n; }
        int id = id0 + tk;
        int t = id / B_, b = id % B_;
        #pragma unroll
        for (int n = 0; n < 8; ++n) {
            float v = (n == i1 || n == i2) ? p[n] : 0.f;
            cw[((size_t)(b * N_ + n)) * T_ + t] = v;
        }
    }
}

// ---------------- capacity: exact top-CAP rank per (b,n); builds inverse map ----------------
__global__ __launch_bounds__(256) void k_capacity(
        const float* __restrict__ cw, int* __restrict__ toks,
        float* __restrict__ wts, int* __restrict__ counts,
        int* __restrict__ ecnt, int* __restrict__ erow) {
    __shared__ float v[T_];
    __shared__ int keep[T_];
    int tid = threadIdx.x;
    int bn = blockIdx.x;
    int b = bn >> 3, n = bn & 7;
    if (tid < T_) v[tid] = cw[(size_t)bn * T_ + tid];
    __syncthreads();
    int kp = 0; float my = 0.f;
    if (tid < T_) {
        my = v[tid];
        int rank = 0;
        for (int t2 = 0; t2 < T_; ++t2) {
            float vt = v[t2];
            rank += (vt > my) || (vt == my && t2 < tid);
        }
        kp = (rank < CAP_) && (my > 0.f);
    }
    if (tid < T_) keep[tid] = kp;
    __syncthreads();
    if (tid < T_ && kp) {
        int slot = 0;
        for (int t2 = 0; t2 < T_; ++t2) slot += (t2 < tid) ? keep[t2] : 0;
        toks[bn * CAP_ + slot] = tid;
        wts[bn * CAP_ + slot] = my;
        if (ecnt) {
            int orow = tid * B_ + b;
            int pos = atomicAdd(&ecnt[orow], 1);
            erow[orow * 2 + pos] = n * ME_ + b * CAP_ + slot;
        }
    }
    if (tid == 0) {
        int tot = 0;
        for (int t2 = 0; t2 < T_; ++t2) tot += keep[t2];
        counts[bn] = tot;
    }
}

// ---------------- repack W [E][K][J] fp32 -> WT [E][J][K] bf16, pre-swizzled ----------------
__global__ __launch_bounds__(256) void k_repack(
        const float* __restrict__ W, unsigned short* __restrict__ WT, int K, int J) {
    __shared__ float tile[64][65];
    int bid = blockIdx.x;
    int nk = K >> 6, nj = J >> 6;
    int kt = bid % nk; bid /= nk;
    int jt = bid % nj; int e = bid / nj;
    int k0 = kt * 64, j0 = jt * 64;
    int tid = threadIdx.x;
    int jr = (tid & 15) << 2;
    int kr = tid >> 4;
    const float* src = W + ((size_t)e * K + k0) * J + j0;
    #pragma unroll
    for (int i = 0; i < 4; ++i) {
        float4 v = *(const float4*)(src + (size_t)(kr + 16 * i) * J + jr);
        *(float4*)&tile[kr + 16 * i][jr] = v;
    }
    __syncthreads();
    int c = tid & 7;
    int jrow = tid >> 3;
    #pragma unroll
    for (int i = 0; i < 2; ++i) {
        int j = jrow + 32 * i;
        float f[8];
        #pragma unroll
        for (int s = 0; s < 8; ++s) f[s] = tile[c * 8 + s][j];
        uint4 u;
        u.x = f2bf(f[0]) | ((unsigned)f2bf(f[1]) << 16);
        u.y = f2bf(f[2]) | ((unsigned)f2bf(f[3]) << 16);
        u.z = f2bf(f[4]) | ((unsigned)f2bf(f[5]) << 16);
        u.w = f2bf(f[6]) | ((unsigned)f2bf(f[7]) << 16);
        int jg = j0 + j;
        char* drow = (char*)WT + ((size_t)e * J + jg) * (size_t)K * 2 + (size_t)(k0 >> 6) * 128;
        *(uint4*)(drow + ((c << 4) ^ ((jg & 7) << 4))) = u;
    }
}

// ---------------- gather x rows -> Xg [MT_][768] bf16, pre-swizzled, zero-padded ----------------
__global__ __launch_bounds__(256) void k_gather(
        const float* __restrict__ x, const int* __restrict__ toks,
        const int* __restrict__ counts, unsigned short* __restrict__ Xg) {
    int gi = blockIdx.x * 256 + threadIdx.x;
    int R = gi / 96, c = gi - R * 96;
    int e = R / ME_, re = R - e * ME_;
    uint4 val = make_uint4(0u, 0u, 0u, 0u);
    if (re < MR_) {
        int g = re / CAP_, slot = re - g * CAP_;
        int bn = g * N_ + e;
        if (slot < counts[bn]) {
            int t = toks[bn * CAP_ + slot];
            const float* xp = x + ((size_t)t * B_ + g) * F_ + c * 8;
            float4 v0 = *(const float4*)xp;
            float4 v1 = *(const float4*)(xp + 4);
            val.x = f2bf(v0.x) | ((unsigned)f2bf(v0.y) << 16);
            val.y = f2bf(v0.z) | ((unsigned)f2bf(v0.w) << 16);
            val.z = f2bf(v1.x) | ((unsigned)f2bf(v1.y) << 16);
            val.w = f2bf(v1.z) | ((unsigned)f2bf(v1.w) << 16);
        }
    }
    int w = (c * 16) & 127;
    char* dst = (char*)Xg + (size_t)R * 1536 + (c >> 3) * 128 + (w ^ ((R & 7) << 4));
    *(uint4*)dst = val;
}

// ---------------- GEMM1 pass p: Hg_q = relu(W1T[:, pass-slice of H] . Xg^T + b1) ----------------
// grid 1200 = 8e x 25mt x 6jt; 2-phase dbuf; LDS-transposed coalesced epilogue.
__global__ __launch_bounds__(256) void k_gemm1(
        const unsigned short* __restrict__ W1T, const unsigned short* __restrict__ Xg,
        const float* __restrict__ b1, unsigned short* __restrict__ Hg, int pass) {
    __shared__ char ldsA[2][16384];
    __shared__ char ldsB[2][16384];
    int swzb = xcd_swz(blockIdx.x, NBLK_);
    int e = swzb / 150;
    int rem = swzb - e * 150;
    int mt = rem / 6, jt = rem % 6;
    int tid = threadIdx.x, lane = tid & 63, wid = tid >> 6;
    int lr8 = lane >> 3, sl = (lane & 7) << 4;
    const char* Ab = (const char*)W1T + ((size_t)e * H_ + pass * HP_ + jt * 128) * (F_ * 2);
    const char* Bb = (const char*)Xg + ((size_t)e * ME_ + mt * 128) * (F_ * 2);
    f32x4 acc[4][4] = {};
    int swz = (lane & 7) << 4;
    int q16 = (lane >> 4) << 4;

    auto stage = [&](int buf, int it) {
        int kb = it << 7;
        #pragma unroll
        for (int i = 0; i < 4; ++i) {
            int lr = wid * 32 + i * 8 + lr8;
            GLL16(Ab + (size_t)lr * 1536 + kb + sl, ldsA[buf] + (wid * 32 + i * 8) * 128);
            GLL16(Bb + (size_t)lr * 1536 + kb + sl, ldsB[buf] + (wid * 32 + i * 8) * 128);
        }
    };

    stage(0, 0);
    __syncthreads();
    int cur = 0;
    for (int it = 0; it < 12; ++it) {
        if (it < 11) stage(cur ^ 1, it + 1);
        const char* la = ldsA[cur] + ((wid & 1) * 64) * 128;
        const char* lb = ldsB[cur] + ((wid >> 1) * 64) * 128;
        #pragma unroll
        for (int ks = 0; ks < 2; ++ks) {
            bf16x8 af[4], bfr[4];
            int kk = (ks * 64 + q16) ^ swz;
            #pragma unroll
            for (int t = 0; t < 4; ++t) {
                int ro = (16 * t + (lane & 15)) * 128;
                af[t]  = *(const bf16x8*)(la + ro + kk);
                bfr[t] = *(const bf16x8*)(lb + ro + kk);
            }
            #pragma unroll
            for (int ti = 0; ti < 4; ++ti)
                #pragma unroll
                for (int tm = 0; tm < 4; ++tm)
                    acc[ti][tm] = __builtin_amdgcn_mfma_f32_16x16x32_bf16(af[ti], bfr[tm], acc[ti][tm], 0, 0, 0);
        }
        __syncthreads();
        cur ^= 1;
    }
    // epilogue: bias+relu -> bf16 swizzled LDS tile, then coalesced copy (Hg_q row stride 1536 B)
    char* tile = &ldsA[0][0];
    int jl0 = (wid & 1) * 64;
    int ml0 = (wid >> 1) * 64;
    const float* b1p = b1 + (size_t)e * H_ + pass * HP_ + jt * 128;
    #pragma unroll
    for (int tj = 0; tj < 4; ++tj) {
        int jc = jl0 + 16 * tj + ((lane >> 4) << 2);
        float bb0 = b1p[jc], bb1 = b1p[jc + 1], bb2 = b1p[jc + 2], bb3 = b1p[jc + 3];
        #pragma unroll
        for (int tm = 0; tm < 4; ++tm) {
            int m = ml0 + 16 * tm + (lane & 15);
            f32x4 a = acc[tj][tm];
            unsigned int u0 = f2bf(fmaxf(a[0] + bb0, 0.f)) | ((unsigned)f2bf(fmaxf(a[1] + bb1, 0.f)) << 16);
            unsigned int u1 = f2bf(fmaxf(a[2] + bb2, 0.f)) | ((unsigned)f2bf(fmaxf(a[3] + bb3, 0.f)) << 16);
            int bcol = jc * 2;
            int w = bcol & 127;
            *(uint2*)(tile + m * 256 + (bcol & ~127) + (w ^ ((m & 7) << 4))) = make_uint2(u0, u1);
        }
    }
    __syncthreads();
    char* Hrow = (char*)Hg + ((size_t)e * ME_ + mt * 128) * (HP_ * 2) + (size_t)jt * 256;
    #pragma unroll
    for (int i = 0; i < 8; ++i) {
        int idx = tid + i * 256;
        int r = idx >> 4, c = (idx & 15) << 4;
        *(uint4*)(Hrow + (size_t)r * (HP_ * 2) + c) = *(const uint4*)(tile + r * 256 + c);
    }
}

// ---------------- GEMM2 pass p: Og (+)= fw * (W2T[:, K-slice] . Hg_q^T) (+ fw*b2 at p=0) ----------------
// grid 1200 = 8e x 25mt x 6ft; clean coalesced rmw stores, no atomics.
__global__ __launch_bounds__(256) void k_gemm2(
        const unsigned short* __restrict__ W2T, const unsigned short* __restrict__ Hg,
        const float* __restrict__ b2, const float* __restrict__ wts,
        const int* __restrict__ counts, unsigned short* __restrict__ Og, int pass) {
    __shared__ char ldsA[2][16384];
    __shared__ char ldsB[2][16384];
    int swzb = xcd_swz(blockIdx.x, NBLK_);
    int e = swzb / 150;
    int rem = swzb - e * 150;
    int mt = rem / 6, ft = rem % 6;
    int tid = threadIdx.x, lane = tid & 63, wid = tid >> 6;
    int lr8 = lane >> 3, sl = (lane & 7) << 4;
    const char* Ab = (const char*)W2T + ((size_t)e * F_ + ft * 128) * (H_ * 2) + (size_t)pass * (HP_ * 2);
    const char* Bb = (const char*)Hg + ((size_t)e * ME_ + mt * 128) * (HP_ * 2);
    f32x4 acc[4][4] = {};
    int swz = (lane & 7) << 4;
    int q16 = (lane >> 4) << 4;

    auto stage = [&](int buf, int it) {
        int kb = it << 7;
        #pragma unroll
        for (int i = 0; i < 4; ++i) {
            int lr = wid * 32 + i * 8 + lr8;
            GLL16(Ab + (size_t)lr * 6144 + kb + sl, ldsA[buf] + (wid * 32 + i * 8) * 128);
            GLL16(Bb + (size_t)lr * 1536 + kb + sl, ldsB[buf] + (wid * 32 + i * 8) * 128);
        }
    };

    stage(0, 0);
    __syncthreads();
    int cur = 0;
    for (int it = 0; it < 12; ++it) {
        if (it < 11) stage(cur ^ 1, it + 1);
        const char* la = ldsA[cur] + ((wid & 1) * 64) * 128;
        const char* lb = ldsB[cur] + ((wid >> 1) * 64) * 128;
        #pragma unroll
        for (int ks = 0; ks < 2; ++ks) {
            bf16x8 af[4], bfr[4];
            int kk = (ks * 64 + q16) ^ swz;
            #pragma unroll
            for (int t = 0; t < 4; ++t) {
                int ro = (16 * t + (lane & 15)) * 128;
                af[t]  = *(const bf16x8*)(la + ro + kk);
                bfr[t] = *(const bf16x8*)(lb + ro + kk);
            }
            #pragma unroll
            for (int ti = 0; ti < 4; ++ti)
                #pragma unroll
                for (int tm = 0; tm < 4; ++tm)
                    acc[ti][tm] = __builtin_amdgcn_mfma_f32_16x16x32_bf16(af[ti], bfr[tm], acc[ti][tm], 0, 0, 0);
        }
        __syncthreads();
        cur ^= 1;
    }
    // epilogue: fw*(acc [+ b2]) -> bf16 swizzled LDS tile, then coalesced (accumulating) copy-out
    char* tile = &ldsA[0][0];
    int fl0 = (wid & 1) * 64;
    int ml0 = (wid >> 1) * 64;
    const float* b2p = b2 + (size_t)e * F_ + (size_t)ft * 128;
    float fwv[4];
    #pragma unroll
    for (int tm = 0; tm < 4; ++tm) {
        int mloc = ml0 + 16 * tm + (lane & 15);
        int re = mt * 128 + mloc;
        float fw = 0.f;
        if (re < MR_) {
            int g = re / CAP_;
            int slot = re - g * CAP_;
            int bn = g * N_ + e;
            if (slot < counts[bn]) fw = wts[bn * CAP_ + slot];
        }
        fwv[tm] = fw;
    }
    #pragma unroll
    for (int tf = 0; tf < 4; ++tf) {
        int fc = fl0 + 16 * tf + ((lane >> 4) << 2);
        float c0 = 0.f, c1 = 0.f, c2 = 0.f, c3 = 0.f;
        if (pass == 0) { c0 = b2p[fc]; c1 = b2p[fc + 1]; c2 = b2p[fc + 2]; c3 = b2p[fc + 3]; }
        #pragma unroll
        for (int tm = 0; tm < 4; ++tm) {
            int mloc = ml0 + 16 * tm + (lane & 15);
            f32x4 a = acc[tf][tm];
            float fw = fwv[tm];
            unsigned int u0 = f2bf(fw * (a[0] + c0)) | ((unsigned)f2bf(fw * (a[1] + c1)) << 16);
            unsigned int u1 = f2bf(fw * (a[2] + c2)) | ((unsigned)f2bf(fw * (a[3] + c3)) << 16);
            int bcol = fc * 2;
            int w = bcol & 127;
            *(uint2*)(tile + mloc * 256 + (bcol & ~127) + (w ^ ((mloc & 7) << 4))) = make_uint2(u0, u1);
        }
    }
    __syncthreads();
    char* Orow = (char*)Og + ((size_t)e * ME_ + mt * 128) * (F_ * 2) + (size_t)ft * 256;
    if (pass == 0) {
        #pragma unroll
        for (int i = 0; i < 8; ++i) {
            int idx = tid + i * 256;
            int r = idx >> 4, c = (idx & 15) << 4;
            const char* src = tile + r * 256 + (c & ~127) + ((c & 127) ^ ((r & 7) << 4));
            *(uint4*)(Orow + (size_t)r * (F_ * 2) + c) = *(const uint4*)src;
        }
    } else {
        #pragma unroll
        for (int i = 0; i < 8; ++i) {
            int idx = tid + i * 256;
            int r = idx >> 4, c = (idx & 15) << 4;
            const char* src = tile + r * 256 + (c & ~127) + ((c & 127) ^ ((r & 7) << 4));
            uint4 nw = *(const uint4*)src;
            uint4* dst = (uint4*)(Orow + (size_t)r * (F_ * 2) + c);
            uint4 old = *dst;
            uint4 res;
            res.x = add2bf(old.x, nw.x);
            res.y = add2bf(old.y, nw.y);
            res.z = add2bf(old.z, nw.z);
            res.w = add2bf(old.w, nw.w);
            *dst = res;
        }
    }
}

// ---------------- combine: out[t,b,:] = sum(og entries) - x ----------------
__global__ __launch_bounds__(256) void k_combine(
        const float* __restrict__ x, const unsigned short* __restrict__ Og,
        const int* __restrict__ ecnt, const int* __restrict__ erow,
        float* __restrict__ out) {
    int idx = blockIdx.x * 256 + threadIdx.x;
    int row = idx / 192, c4 = idx - row * 192;
    float4 s = make_float4(0.f, 0.f, 0.f, 0.f);
    int c = ecnt[row];
    if (c > 0) {
        ushort4 u = *(const ushort4*)(Og + (size_t)erow[row * 2] * F_ + c4 * 4);
        s.x += bf2f(u.x); s.y += bf2f(u.y); s.z += bf2f(u.z); s.w += bf2f(u.w);
    }
    if (c > 1) {
        ushort4 u = *(const ushort4*)(Og + (size_t)erow[row * 2 + 1] * F_ + c4 * 4);
        s.x += bf2f(u.x); s.y += bf2f(u.y); s.z += bf2f(u.z); s.w += bf2f(u.w);
    }
    float4 xv = ((const float4*)x)[idx];
    ((float4*)out)[idx] = make_float4(s.x - xv.x, s.y - xv.y, s.z - xv.z, s.w - xv.w);
}

// ================= round-1 fallback kernels (tiny ws only) =================
__global__ __launch_bounds__(HCF_) void k_fc1(
        const float* __restrict__ x, const float* __restrict__ W1,
        const float* __restrict__ b1, const int* __restrict__ toks,
        const int* __restrict__ counts, __hip_bfloat16* __restrict__ h, int pass) {
    __shared__ float xs[25][F_];
    int tid = threadIdx.x;
    int bn = blockIdx.x >> 1;
    int half = blockIdx.x & 1;
    int r0 = half * 25;
    int b = bn >> 3, n = bn & 7;
    int c = counts[bn];
    for (int idx = tid; idx < 25 * (F_/4); idx += HCF_) {
        int r = idx / (F_/4), k4 = idx % (F_/4);
        int gr = r0 + r;
        float4 val = make_float4(0.f, 0.f, 0.f, 0.f);
        if (gr < c) {
            int t = toks[bn * CAP_ + gr];
            val = ((const float4*)(x + ((size_t)(t * B_ + b)) * F_))[k4];
        }
        ((float4*)&xs[r][0])[k4] = val;
    }
    __syncthreads();
    int j = pass * HCF_ + tid;
    const float* w1p = W1 + (size_t)n * F_ * H_ + j;
    float bias = b1[n * H_ + j];
    float acc[25];
    #pragma unroll
    for (int r = 0; r < 25; ++r) acc[r] = bias;
    const float4* xsv = (const float4*)&xs[0][0];
    for (int k4 = 0; k4 < F_/4; ++k4) {
        float w0 = w1p[(size_t)(4*k4+0) * H_];
        float w1v = w1p[(size_t)(4*k4+1) * H_];
        float w2v = w1p[(size_t)(4*k4+2) * H_];
        float w3v = w1p[(size_t)(4*k4+3) * H_];
        #pragma unroll
        for (int r = 0; r < 25; ++r) {
            float4 xv = xsv[r * (F_/4) + k4];
            acc[r] += xv.x*w0 + xv.y*w1v + xv.z*w2v + xv.w*w3v;
        }
    }
    __hip_bfloat16* hp = h + ((size_t)bn * CAP_ + r0) * HCF_ + tid;
    #pragma unroll
    for (int r = 0; r < 25; ++r) {
        int gr = r0 + r;
        if (gr < CAP_) hp[(size_t)r * HCF_] = __float2bfloat16(fmaxf(acc[r], 0.f));
    }
}

__global__ __launch_bounds__(768) void k_fc2(
        const float* __restrict__ W2, const float* __restrict__ b2,
        const int* __restrict__ toks, const float* __restrict__ wts,
        const int* __restrict__ counts, const __hip_bfloat16* __restrict__ h,
        float* __restrict__ out, int pass) {
    __shared__ float hs[CAP_][HCF_];
    int tid = threadIdx.x;
    int bn = blockIdx.x;
    int c = counts[bn];
    if (c == 0) return;
    int b = bn >> 3, n = bn & 7;
    const ushort4* hv = (const ushort4*)(h + (size_t)bn * CAP_ * HCF_);
    for (int idx = tid; idx < CAP_ * (HCF_/4); idx += 768) {
        ushort4 u = hv[idx];
        float4 fv;
        fv.x = __bfloat162float(*(const __hip_bfloat16*)&u.x);
        fv.y = __bfloat162float(*(const __hip_bfloat16*)&u.y);
        fv.z = __bfloat162float(*(const __hip_bfloat16*)&u.z);
        fv.w = __bfloat162float(*(const __hip_bfloat16*)&u.w);
        ((float4*)&hs[0][0])[idx] = fv;
    }
    __syncthreads();
    int f = tid;
    const float* w2p = W2 + (size_t)n * H_ * F_ + (size_t)(pass * HCF_) * F_ + f;
    float acc[CAP_];
    #pragma unroll
    for (int r = 0; r < CAP_; ++r) acc[r] = 0.f;
    for (int j4 = 0; j4 < HCF_/4; ++j4) {
        float w0 = w2p[(size_t)(4*j4+0) * F_];
        float w1v = w2p[(size_t)(4*j4+1) * F_];
        float w2v = w2p[(size_t)(4*j4+2) * F_];
        float w3v = w2p[(size_t)(4*j4+3) * F_];
        #pragma unroll
        for (int r = 0; r < CAP_; ++r) {
            float4 hh = ((const float4*)&hs[r][0])[j4];
            acc[r] += hh.x*w0 + hh.y*w1v + hh.z*w2v + hh.w*w3v;
        }
    }
    float bias = (pass == 0) ? b2[n * F_ + f] : 0.f;
    #pragma unroll
    for (int r = 0; r < CAP_; ++r) {
        if (r < c) {
            int t = toks[bn * CAP_ + r];
            float fw = wts[bn * CAP_ + r];
            atomicAdd(&out[((size_t)(t * B_ + b)) * F_ + f], fw * (acc[r] + bias));
        }
    }
}

extern "C" void kernel_launch(void* const* d_in, const int* in_sizes, int n_in,
                              void* d_out, int out_size, void* d_ws, size_t ws_size,
                              hipStream_t stream) {
    const float* x   = (const float*)d_in[0];
    const float* Wg1 = (const float*)d_in[1];
    const float* bg1 = (const float*)d_in[2];
    const float* Wg2 = (const float*)d_in[3];
    const float* bg2 = (const float*)d_in[4];
    const float* W1  = (const float*)d_in[5];
    const float* b1  = (const float*)d_in[6];
    const float* W2  = (const float*)d_in[7];
    const float* b2  = (const float*)d_in[8];
    float* out = (float*)d_out;

    // ws layout (total 194,219,776 B — identical to the proven grp=2 requirement)
    size_t oW1T  = 0;
    size_t oW2T  = oW1T + (size_t)N_ * H_ * F_ * 2;
    size_t oXg   = oW2T + (size_t)N_ * H_ * F_ * 2;
    size_t oCw   = oXg  + (size_t)MT_ * F_ * 2;
    size_t oWts  = oCw  + (size_t)NBN_ * T_ * 4;
    size_t oTok  = oWts + (size_t)NBN_ * CAP_ * 4;
    size_t oCnt  = oTok + (size_t)NBN_ * CAP_ * 4;
    size_t oEcnt = oCnt + (size_t)NBN_ * 4;
    size_t oErow = oEcnt + (size_t)TB_ * 4;
    size_t oOg   = oErow + (size_t)TB_ * 8;
    size_t oHg   = oOg  + (size_t)MT_ * F_ * 2;
    size_t need  = oHg + (size_t)MT_ * HP_ * 2;   // Hg quarter-slice (39.3 MB)

    if (ws_size >= need) {
        unsigned short* W1T = (unsigned short*)((char*)d_ws + oW1T);
        unsigned short* W2T = (unsigned short*)((char*)d_ws + oW2T);
        unsigned short* Xg  = (unsigned short*)((char*)d_ws + oXg);
        unsigned short* Og  = (unsigned short*)((char*)d_ws + oOg);
        unsigned short* Hg  = (unsigned short*)((char*)d_ws + oHg);
        float* gs_part = (float*)((char*)d_ws + oHg);   // aliases Hg: dead before gemm1_0 writes
        float* cw   = (float*)((char*)d_ws + oCw);
        float* wts  = (float*)((char*)d_ws + oWts);
        int* toks   = (int*)((char*)d_ws + oTok);
        int* counts = (int*)((char*)d_ws + oCnt);
        int* ecnt   = (int*)((char*)d_ws + oEcnt);
        int* erow   = (int*)((char*)d_ws + oErow);

        k_gate1<<<197 * KH_, 256, 0, stream>>>(x, Wg1, gs_part);
        k_gate2<<<TB_ / 32, 256, 0, stream>>>(gs_part, bg1, Wg2, bg2, cw, ecnt);
        k_capacity<<<NBN_, 256, 0, stream>>>(cw, toks, wts, counts, ecnt, erow);
        k_repack<<<N_ * (F_/64) * (H_/64), 256, 0, stream>>>(W1, W1T, F_, H_);
        k_repack<<<N_ * (H_/64) * (F_/64), 256, 0, stream>>>(W2, W2T, H_, F_);
        k_gather<<<(MT_ * 96) / 256, 256, 0, stream>>>(x, toks, counts, Xg);
        for (int p = 0; p < 4; ++p) {
            k_gemm1<<<NBLK_, 256, 0, stream>>>(W1T, Xg, b1, Hg, p);
            k_gemm2<<<NBLK_, 256, 0, stream>>>(W2T, Hg, b2, wts, counts, Og, p);
        }
        k_combine<<<(TB_ * 192) / 256, 256, 0, stream>>>(x, Og, ecnt, erow, out);
    } else {
        // round-1 fallback (~20 MB ws)
        __hip_bfloat16* h = (__hip_bfloat16*)d_ws;
        float* cw  = (float*)((char*)d_ws + (size_t)NBN_ * CAP_ * HCF_ * 2);
        float* wts = cw + (size_t)NBN_ * T_;
        int* toks  = (int*)(wts + NBN_ * CAP_);
        int* counts = toks + NBN_ * CAP_;
        k_init_out<<<(TB_ * F_) / 1024, 256, 0, stream>>>(x, out);
        k_gate<<<TB_ / 8, 256, 0, stream>>>(x, Wg1, bg1, Wg2, bg2, cw, nullptr);
        k_capacity<<<NBN_, 256, 0, stream>>>(cw, toks, wts, counts, nullptr, nullptr);
        for (int p = 0; p < NPF_; ++p) {
            k_fc1<<<NBN_ * 2, HCF_, 0, stream>>>(x, W1, b1, toks, counts, h, p);
            k_fc2<<<NBN_, 768, 0, stream>>>(W2, b2, toks, wts, counts, h, out, p);
        }
    }
}